// Round 3
// baseline (6993.434 us; speedup 1.0000x reference)
//
#include <hip/hip_runtime.h>
#include <hip/hip_bf16.h>

// NodeFormerConv: Performer/Gumbel attention. fp32 math, fp32 output.
// Pipeline (all on `stream`):
//   k0   zero kvs[4][300][64] + kssum[4][300]
//   k1   q-features -> qp (bf16, [n][h][m]) ; k-side per-tile max -> blockmax
//   k1b  blockmax -> headmax[4]
//   k2   recompute k-features per (head,chunk); v = z@Wv; accumulate
//        kvs[h,k,m,d] += kp*ge*v, kssum[h,k,m] += kp*ge (regs, atomic flush)
//   k3   per 32-row block: loop heads {kvs_h->LDS, qp rows->LDS, den on the
//        fly, numerator -> zl[32][256] in LDS}; then out = zl@Wo + bo (f32)
// ws: qp16 N*120*2B | kvs 76800f | kssum 1200f | headmax 4f | blockmax ntiles*4f  (~12.4 MB)

#define NEPS  1e-6f
#define RATIO 0.18257418583505536f   // 1/sqrt(30)
#define DNORM 0.35355339059327378f   // 64^-0.25

__global__ __launch_bounds__(256) void k0_zero(float* __restrict__ p, int count) {
    int id = blockIdx.x * 256 + threadIdx.x;
    if (id < count) p[id] = 0.f;
}

// ---- k1: per 8-row tile: QK gemm (64x256), q-phi -> qp(bf16), k-phi -> per-tile max ----
__global__ __launch_bounds__(256) void k1_feat(
    const float* __restrict__ z, const float* __restrict__ Wq, const float* __restrict__ bq,
    const float* __restrict__ Wk, const float* __restrict__ bk,
    const float* __restrict__ proj, const float* __restrict__ tau,
    __hip_bfloat16* __restrict__ qp16, float* __restrict__ blockmax, int N)
{
    __shared__ float zs[512];
    __shared__ float projl[30 * 65];
    __shared__ float dq[8 * 260];     // [nn][h*65+d]
    __shared__ float dk[8 * 260];
    __shared__ float ddq[8 * 120];    // q dd: [nn][h*30+m]
    __shared__ float dgq[32];         // q diag: [nn*4+h]
    __shared__ float kmx[120];        // k max over nn: [h*30+m]

    const int t = threadIdx.x;
    const int tile = blockIdx.x;
    const int n0 = tile * 8;

    for (int i = t; i < 1920; i += 256) projl[(i >> 6) * 65 + (i & 63)] = proj[i];
    for (int i = t; i < 512; i += 256) {
        int nn = i >> 6;
        zs[i] = (n0 + nn < N) ? z[(long)n0 * 64 + i] : 0.f;
    }
    __syncthreads();

    const float dsc = rsqrtf(tau[0]) * DNORM;
    {
        const int c = t;
        float accq[8] = {0,0,0,0,0,0,0,0};
        float acck[8] = {0,0,0,0,0,0,0,0};
        for (int i = 0; i < 64; ++i) {
            float wq = Wq[i * 256 + c];
            float wk = Wk[i * 256 + c];
#pragma unroll
            for (int nn = 0; nn < 8; ++nn) {
                float zv = zs[nn * 64 + i];
                accq[nn] += zv * wq;
                acck[nn] += zv * wk;
            }
        }
        const float bqc = bq[c], bkc = bk[c];
        const int hh = c >> 6, d2 = c & 63;
#pragma unroll
        for (int nn = 0; nn < 8; ++nn) {
            dq[nn * 260 + hh * 65 + d2] = (accq[nn] + bqc) * dsc;
            dk[nn * 260 + hh * 65 + d2] = (acck[nn] + bkc) * dsc;
        }
    }
    __syncthreads();

    if (t < 120) {                       // q-phi
        const int hh = t / 30, m = t % 30;
#pragma unroll
        for (int nn = 0; nn < 8; ++nn) {
            float s = 0.f;
            for (int i = 0; i < 64; ++i) s += dq[nn * 260 + hh * 65 + i] * projl[m * 65 + i];
            ddq[nn * 120 + t] = s;
        }
    }
    if (t >= 128 && t < 248) {           // k-phi + max over rows
        const int tt = t - 128, hh = tt / 30, m = tt % 30;
        float tmax = -3.4e38f;
#pragma unroll
        for (int nn = 0; nn < 8; ++nn) {
            float s = 0.f;
            for (int i = 0; i < 64; ++i) s += dk[nn * 260 + hh * 65 + i] * projl[m * 65 + i];
            tmax = fmaxf(tmax, s);
        }
        kmx[tt] = tmax;
    }
    if (t < 32) {                        // q diag
        const int nn = t >> 2, hh = t & 3;
        float s = 0.f;
        for (int i = 0; i < 64; ++i) { float x = dq[nn * 260 + hh * 65 + i]; s += x * x; }
        dgq[t] = 0.5f * s;
    }
    __syncthreads();

    if (t < 4) {
        float mx = kmx[t * 30];
        for (int m = 1; m < 30; ++m) mx = fmaxf(mx, kmx[t * 30 + m]);
        blockmax[tile * 4 + t] = mx;
    }
    for (int idx = t; idx < 960; idx += 256) {
        int nn = idx / 120, r = idx % 120, hh = r / 30;
        float rmax = ddq[nn * 120 + hh * 30];
        for (int m = 1; m < 30; ++m) rmax = fmaxf(rmax, ddq[nn * 120 + hh * 30 + m]);
        float val = RATIO * (expf(ddq[nn * 120 + r] - dgq[nn * 4 + hh] - rmax) + NEPS);
        if (n0 + nn < N) qp16[(long)tile * 960 + idx] = __float2bfloat16(val);
    }
}

__global__ __launch_bounds__(256) void k1b_redmax(
    const float* __restrict__ blockmax, float* __restrict__ headmax, int ntiles)
{
    __shared__ float red[4 * 256];
    const int t = threadIdx.x;
    float lm[4] = {-3.4e38f, -3.4e38f, -3.4e38f, -3.4e38f};
    for (int i = t; i < ntiles; i += 256) {
#pragma unroll
        for (int hh = 0; hh < 4; ++hh) lm[hh] = fmaxf(lm[hh], blockmax[i * 4 + hh]);
    }
#pragma unroll
    for (int hh = 0; hh < 4; ++hh) red[hh * 256 + t] = lm[hh];
    __syncthreads();
    if (t < 4) {
        float mx = red[t * 256];
        for (int i = 1; i < 256; ++i) mx = fmaxf(mx, red[t * 256 + i]);
        headmax[t] = mx;
    }
}

// ---- k2: recompute k-features per (head, chunk); accumulate kvs / kssum ----
__global__ __launch_bounds__(256) void k2_kvs(
    const float* __restrict__ z, const float* __restrict__ Wk, const float* __restrict__ bk,
    const float* __restrict__ Wv, const float* __restrict__ bv,
    const float* __restrict__ proj, const float* __restrict__ gum,
    const float* __restrict__ tau, const float* __restrict__ headmax,
    float* __restrict__ kvs, float* __restrict__ kssum, int N, int nchunk)
{
    __shared__ float projl[30 * 65];
    __shared__ float zs[64], kkv[64], vv[64];
    __shared__ float ddk[30], dgk[1], kpl[30], gel[10], pl[300];

    const int t = threadIdx.x;
    const int h = blockIdx.x >> 7;       // 128 chunks per head
    const int chunk = blockIdx.x & 127;
    const int n0 = chunk * nchunk;
    const int n1 = (n0 + nchunk < N) ? (n0 + nchunk) : N;
    const float MX = headmax[h];
    const float itau = 1.0f / tau[0];
    const float dsc = rsqrtf(tau[0]) * DNORM;
    const int wg = t >> 6, d = t & 63;

    for (int i = t; i < 1920; i += 256) projl[(i >> 6) * 65 + (i & 63)] = proj[i];

    float akv[75], aks[75];
#pragma unroll
    for (int j = 0; j < 75; ++j) { akv[j] = 0.f; aks[j] = 0.f; }
    __syncthreads();   // projl ready

    for (int n = n0; n < n1; ++n) {
        if (t < 64) zs[t] = z[(long)n * 64 + t];
        __syncthreads();                                     // B0
        if (t < 64) {
            float a = bk[h * 64 + t];
            for (int i = 0; i < 64; ++i) a += zs[i] * Wk[i * 256 + h * 64 + t];
            kkv[t] = a * dsc;
        } else if (t < 128) {
            const int c = t - 64;
            float a = bv[h * 64 + c];
            for (int i = 0; i < 64; ++i) a += zs[i] * Wv[i * 256 + h * 64 + c];
            vv[c] = a;
        } else if (t < 138) {
            gel[t - 128] = expf(gum[(long)n * 40 + h * 10 + (t - 128)] * itau);
        }
        __syncthreads();                                     // B1
        if (t < 30) {
            float s = 0.f;
            for (int i = 0; i < 64; ++i) s += kkv[i] * projl[t * 65 + i];
            ddk[t] = s;
        } else if (t == 30) {
            float s = 0.f;
            for (int i = 0; i < 64; ++i) { float x = kkv[i]; s += x * x; }
            dgk[0] = 0.5f * s;
        }
        __syncthreads();                                     // B2
        if (t < 30) kpl[t] = RATIO * (expf(ddk[t] - dgk[0] - MX) + NEPS);
        __syncthreads();                                     // B3
        pl[t] = kpl[t % 30] * gel[t / 30];                   // t<256 < 300
        if (t < 44) pl[t + 256] = kpl[(t + 256) % 30] * gel[(t + 256) / 30];
        __syncthreads();                                     // B4
        const float vd = vv[d];
        const float* pp = &pl[wg * 75];                      // wave-uniform -> LDS broadcast
#pragma unroll
        for (int j = 0; j < 75; ++j) {
            float p = pp[j];
            akv[j] += p * vd;
            aks[j] += p;
        }
        // next iteration's B0 orders zs/vv/pl rewrites after this read phase
    }

    float* kvh = kvs + h * 19200;
#pragma unroll
    for (int j = 0; j < 75; ++j) atomicAdd(&kvh[(wg * 75 + j) * 64 + d], akv[j]);
    if (d == 0) {
        float* ksh = kssum + h * 300 + wg * 75;
#pragma unroll
        for (int j = 0; j < 75; ++j) atomicAdd(&ksh[j], aks[j]);
    }
}

// ---- k3: 32-row block; heads sequential (kvs_h in LDS); den+num fused; out = zl@Wo + bo (f32) ----
__global__ __launch_bounds__(512) void k3_out(
    const __hip_bfloat16* __restrict__ qp16, const float* __restrict__ kvs,
    const float* __restrict__ kssum, const float* __restrict__ Wo,
    const float* __restrict__ bo, float* __restrict__ out, int N)
{
    __shared__ alignas(16) float SA[19200];     // kvs_h, later Wo
    __shared__ alignas(16) float zl[32 * 260];  // [r][c] c=h*64+d, pad 260 (16B-aligned rows)
    __shared__ float qpl[32 * 30];
    __shared__ float idl[32 * 10];
    __shared__ float ksl[300];
    __shared__ alignas(16) float bol[64];

    const int t = threadIdx.x;
    const int n0 = blockIdx.x * 32;
    const int r = t >> 4, d4 = t & 15;          // 32 rows x 16 float4-columns

    for (int h = 0; h < 4; ++h) {
        __syncthreads();                         // A: prev head's readers done
        for (int i = t; i < 19200; i += 512) SA[i] = kvs[h * 19200 + i];
        if (t < 300) ksl[t] = kssum[h * 300 + t];
        for (int i = t; i < 960; i += 512) {
            int rr = i / 30, m = i % 30;
            long n = n0 + rr;
            qpl[i] = (n < N) ? __bfloat162float(qp16[n * 120 + h * 30 + m]) : 1.0f;
        }
        __syncthreads();                         // B: SA/ksl/qpl ready
        if (t < 320) {
            const int rr = t / 10, kk = t % 10;
            float s = 0.f;
#pragma unroll
            for (int m = 0; m < 30; ++m) s += qpl[rr * 30 + m] * ksl[kk * 30 + m];
            idl[t] = 1.0f / s;
        }
        __syncthreads();                         // C: idl ready
        {
            const float* qr = &qpl[r * 30];
            const float* ir = &idl[r * 10];
            const float4* SA4 = reinterpret_cast<const float4*>(SA);
            float sx = 0.f, sy = 0.f, sz = 0.f, sw = 0.f;
#pragma unroll
            for (int kk = 0; kk < 10; ++kk) {
                float ax = 0.f, ay = 0.f, az = 0.f, aw = 0.f;
#pragma unroll
                for (int m = 0; m < 30; ++m) {
                    float4 b = SA4[(kk * 30 + m) * 16 + d4];
                    float q = qr[m];
                    ax += q * b.x; ay += q * b.y; az += q * b.z; aw += q * b.w;
                }
                float w = ir[kk];
                sx += ax * w; sy += ay * w; sz += az * w; sw += aw * w;
            }
            float4 zv; zv.x = 0.1f * sx; zv.y = 0.1f * sy; zv.z = 0.1f * sz; zv.w = 0.1f * sw;
            reinterpret_cast<float4*>(zl)[r * 65 + h * 16 + d4] = zv;
        }
    }
    __syncthreads();                             // D: zl complete, SA readers done
    for (int i = t; i < 16384; i += 512) SA[i] = Wo[i];
    if (t < 64) bol[t] = bo[t];
    __syncthreads();
    {
        const float4* W4 = reinterpret_cast<const float4*>(SA);
        float4 o = reinterpret_cast<const float4*>(bol)[d4];
        const float* zr = &zl[r * 260];
#pragma unroll 8
        for (int c = 0; c < 256; ++c) {
            float zv = zr[c];
            float4 w = W4[c * 16 + d4];
            o.x += zv * w.x; o.y += zv * w.y; o.z += zv * w.z; o.w += zv * w.w;
        }
        long n = n0 + r;
        if (n < N) {
            *reinterpret_cast<float4*>(out + n * 64 + d4 * 4) = o;   // f32 output
        }
    }
}

extern "C" void kernel_launch(void* const* d_in, const int* in_sizes, int n_in,
                              void* d_out, int out_size, void* d_ws, size_t ws_size,
                              hipStream_t stream)
{
    const float* z    = (const float*)d_in[0];
    const float* Wq   = (const float*)d_in[1];
    const float* bq   = (const float*)d_in[2];
    const float* Wk   = (const float*)d_in[3];
    const float* bk   = (const float*)d_in[4];
    const float* Wv   = (const float*)d_in[5];
    const float* bv   = (const float*)d_in[6];
    const float* Wo   = (const float*)d_in[7];
    const float* bo   = (const float*)d_in[8];
    const float* proj = (const float*)d_in[9];
    const float* gum  = (const float*)d_in[10];
    const float* tau  = (const float*)d_in[11];
    float* out = (float*)d_out;

    const int N = in_sizes[0] / 64;          // 50000
    const int ntiles = (N + 7) / 8;          // 6250
    const int nchunk = (N + 127) / 128;      // 391
    const int nblk3  = (N + 31) / 32;        // 1563

    // ws layout: qp16 (bf16) | kvs | kssum | headmax | blockmax  (~12.4 MB)
    char* wsb = (char*)d_ws;
    __hip_bfloat16* qp16 = (__hip_bfloat16*)wsb;
    size_t qpB = ((size_t)N * 120 * 2 + 255) & ~(size_t)255;
    float* kvs      = (float*)(wsb + qpB);
    float* kssum    = kvs + 76800;
    float* headmax  = kssum + 1200;
    float* blockmax = headmax + 4;

    k0_zero<<<dim3((78000 + 255) / 256), dim3(256), 0, stream>>>(kvs, 78000);
    k1_feat<<<dim3(ntiles), dim3(256), 0, stream>>>(z, Wq, bq, Wk, bk, proj, tau,
                                                    qp16, blockmax, N);
    k1b_redmax<<<dim3(1), dim3(256), 0, stream>>>(blockmax, headmax, ntiles);
    k2_kvs<<<dim3(512), dim3(256), 0, stream>>>(z, Wk, bk, Wv, bv, proj, gum, tau,
                                                headmax, kvs, kssum, N, nchunk);
    k3_out<<<dim3(nblk3), dim3(512), 0, stream>>>(qp16, kvs, kssum, Wo, bo, out, N);
}

// Round 4
// 901.178 us; speedup vs baseline: 7.7603x; 7.7603x over previous
//
#include <hip/hip_runtime.h>
#include <hip/hip_bf16.h>

// NodeFormerConv: Performer/Gumbel attention. fp32 math, fp32 output.
//   k0   zero kvs[4][300][64] + kssum[4][300]
//   k1   q-features -> qp (bf16, [n][h][m]) ; k-side per-tile max -> blockmax
//   k1b  blockmax -> headmax[4]
//   k2   64-row-tiled: z->LDS, kk GEMM, phi+diag, kp, vv GEMM, factored
//        accumulate akv[60]/aks in regs (wave owns 6m x 10k), atomic flush
//   k3   per 32-row block: heads sequential; den+num fused; out = zl@Wo + bo (f32)
// ws: qp16 N*120*2B | kvs 76800f | kssum 1200f | headmax 4f | blockmax ntiles*4f

#define NEPS  1e-6f
#define RATIO 0.18257418583505536f   // 1/sqrt(30)
#define DNORM 0.35355339059327378f   // 64^-0.25

__global__ __launch_bounds__(256) void k0_zero(float* __restrict__ p, int count) {
    int id = blockIdx.x * 256 + threadIdx.x;
    if (id < count) p[id] = 0.f;
}

// ---- k1: per 8-row tile: QK gemm (64x256), q-phi -> qp(bf16), k-phi -> per-tile max ----
__global__ __launch_bounds__(256) void k1_feat(
    const float* __restrict__ z, const float* __restrict__ Wq, const float* __restrict__ bq,
    const float* __restrict__ Wk, const float* __restrict__ bk,
    const float* __restrict__ proj, const float* __restrict__ tau,
    __hip_bfloat16* __restrict__ qp16, float* __restrict__ blockmax, int N)
{
    __shared__ float zs[512];
    __shared__ float projl[30 * 65];
    __shared__ float dq[8 * 260];     // [nn][h*65+d]
    __shared__ float dk[8 * 260];
    __shared__ float ddq[8 * 120];    // q dd: [nn][h*30+m]
    __shared__ float dgq[32];         // q diag: [nn*4+h]
    __shared__ float kmx[120];        // k max over nn: [h*30+m]

    const int t = threadIdx.x;
    const int tile = blockIdx.x;
    const int n0 = tile * 8;

    for (int i = t; i < 1920; i += 256) projl[(i >> 6) * 65 + (i & 63)] = proj[i];
    for (int i = t; i < 512; i += 256) {
        int nn = i >> 6;
        zs[i] = (n0 + nn < N) ? z[(long)n0 * 64 + i] : 0.f;
    }
    __syncthreads();

    const float dsc = rsqrtf(tau[0]) * DNORM;
    {
        const int c = t;
        float accq[8] = {0,0,0,0,0,0,0,0};
        float acck[8] = {0,0,0,0,0,0,0,0};
        for (int i = 0; i < 64; ++i) {
            float wq = Wq[i * 256 + c];
            float wk = Wk[i * 256 + c];
#pragma unroll
            for (int nn = 0; nn < 8; ++nn) {
                float zv = zs[nn * 64 + i];
                accq[nn] += zv * wq;
                acck[nn] += zv * wk;
            }
        }
        const float bqc = bq[c], bkc = bk[c];
        const int hh = c >> 6, d2 = c & 63;
#pragma unroll
        for (int nn = 0; nn < 8; ++nn) {
            dq[nn * 260 + hh * 65 + d2] = (accq[nn] + bqc) * dsc;
            dk[nn * 260 + hh * 65 + d2] = (acck[nn] + bkc) * dsc;
        }
    }
    __syncthreads();

    if (t < 120) {                       // q-phi
        const int hh = t / 30, m = t % 30;
#pragma unroll
        for (int nn = 0; nn < 8; ++nn) {
            float s = 0.f;
            for (int i = 0; i < 64; ++i) s += dq[nn * 260 + hh * 65 + i] * projl[m * 65 + i];
            ddq[nn * 120 + t] = s;
        }
    }
    if (t >= 128 && t < 248) {           // k-phi + max over rows
        const int tt = t - 128, hh = tt / 30, m = tt % 30;
        float tmax = -3.4e38f;
#pragma unroll
        for (int nn = 0; nn < 8; ++nn) {
            float s = 0.f;
            for (int i = 0; i < 64; ++i) s += dk[nn * 260 + hh * 65 + i] * projl[m * 65 + i];
            tmax = fmaxf(tmax, s);
        }
        kmx[tt] = tmax;
    }
    if (t < 32) {                        // q diag
        const int nn = t >> 2, hh = t & 3;
        float s = 0.f;
        for (int i = 0; i < 64; ++i) { float x = dq[nn * 260 + hh * 65 + i]; s += x * x; }
        dgq[t] = 0.5f * s;
    }
    __syncthreads();

    if (t < 4) {
        float mx = kmx[t * 30];
        for (int m = 1; m < 30; ++m) mx = fmaxf(mx, kmx[t * 30 + m]);
        blockmax[tile * 4 + t] = mx;
    }
    for (int idx = t; idx < 960; idx += 256) {
        int nn = idx / 120, r = idx % 120, hh = r / 30;
        float rmax = ddq[nn * 120 + hh * 30];
        for (int m = 1; m < 30; ++m) rmax = fmaxf(rmax, ddq[nn * 120 + hh * 30 + m]);
        float val = RATIO * (expf(ddq[nn * 120 + r] - dgq[nn * 4 + hh] - rmax) + NEPS);
        if (n0 + nn < N) qp16[(long)tile * 960 + idx] = __float2bfloat16(val);
    }
}

__global__ __launch_bounds__(256) void k1b_redmax(
    const float* __restrict__ blockmax, float* __restrict__ headmax, int ntiles)
{
    __shared__ float red[4 * 256];
    const int t = threadIdx.x;
    float lm[4] = {-3.4e38f, -3.4e38f, -3.4e38f, -3.4e38f};
    for (int i = t; i < ntiles; i += 256) {
#pragma unroll
        for (int hh = 0; hh < 4; ++hh) lm[hh] = fmaxf(lm[hh], blockmax[i * 4 + hh]);
    }
#pragma unroll
    for (int hh = 0; hh < 4; ++hh) red[hh * 256 + t] = lm[hh];
    __syncthreads();
    if (t < 4) {
        float mx = red[t * 256];
        for (int i = 1; i < 256; ++i) mx = fmaxf(mx, red[t * 256 + i]);
        headmax[t] = mx;
    }
}

// ---- k2: 64-row-tiled accumulate of kvs[h,km,d] and kssum[h,km] ----
// 320 threads = 5 waves. Wave wg owns m-range [6wg,6wg+6) x k 0..9 -> akv[60].
// aks: thread t<300 owns (k=t/30, m=t%30) -> 1 reg.
__global__ __launch_bounds__(320) void k2_kvs(
    const float* __restrict__ z, const float* __restrict__ Wk, const float* __restrict__ bk,
    const float* __restrict__ Wv, const float* __restrict__ bv,
    const float* __restrict__ proj, const float* __restrict__ gum,
    const float* __restrict__ tau, const float* __restrict__ headmax,
    float* __restrict__ kvs, float* __restrict__ kssum, int N, int nchunk)
{
    __shared__ float zL[4096];        // [64 rows][64]
    __shared__ float kvL[64 * 66];    // kk, then vv (pad 66: 2-way=free)
    __shared__ float projL[1920];     // [m][64], broadcast-read only
    __shared__ float kpL[64 * 33];    // pad 33 (coprime 32: conflict-free col-write + row-read)
    __shared__ float geL[64 * 12];    // pad 12 (float4-aligned rows)
    __shared__ float diagL[64];

    const int t = threadIdx.x;
    const int h = blockIdx.x >> 7;       // 4 heads x 128 chunks
    const int chunk = blockIdx.x & 127;
    const int n0 = chunk * nchunk;
    const int n1 = (n0 + nchunk < N) ? (n0 + nchunk) : N;
    const float MX = headmax[h];
    const float itau = 1.0f / tau[0];
    const float dsc = rsqrtf(tau[0]) * DNORM;

    const int wg = t >> 6;               // 0..4
    const int lane = t & 63;
    const int mks = t % 30, kks = t / 30; // aks ownership (t<300)

    for (int i = t; i < 1920; i += 320) projL[i] = proj[i];

    float akv[60];
#pragma unroll
    for (int j = 0; j < 60; ++j) akv[j] = 0.f;
    float aks = 0.f;

    const int ntile = (n1 - n0 + 63) >> 6;
    for (int tt = 0; tt < ntile; ++tt) {
        const int nb = n0 + tt * 64;
        __syncthreads();                               // prev E readers done (projL on t0)
        // T0: z tile -> LDS (waves 0-3); gumbel -> geL (wave 4)
        if (t < 256) {
            for (int i = t; i < 4096; i += 256) {
                int rr = i >> 6;
                zL[i] = (nb + rr < n1) ? z[(long)(nb + rr) * 64 + (i & 63)] : 0.f;
            }
        } else {
            const int rr = t - 256;
            const bool va = (nb + rr < n1);
#pragma unroll
            for (int k = 0; k < 10; ++k)
                geL[rr * 12 + k] = va ? expf(gum[(long)(nb + rr) * 40 + h * 10 + k] * itau) : 0.f;
        }
        __syncthreads();
        // T1: kk = (z@Wk_h + bk)*dsc  (waves 0-3: col c=lane, rows wg*16..+16)
        if (t < 256) {
            float acc[16];
#pragma unroll
            for (int r16 = 0; r16 < 16; ++r16) acc[r16] = 0.f;
            const float* Wc = Wk + h * 64 + lane;
#pragma unroll 4
            for (int i = 0; i < 64; ++i) {
                float w = Wc[i * 256];
#pragma unroll
                for (int r16 = 0; r16 < 16; ++r16)
                    acc[r16] += zL[(wg * 16 + r16) * 64 + i] * w;
            }
            const float bb = bk[h * 64 + lane];
#pragma unroll
            for (int r16 = 0; r16 < 16; ++r16)
                kvL[(wg * 16 + r16) * 66 + lane] = (acc[r16] + bb) * dsc;
        }
        __syncthreads();
        // T2: phi (waves 0-3: r=lane, m-chunk=wg) ; diag (wave 4)
        float dd[8];
        if (t < 256) {
            const int m0 = wg * 8;
            const int mcnt = (wg == 3) ? 6 : 8;
#pragma unroll
            for (int mm = 0; mm < 8; ++mm) dd[mm] = 0.f;
#pragma unroll 4
            for (int i = 0; i < 64; ++i) {
                float kk = kvL[lane * 66 + i];
#pragma unroll
                for (int mm = 0; mm < 8; ++mm)
                    if (mm < mcnt) dd[mm] += kk * projL[(m0 + mm) * 64 + i];
            }
        } else {
            const int r = t - 256;
            float s = 0.f;
#pragma unroll 4
            for (int i = 0; i < 64; ++i) { float x = kvL[r * 66 + i]; s += x * x; }
            diagL[r] = 0.5f * s;
        }
        __syncthreads();
        // T3: kp write (conflict-free: bank=(r+m)%32) + vv GEMM into kvL
        if (t < 256) {
            const int m0 = wg * 8;
            const int mcnt = (wg == 3) ? 6 : 8;
            const float dg = diagL[lane];
#pragma unroll
            for (int mm = 0; mm < 8; ++mm)
                if (mm < mcnt)
                    kpL[lane * 33 + m0 + mm] = RATIO * (expf(dd[mm] - dg - MX) + NEPS);
            float acc[16];
#pragma unroll
            for (int r16 = 0; r16 < 16; ++r16) acc[r16] = 0.f;
            const float* Wc = Wv + h * 64 + lane;
#pragma unroll 4
            for (int i = 0; i < 64; ++i) {
                float w = Wc[i * 256];
#pragma unroll
                for (int r16 = 0; r16 < 16; ++r16)
                    acc[r16] += zL[(wg * 16 + r16) * 64 + i] * w;
            }
            const float bb = bv[h * 64 + lane];
#pragma unroll
            for (int r16 = 0; r16 < 16; ++r16)
                kvL[(wg * 16 + r16) * 66 + lane] = acc[r16] + bb;
        }
        __syncthreads();
        // E: accumulate. Per row: 6 kp + 10 ge (2xfloat4+2) + 1 vv reads.
        {
            const int mb = 6 * wg;
            for (int r = 0; r < 64; ++r) {
                float kp6[6];
#pragma unroll
                for (int mm = 0; mm < 6; ++mm) kp6[mm] = kpL[r * 33 + mb + mm];
                float4 ga = *reinterpret_cast<const float4*>(&geL[r * 12]);
                float4 gb = *reinterpret_cast<const float4*>(&geL[r * 12 + 4]);
                float g8 = geL[r * 12 + 8], g9 = geL[r * 12 + 9];
                const float vd = kvL[r * 66 + lane];
                float gv[10];
                gv[0] = ga.x * vd; gv[1] = ga.y * vd; gv[2] = ga.z * vd; gv[3] = ga.w * vd;
                gv[4] = gb.x * vd; gv[5] = gb.y * vd; gv[6] = gb.z * vd; gv[7] = gb.w * vd;
                gv[8] = g8 * vd;   gv[9] = g9 * vd;
#pragma unroll
                for (int k = 0; k < 10; ++k)
#pragma unroll
                    for (int mm = 0; mm < 6; ++mm)
                        akv[k * 6 + mm] += kp6[mm] * gv[k];
                if (t < 300) aks += kpL[r * 33 + mks] * geL[r * 12 + kks];
            }
        }
    }
    // flush
    float* kvh = kvs + h * 19200;
#pragma unroll
    for (int k = 0; k < 10; ++k)
#pragma unroll
        for (int mm = 0; mm < 6; ++mm)
            atomicAdd(&kvh[(k * 30 + 6 * wg + mm) * 64 + lane], akv[k * 6 + mm]);
    if (t < 300) atomicAdd(&kssum[h * 300 + t], aks);
}

// ---- k3: 32-row block; heads sequential (kvs_h in LDS); den+num fused; out = zl@Wo + bo (f32) ----
__global__ __launch_bounds__(512) void k3_out(
    const __hip_bfloat16* __restrict__ qp16, const float* __restrict__ kvs,
    const float* __restrict__ kssum, const float* __restrict__ Wo,
    const float* __restrict__ bo, float* __restrict__ out, int N)
{
    __shared__ alignas(16) float SA[19200];     // kvs_h, later Wo
    __shared__ alignas(16) float zl[32 * 260];  // [r][c] c=h*64+d, pad 260
    __shared__ float qpl[32 * 30];
    __shared__ float idl[32 * 10];
    __shared__ float ksl[300];
    __shared__ alignas(16) float bol[64];

    const int t = threadIdx.x;
    const int n0 = blockIdx.x * 32;
    const int r = t >> 4, d4 = t & 15;          // 32 rows x 16 float4-columns

    for (int h = 0; h < 4; ++h) {
        __syncthreads();                         // A: prev head's readers done
        for (int i = t; i < 19200; i += 512) SA[i] = kvs[h * 19200 + i];
        if (t < 300) ksl[t] = kssum[h * 300 + t];
        for (int i = t; i < 960; i += 512) {
            int rr = i / 30, m = i % 30;
            long n = n0 + rr;
            qpl[i] = (n < N) ? __bfloat162float(qp16[n * 120 + h * 30 + m]) : 1.0f;
        }
        __syncthreads();                         // B: SA/ksl/qpl ready
        if (t < 320) {
            const int rr = t / 10, kk = t % 10;
            float s = 0.f;
#pragma unroll
            for (int m = 0; m < 30; ++m) s += qpl[rr * 30 + m] * ksl[kk * 30 + m];
            idl[t] = 1.0f / s;
        }
        __syncthreads();                         // C: idl ready
        {
            const float* qr = &qpl[r * 30];
            const float* ir = &idl[r * 10];
            const float4* SA4 = reinterpret_cast<const float4*>(SA);
            float sx = 0.f, sy = 0.f, sz = 0.f, sw = 0.f;
#pragma unroll
            for (int kk = 0; kk < 10; ++kk) {
                float ax = 0.f, ay = 0.f, az = 0.f, aw = 0.f;
#pragma unroll
                for (int m = 0; m < 30; ++m) {
                    float4 b = SA4[(kk * 30 + m) * 16 + d4];
                    float q = qr[m];
                    ax += q * b.x; ay += q * b.y; az += q * b.z; aw += q * b.w;
                }
                float w = ir[kk];
                sx += ax * w; sy += ay * w; sz += az * w; sw += aw * w;
            }
            float4 zv; zv.x = 0.1f * sx; zv.y = 0.1f * sy; zv.z = 0.1f * sz; zv.w = 0.1f * sw;
            reinterpret_cast<float4*>(zl)[r * 65 + h * 16 + d4] = zv;
        }
    }
    __syncthreads();                             // D: zl complete, SA readers done
    for (int i = t; i < 16384; i += 512) SA[i] = Wo[i];
    if (t < 64) bol[t] = bo[t];
    __syncthreads();
    {
        const float4* W4 = reinterpret_cast<const float4*>(SA);
        float4 o = reinterpret_cast<const float4*>(bol)[d4];
        const float* zr = &zl[r * 260];
#pragma unroll 8
        for (int c = 0; c < 256; ++c) {
            float zv = zr[c];
            float4 w = W4[c * 16 + d4];
            o.x += zv * w.x; o.y += zv * w.y; o.z += zv * w.z; o.w += zv * w.w;
        }
        long n = n0 + r;
        if (n < N) {
            *reinterpret_cast<float4*>(out + n * 64 + d4 * 4) = o;
        }
    }
}

extern "C" void kernel_launch(void* const* d_in, const int* in_sizes, int n_in,
                              void* d_out, int out_size, void* d_ws, size_t ws_size,
                              hipStream_t stream)
{
    const float* z    = (const float*)d_in[0];
    const float* Wq   = (const float*)d_in[1];
    const float* bq   = (const float*)d_in[2];
    const float* Wk   = (const float*)d_in[3];
    const float* bk   = (const float*)d_in[4];
    const float* Wv   = (const float*)d_in[5];
    const float* bv   = (const float*)d_in[6];
    const float* Wo   = (const float*)d_in[7];
    const float* bo   = (const float*)d_in[8];
    const float* proj = (const float*)d_in[9];
    const float* gum  = (const float*)d_in[10];
    const float* tau  = (const float*)d_in[11];
    float* out = (float*)d_out;

    const int N = in_sizes[0] / 64;          // 50000
    const int ntiles = (N + 7) / 8;          // 6250
    const int nchunk = (N + 127) / 128;      // 391
    const int nblk3  = (N + 31) / 32;        // 1563

    // ws layout: qp16 (bf16) | kvs | kssum | headmax | blockmax  (~12.4 MB)
    char* wsb = (char*)d_ws;
    __hip_bfloat16* qp16 = (__hip_bfloat16*)wsb;
    size_t qpB = ((size_t)N * 120 * 2 + 255) & ~(size_t)255;
    float* kvs      = (float*)(wsb + qpB);
    float* kssum    = kvs + 76800;
    float* headmax  = kssum + 1200;
    float* blockmax = headmax + 4;

    k0_zero<<<dim3((78000 + 255) / 256), dim3(256), 0, stream>>>(kvs, 78000);
    k1_feat<<<dim3(ntiles), dim3(256), 0, stream>>>(z, Wq, bq, Wk, bk, proj, tau,
                                                    qp16, blockmax, N);
    k1b_redmax<<<dim3(1), dim3(256), 0, stream>>>(blockmax, headmax, ntiles);
    k2_kvs<<<dim3(512), dim3(320), 0, stream>>>(z, Wk, bk, Wv, bv, proj, gum, tau,
                                                headmax, kvs, kssum, N, nchunk);
    k3_out<<<dim3(nblk3), dim3(512), 0, stream>>>(qp16, kvs, kssum, Wo, bo, out, N);
}

// Round 5
// 776.523 us; speedup vs baseline: 9.0061x; 1.1605x over previous
//
#include <hip/hip_runtime.h>
#include <hip/hip_bf16.h>

// NodeFormerConv: Performer/Gumbel attention. fp32 math, fp32 output.
//   k0   zero kvs[4][300][64] + kssum[4][300]
//   k1   QKV gemm (64x768 per 8-row tile): qp16 (bf16), v16 (bf16), argk=ddk-diagk (f32),
//        per-tile k-max -> blockmax
//   k1b  blockmax -> headmax[4]
//   k2   MFMA accumulate: per 64-row tile build P[320x72]bf16 (kp*ge) and Vt[80x72]bf16
//        (V^T + ones row 64), then kvs[300x64] += P@V, kssum += P@1 (ones col) per head.
//   k3   per 32-row block: heads sequential; den+num fused; out = zl@Wo + bo (f32)
// ws: qp16 12MB | v16 25.6MB | argk 24MB | kvs/kssum/headmax/blockmax (~62MB)

#define NEPS  1e-6f
#define RATIO 0.18257418583505536f   // 1/sqrt(30)
#define DNORM 0.35355339059327378f   // 64^-0.25

typedef __attribute__((ext_vector_type(8))) short short8;
typedef __attribute__((ext_vector_type(4))) float floatx4;

__device__ inline unsigned short f2bf(float x) {
    __hip_bfloat16 b = __float2bfloat16(x);
    return __builtin_bit_cast(unsigned short, b);
}

__global__ __launch_bounds__(256) void k0_zero(float* __restrict__ p, int count) {
    int id = blockIdx.x * 256 + threadIdx.x;
    if (id < count) p[id] = 0.f;
}

// ---- k1: per 8-row tile: QKV gemm, q-phi -> qp16, k-phi -> argk + per-tile max, v -> v16 ----
__global__ __launch_bounds__(256) void k1_feat(
    const float* __restrict__ z, const float* __restrict__ Wq, const float* __restrict__ bq,
    const float* __restrict__ Wk, const float* __restrict__ bk,
    const float* __restrict__ Wv, const float* __restrict__ bv,
    const float* __restrict__ proj, const float* __restrict__ tau,
    __hip_bfloat16* __restrict__ qp16, __hip_bfloat16* __restrict__ v16,
    float* __restrict__ argk, float* __restrict__ blockmax, int N)
{
    __shared__ float zs[512];
    __shared__ float projl[30 * 65];
    __shared__ float dq[8 * 260];     // [nn][h*65+d]
    __shared__ float dk[8 * 260];
    __shared__ float ddq[8 * 120];    // [nn][h*30+m]
    __shared__ float ddk[8 * 120];
    __shared__ float dgq[32];         // [nn*4+h]
    __shared__ float dgk[32];
    __shared__ float kmx[120];        // k max over nn: [h*30+m]

    const int t = threadIdx.x;
    const int tile = blockIdx.x;
    const int n0 = tile * 8;

    for (int i = t; i < 1920; i += 256) projl[(i >> 6) * 65 + (i & 63)] = proj[i];
    for (int i = t; i < 512; i += 256) {
        int nn = i >> 6;
        zs[i] = (n0 + nn < N) ? z[(long)n0 * 64 + i] : 0.f;
    }
    __syncthreads();

    const float dsc = rsqrtf(tau[0]) * DNORM;
    {
        const int c = t;
        float accq[8] = {0,0,0,0,0,0,0,0};
        float acck[8] = {0,0,0,0,0,0,0,0};
        float accv[8] = {0,0,0,0,0,0,0,0};
        for (int i = 0; i < 64; ++i) {
            float wq = Wq[i * 256 + c];
            float wk = Wk[i * 256 + c];
            float wv = Wv[i * 256 + c];
#pragma unroll
            for (int nn = 0; nn < 8; ++nn) {
                float zv = zs[nn * 64 + i];
                accq[nn] += zv * wq;
                acck[nn] += zv * wk;
                accv[nn] += zv * wv;
            }
        }
        const float bqc = bq[c], bkc = bk[c], bvc = bv[c];
        const int hh = c >> 6, d2 = c & 63;
#pragma unroll
        for (int nn = 0; nn < 8; ++nn) {
            dq[nn * 260 + hh * 65 + d2] = (accq[nn] + bqc) * dsc;
            dk[nn * 260 + hh * 65 + d2] = (acck[nn] + bkc) * dsc;
            if (n0 + nn < N)
                v16[(long)(n0 + nn) * 256 + c] = __float2bfloat16(accv[nn] + bvc);
        }
    }
    __syncthreads();

    if (t < 120) {                       // q-phi
        const int hh = t / 30, m = t % 30;
#pragma unroll
        for (int nn = 0; nn < 8; ++nn) {
            float s = 0.f;
            for (int i = 0; i < 64; ++i) s += dq[nn * 260 + hh * 65 + i] * projl[m * 65 + i];
            ddq[nn * 120 + t] = s;
        }
    }
    if (t >= 128 && t < 248) {           // k-phi -> ddk + max over rows
        const int tt = t - 128, hh = tt / 30, m = tt % 30;
        float tmax = -3.4e38f;
#pragma unroll
        for (int nn = 0; nn < 8; ++nn) {
            float s = 0.f;
            for (int i = 0; i < 64; ++i) s += dk[nn * 260 + hh * 65 + i] * projl[m * 65 + i];
            ddk[nn * 120 + tt] = s;
            tmax = fmaxf(tmax, s);
        }
        kmx[tt] = tmax;
    }
    if (t >= 120 && t < 124) {           // q-diag (disjoint threads)
#pragma unroll
        for (int j = 0; j < 8; ++j) {
            int idx = (t - 120) * 8 + j;
            int nn = idx >> 2, hh = idx & 3;
            float s = 0.f;
            for (int i = 0; i < 64; ++i) { float x = dq[nn * 260 + hh * 65 + i]; s += x * x; }
            dgq[idx] = 0.5f * s;
        }
    }
    if (t >= 124 && t < 128) {           // k-diag
#pragma unroll
        for (int j = 0; j < 8; ++j) {
            int idx = (t - 124) * 8 + j;
            int nn = idx >> 2, hh = idx & 3;
            float s = 0.f;
            for (int i = 0; i < 64; ++i) { float x = dk[nn * 260 + hh * 65 + i]; s += x * x; }
            dgk[idx] = 0.5f * s;
        }
    }
    __syncthreads();

    if (t < 4) {
        float mx = kmx[t * 30];
        for (int m = 1; m < 30; ++m) mx = fmaxf(mx, kmx[t * 30 + m]);
        blockmax[tile * 4 + t] = mx;
    }
    for (int idx = t; idx < 960; idx += 256) {
        int nn = idx / 120, r = idx % 120, hh = r / 30;
        if (n0 + nn < N) {
            float rmax = ddq[nn * 120 + hh * 30];
            for (int m = 1; m < 30; ++m) rmax = fmaxf(rmax, ddq[nn * 120 + hh * 30 + m]);
            float val = RATIO * (expf(ddq[nn * 120 + r] - dgq[nn * 4 + hh] - rmax) + NEPS);
            qp16[(long)tile * 960 + idx] = __float2bfloat16(val);
            argk[(long)tile * 960 + idx] = ddk[nn * 120 + r] - dgk[nn * 4 + hh];
        }
    }
}

__global__ __launch_bounds__(256) void k1b_redmax(
    const float* __restrict__ blockmax, float* __restrict__ headmax, int ntiles)
{
    __shared__ float red[4 * 256];
    const int t = threadIdx.x;
    float lm[4] = {-3.4e38f, -3.4e38f, -3.4e38f, -3.4e38f};
    for (int i = t; i < ntiles; i += 256) {
#pragma unroll
        for (int hh = 0; hh < 4; ++hh) lm[hh] = fmaxf(lm[hh], blockmax[i * 4 + hh]);
    }
#pragma unroll
    for (int hh = 0; hh < 4; ++hh) red[hh * 256 + t] = lm[hh];
    __syncthreads();
    if (t < 4) {
        float mx = red[t * 256];
        for (int i = 1; i < 256; ++i) mx = fmaxf(mx, red[t * 256 + i]);
        headmax[t] = mx;
    }
}

// ---- k2: MFMA accumulate. Per (head, chunk): 64-row tiles.
// P[320 km][72 n] bf16 (stride 72 -> 144B rows, 16B-aligned frags),
// Vt[80 d][72 n] bf16 with row 64 = ones (kssum column).
// 4 waves; wave w owns km-tiles 5w..5w+4 x 5 d-tiles; acc[5][5] f32x4.
__global__ __launch_bounds__(256) void k2_kvs(
    const float* __restrict__ argk, const float* __restrict__ gum,
    const __hip_bfloat16* __restrict__ v16, const float* __restrict__ tau,
    const float* __restrict__ headmax,
    float* __restrict__ kvs, float* __restrict__ kssum, int N, int nchunk)
{
    __shared__ alignas(16) unsigned short P[320 * 72];
    __shared__ alignas(16) unsigned short Vt[80 * 72];
    __shared__ float kpL[64 * 33];   // stride 33: conflict-free build reads
    __shared__ float geL[64 * 13];   // stride 13: conflict-free build reads

    const int t = threadIdx.x;
    const int h = blockIdx.x >> 7;       // 4 heads x 128 chunks
    const int chunk = blockIdx.x & 127;
    const int n0 = chunk * nchunk;
    const int n1 = (n0 + nchunk < N) ? (n0 + nchunk) : N;
    const float MX = headmax[h];
    const float itau = 1.0f / tau[0];
    const int wave = t >> 6, lane = t & 63;

    floatx4 acc[5][5];
#pragma unroll
    for (int q = 0; q < 5; ++q)
#pragma unroll
        for (int dt = 0; dt < 5; ++dt) acc[q][dt] = floatx4{0.f, 0.f, 0.f, 0.f};

    // ones row (kssum column), zero pad rows 65-79 (outputs discarded, hygiene)
    if (t < 64) Vt[64 * 72 + t] = f2bf(1.0f);
    for (int i = t; i < 15 * 72; i += 256) Vt[65 * 72 + i] = 0;

    const int ntile = (n1 - n0 + 63) >> 6;
    for (int tt = 0; tt < ntile; ++tt) {
        const int nb = n0 + tt * 64;
        __syncthreads();                               // B0: prev MFMA readers done
        // stage kp (exp), ge, Vt
        for (int i = t; i < 1920; i += 256) {
            int r = i / 30, m = i % 30;
            kpL[r * 33 + m] = (nb + r < n1)
                ? RATIO * (expf(argk[(long)(nb + r) * 120 + h * 30 + m] - MX) + NEPS) : 0.f;
        }
        for (int i = t; i < 640; i += 256) {
            int r = i / 10, k = i % 10;
            geL[r * 13 + k] = (nb + r < n1)
                ? expf(gum[(long)(nb + r) * 40 + h * 10 + k] * itau) : 0.f;
        }
        for (int i = t; i < 2048; i += 256) {          // uint = 2 bf16, coalesced
            int n = i >> 5, dp = (i & 31) * 2;
            unsigned int u = (nb + n < n1)
                ? *reinterpret_cast<const unsigned int*>(v16 + (long)(nb + n) * 256 + h * 64 + dp)
                : 0u;
            Vt[dp * 72 + n] = (unsigned short)(u & 0xffffu);
            Vt[(dp + 1) * 72 + n] = (unsigned short)(u >> 16);
        }
        __syncthreads();                               // B1: staging ready
        // build P[km][n] = kp[n][m] * ge[n][k]  (km = k*30+m; pad km>=300 -> 0)
        for (int i = t; i < 20480; i += 256) {
            int km = i >> 6, n = i & 63;
            float val = 0.f;
            if (km < 300) {
                int m = km % 30, k = km / 30;
                val = kpL[n * 33 + m] * geL[n * 13 + k];
            }
            P[km * 72 + n] = f2bf(val);
        }
        __syncthreads();                               // B2: P ready
        // MFMA: D[304 km x 80 d'] += P @ Vt^T  (d'=64 is kssum)
#pragma unroll
        for (int nh = 0; nh < 2; ++nh) {
            const int ko = nh * 32 + (lane >> 4) * 8;
            short8 b[5];
#pragma unroll
            for (int dt = 0; dt < 5; ++dt)
                b[dt] = *reinterpret_cast<const short8*>(&Vt[(dt * 16 + (lane & 15)) * 72 + ko]);
#pragma unroll
            for (int q = 0; q < 5; ++q) {
                short8 a = *reinterpret_cast<const short8*>(
                    &P[((wave * 5 + q) * 16 + (lane & 15)) * 72 + ko]);
#pragma unroll
                for (int dt = 0; dt < 5; ++dt)
                    acc[q][dt] = __builtin_amdgcn_mfma_f32_16x16x32_bf16(a, b[dt], acc[q][dt], 0, 0, 0);
            }
        }
    }

    // flush: D[row=(lane>>4)*4+r][col=lane&15]
    float* kvh = kvs + h * 19200;
#pragma unroll
    for (int q = 0; q < 5; ++q) {
        const int kmb = (wave * 5 + q) * 16 + (lane >> 4) * 4;
#pragma unroll
        for (int r = 0; r < 4; ++r) {
            const int km = kmb + r;
            if (km < 300) {
#pragma unroll
                for (int dt = 0; dt < 4; ++dt)
                    atomicAdd(&kvh[km * 64 + dt * 16 + (lane & 15)], acc[q][dt][r]);
                if ((lane & 15) == 0)
                    atomicAdd(&kssum[h * 300 + km], acc[q][4][r]);
            }
        }
    }
}

// ---- k3: 32-row block; heads sequential (kvs_h in LDS); den+num fused; out = zl@Wo + bo (f32) ----
__global__ __launch_bounds__(512) void k3_out(
    const __hip_bfloat16* __restrict__ qp16, const float* __restrict__ kvs,
    const float* __restrict__ kssum, const float* __restrict__ Wo,
    const float* __restrict__ bo, float* __restrict__ out, int N)
{
    __shared__ alignas(16) float SA[19200];     // kvs_h, later Wo
    __shared__ alignas(16) float zl[32 * 260];  // [r][c] c=h*64+d, pad 260
    __shared__ float qpl[32 * 30];
    __shared__ float idl[32 * 10];
    __shared__ float ksl[300];
    __shared__ alignas(16) float bol[64];

    const int t = threadIdx.x;
    const int n0 = blockIdx.x * 32;
    const int r = t >> 4, d4 = t & 15;          // 32 rows x 16 float4-columns

    for (int h = 0; h < 4; ++h) {
        __syncthreads();                         // A: prev head's readers done
        for (int i = t; i < 19200; i += 512) SA[i] = kvs[h * 19200 + i];
        if (t < 300) ksl[t] = kssum[h * 300 + t];
        for (int i = t; i < 960; i += 512) {
            int rr = i / 30, m = i % 30;
            long n = n0 + rr;
            qpl[i] = (n < N) ? __bfloat162float(qp16[n * 120 + h * 30 + m]) : 1.0f;
        }
        __syncthreads();                         // B: SA/ksl/qpl ready
        if (t < 320) {
            const int rr = t / 10, kk = t % 10;
            float s = 0.f;
#pragma unroll
            for (int m = 0; m < 30; ++m) s += qpl[rr * 30 + m] * ksl[kk * 30 + m];
            idl[t] = 1.0f / s;
        }
        __syncthreads();                         // C: idl ready
        {
            const float* qr = &qpl[r * 30];
            const float* ir = &idl[r * 10];
            const float4* SA4 = reinterpret_cast<const float4*>(SA);
            float sx = 0.f, sy = 0.f, sz = 0.f, sw = 0.f;
#pragma unroll
            for (int kk = 0; kk < 10; ++kk) {
                float ax = 0.f, ay = 0.f, az = 0.f, aw = 0.f;
#pragma unroll
                for (int m = 0; m < 30; ++m) {
                    float4 b = SA4[(kk * 30 + m) * 16 + d4];
                    float q = qr[m];
                    ax += q * b.x; ay += q * b.y; az += q * b.z; aw += q * b.w;
                }
                float w = ir[kk];
                sx += ax * w; sy += ay * w; sz += az * w; sw += aw * w;
            }
            float4 zv; zv.x = 0.1f * sx; zv.y = 0.1f * sy; zv.z = 0.1f * sz; zv.w = 0.1f * sw;
            reinterpret_cast<float4*>(zl)[r * 65 + h * 16 + d4] = zv;
        }
    }
    __syncthreads();                             // D: zl complete, SA readers done
    for (int i = t; i < 16384; i += 512) SA[i] = Wo[i];
    if (t < 64) bol[t] = bo[t];
    __syncthreads();
    {
        const float4* W4 = reinterpret_cast<const float4*>(SA);
        float4 o = reinterpret_cast<const float4*>(bol)[d4];
        const float* zr = &zl[r * 260];
#pragma unroll 8
        for (int c = 0; c < 256; ++c) {
            float zv = zr[c];
            float4 w = W4[c * 16 + d4];
            o.x += zv * w.x; o.y += zv * w.y; o.z += zv * w.z; o.w += zv * w.w;
        }
        long n = n0 + r;
        if (n < N) {
            *reinterpret_cast<float4*>(out + n * 64 + d4 * 4) = o;
        }
    }
}

extern "C" void kernel_launch(void* const* d_in, const int* in_sizes, int n_in,
                              void* d_out, int out_size, void* d_ws, size_t ws_size,
                              hipStream_t stream)
{
    const float* z    = (const float*)d_in[0];
    const float* Wq   = (const float*)d_in[1];
    const float* bq   = (const float*)d_in[2];
    const float* Wk   = (const float*)d_in[3];
    const float* bk   = (const float*)d_in[4];
    const float* Wv   = (const float*)d_in[5];
    const float* bv   = (const float*)d_in[6];
    const float* Wo   = (const float*)d_in[7];
    const float* bo   = (const float*)d_in[8];
    const float* proj = (const float*)d_in[9];
    const float* gum  = (const float*)d_in[10];
    const float* tau  = (const float*)d_in[11];
    float* out = (float*)d_out;

    const int N = in_sizes[0] / 64;          // 50000
    const int ntiles = (N + 7) / 8;          // 6250
    const int nchunk = (N + 127) / 128;      // 391
    const int nblk3  = (N + 31) / 32;        // 1563

    // ws layout: qp16 | v16 | argk | kvs | kssum | headmax | blockmax (~62MB)
    char* wsb = (char*)d_ws;
    __hip_bfloat16* qp16 = (__hip_bfloat16*)wsb;
    size_t off = ((size_t)N * 120 * 2 + 255) & ~(size_t)255;
    __hip_bfloat16* v16 = (__hip_bfloat16*)(wsb + off);
    off += ((size_t)N * 256 * 2 + 255) & ~(size_t)255;
    float* argk = (float*)(wsb + off);
    off += ((size_t)N * 120 * 4 + 255) & ~(size_t)255;
    float* kvs      = (float*)(wsb + off);
    float* kssum    = kvs + 76800;
    float* headmax  = kssum + 1200;
    float* blockmax = headmax + 4;

    k0_zero<<<dim3((78000 + 255) / 256), dim3(256), 0, stream>>>(kvs, 78000);
    k1_feat<<<dim3(ntiles), dim3(256), 0, stream>>>(z, Wq, bq, Wk, bk, Wv, bv, proj, tau,
                                                    qp16, v16, argk, blockmax, N);
    k1b_redmax<<<dim3(1), dim3(256), 0, stream>>>(blockmax, headmax, ntiles);
    k2_kvs<<<dim3(512), dim3(256), 0, stream>>>(argk, gum, v16, tau, headmax,
                                                kvs, kssum, N, nchunk);
    k3_out<<<dim3(nblk3), dim3(512), 0, stream>>>(qp16, kvs, kssum, Wo, bo, out, N);
}

// Round 6
// 547.702 us; speedup vs baseline: 12.7687x; 1.4178x over previous
//
#include <hip/hip_runtime.h>
#include <hip/hip_bf16.h>

// NodeFormerConv: Performer/Gumbel attention. fp32-equivalent math, fp32 output.
//   k_prep zero-cost: split Wq|Wk|Wv and proj into MFMA-fragment-ordered hi/lo bf16
//   k0   zero kvs[4][300][64] + kssum[4][300]
//   k1   per 16-row tile, MFMA (hi/lo split, 3-pass): QKV gemm -> qd/kd f32 LDS + v16;
//        phi gemm -> ddq/ddk; diag; exp -> qp16, argk, blockmax
//   k1b  blockmax -> headmax[4]
//   k2   MFMA accumulate: P[320x72]bf16 (kp*ge), Vt[80x72]bf16 (+ones row) ->
//        kvs[300x64] += P@V, kssum += P@1 per head
//   k3   per 32-row block: heads sequential; den+num fused; out = zl@Wo + bo (f32)
// ws: qp16 12MB | v16 25.6MB | argk 24MB | kvs/kssum/headmax/blockmax | Wf/Pf frags (~62MB)

#define NEPS  1e-6f
#define RATIO 0.18257418583505536f   // 1/sqrt(30)
#define DNORM 0.35355339059327378f   // 64^-0.25

typedef __attribute__((ext_vector_type(8))) short short8;
typedef __attribute__((ext_vector_type(4))) float floatx4;

__device__ inline unsigned short f2bf(float x) {
    __hip_bfloat16 b = __float2bfloat16(x);
    return __builtin_bit_cast(unsigned short, b);
}
__device__ inline float bf2f(unsigned short h) {
    return __builtin_bit_cast(float, (unsigned int)h << 16);
}
__device__ inline void split2(float v, unsigned short& hi, unsigned short& lo) {
    unsigned short h = f2bf(v);
    hi = h; lo = f2bf(v - bf2f(h));
}

__global__ __launch_bounds__(256) void k0_zero(float* __restrict__ p, int count) {
    int id = blockIdx.x * 256 + threadIdx.x;
    if (id < count) p[id] = 0.f;
}

// ---- k_prep: fragment-ordered hi/lo split of W (64x768) and proj (30x64, pad 32) ----
// Wf layout: [(ct*2+ks)*512 + lane*8 + j], col=ct*16+(lane&15), k=ks*32+(lane>>4)*8+j
__global__ __launch_bounds__(256) void k_prep(
    const float* __restrict__ Wq, const float* __restrict__ Wk, const float* __restrict__ Wv,
    const float* __restrict__ proj,
    unsigned short* __restrict__ Wfh, unsigned short* __restrict__ Wfl,
    unsigned short* __restrict__ Pfh, unsigned short* __restrict__ Pfl)
{
    const int b = blockIdx.x, t = threadIdx.x;
    if (b < 24) {
        const int slot = b * 256 + t;           // (ct*2+ks)*64 + lane
        const int lane = slot & 63;
        const int ctks = slot >> 6;
        const int ct = ctks >> 1, ks = ctks & 1;
        const int col = ct * 16 + (lane & 15);
        const int k0 = ks * 32 + (lane >> 4) * 8;
        const float* W = (col < 256) ? Wq : (col < 512) ? Wk : Wv;
        const int cm = col & 255;
#pragma unroll
        for (int j = 0; j < 8; ++j) {
            float w = W[(k0 + j) * 256 + cm];
            unsigned short hi, lo; split2(w, hi, lo);
            Wfh[slot * 8 + j] = hi;
            Wfl[slot * 8 + j] = lo;
        }
    } else {                                    // proj frags (exactly 256 threads)
        const int lane = t & 63;
        const int ctks = t >> 6;                // ct2*2+ks
        const int ct2 = ctks >> 1, ks = ctks & 1;
        const int m = ct2 * 16 + (lane & 15);
        const int k0 = ks * 32 + (lane >> 4) * 8;
#pragma unroll
        for (int j = 0; j < 8; ++j) {
            float p = (m < 30) ? proj[m * 64 + k0 + j] : 0.f;
            unsigned short hi, lo; split2(p, hi, lo);
            Pfh[t * 8 + j] = hi;
            Pfl[t * 8 + j] = lo;
        }
    }
}

// ---- k1: per 16-row tile, MFMA QKV + phi (hi/lo 3-pass) ----
__global__ __launch_bounds__(256) void k1_feat(
    const float* __restrict__ z,
    const float* __restrict__ bq, const float* __restrict__ bk, const float* __restrict__ bv,
    const unsigned short* __restrict__ Wfh, const unsigned short* __restrict__ Wfl,
    const unsigned short* __restrict__ Pfh, const unsigned short* __restrict__ Pfl,
    const float* __restrict__ tau,
    __hip_bfloat16* __restrict__ qp16, __hip_bfloat16* __restrict__ v16,
    float* __restrict__ argk, float* __restrict__ blockmax, int N)
{
    __shared__ alignas(16) unsigned short zh[16 * 72];  // stride 72: 2-way (free)
    __shared__ alignas(16) unsigned short zl_[16 * 72];
    __shared__ alignas(16) float qd[16 * 264];          // [row][h*64+d]
    __shared__ alignas(16) float kd[16 * 264];
    __shared__ float ddq[16 * 128];                     // [row][h*32+m]
    __shared__ float ddk[16 * 128];
    __shared__ float dgq[64], dgk[64];                  // [h*16+row]
    __shared__ float qmx[64], kmx[64];                  // per-(h,row) maxes

    const int t = threadIdx.x;
    const int n0 = blockIdx.x * 16;
    const int wave = t >> 6, lane = t & 63;
    const float dsc = rsqrtf(tau[0]) * DNORM;

    // P0: load z rows, split hi/lo
    for (int i = t; i < 1024; i += 256) {
        int r = i >> 6, c = i & 63;
        float v = (n0 + r < N) ? z[(long)(n0 + r) * 64 + c] : 0.f;
        unsigned short hi, lo; split2(v, hi, lo);
        zh[r * 72 + c] = hi;
        zl_[r * 72 + c] = lo;
    }
    __syncthreads();

    // P1: QKV GEMM. wave w: col-tiles 12w..12w+11 (cols 192w..192w+191)
    {
        const int abase = (lane & 15) * 72 + (lane >> 4) * 8;
        short8 ah0 = *reinterpret_cast<const short8*>(&zh[abase]);
        short8 ah1 = *reinterpret_cast<const short8*>(&zh[abase + 32]);
        short8 al0 = *reinterpret_cast<const short8*>(&zl_[abase]);
        short8 al1 = *reinterpret_cast<const short8*>(&zl_[abase + 32]);
        const int row0 = (lane >> 4) * 4;
#pragma unroll 2
        for (int ci = 0; ci < 12; ++ci) {
            const int ct = wave * 12 + ci;
            short8 bh0 = *reinterpret_cast<const short8*>(&Wfh[(ct * 2 + 0) * 512 + lane * 8]);
            short8 bh1 = *reinterpret_cast<const short8*>(&Wfh[(ct * 2 + 1) * 512 + lane * 8]);
            short8 bl0 = *reinterpret_cast<const short8*>(&Wfl[(ct * 2 + 0) * 512 + lane * 8]);
            short8 bl1 = *reinterpret_cast<const short8*>(&Wfl[(ct * 2 + 1) * 512 + lane * 8]);
            floatx4 acc = floatx4{0.f, 0.f, 0.f, 0.f};
            acc = __builtin_amdgcn_mfma_f32_16x16x32_bf16(ah0, bh0, acc, 0, 0, 0);
            acc = __builtin_amdgcn_mfma_f32_16x16x32_bf16(ah1, bh1, acc, 0, 0, 0);
            acc = __builtin_amdgcn_mfma_f32_16x16x32_bf16(ah0, bl0, acc, 0, 0, 0);
            acc = __builtin_amdgcn_mfma_f32_16x16x32_bf16(ah1, bl1, acc, 0, 0, 0);
            acc = __builtin_amdgcn_mfma_f32_16x16x32_bf16(al0, bh0, acc, 0, 0, 0);
            acc = __builtin_amdgcn_mfma_f32_16x16x32_bf16(al1, bh1, acc, 0, 0, 0);
            const int c = ct * 16 + (lane & 15);
            if (c < 256) {
                const float bb = bq[c];
#pragma unroll
                for (int r = 0; r < 4; ++r) qd[(row0 + r) * 264 + c] = (acc[r] + bb) * dsc;
            } else if (c < 512) {
                const float bb = bk[c - 256];
#pragma unroll
                for (int r = 0; r < 4; ++r) kd[(row0 + r) * 264 + (c - 256)] = (acc[r] + bb) * dsc;
            } else {
                const float bb = bv[c - 512];
#pragma unroll
                for (int r = 0; r < 4; ++r)
                    if (n0 + row0 + r < N)
                        v16[(long)(n0 + row0 + r) * 256 + (c - 512)] = __float2bfloat16(acc[r] + bb);
            }
        }
    }
    __syncthreads();

    // P2: phi MFMA (wave w: head w, sides q/k) + diag (t<128, reads stable qd/kd)
    {
        short8 pbh[2][2], pbl[2][2];   // [ct2][ks]
#pragma unroll
        for (int ct2 = 0; ct2 < 2; ++ct2)
#pragma unroll
            for (int ks = 0; ks < 2; ++ks) {
                pbh[ct2][ks] = *reinterpret_cast<const short8*>(&Pfh[(ct2 * 2 + ks) * 512 + lane * 8]);
                pbl[ct2][ks] = *reinterpret_cast<const short8*>(&Pfl[(ct2 * 2 + ks) * 512 + lane * 8]);
            }
        const int h = wave;
        const int row0 = (lane >> 4) * 4;
#pragma unroll
        for (int side = 0; side < 2; ++side) {
            const float* dat = side ? kd : qd;
            float* dd = side ? ddk : ddq;
            const int rbase = (lane & 15) * 264 + h * 64 + (lane >> 4) * 8;
            float xv[8], yv[8];
            {
                float4 x0 = *reinterpret_cast<const float4*>(&dat[rbase]);
                float4 x1 = *reinterpret_cast<const float4*>(&dat[rbase + 4]);
                float4 y0 = *reinterpret_cast<const float4*>(&dat[rbase + 32]);
                float4 y1 = *reinterpret_cast<const float4*>(&dat[rbase + 36]);
                xv[0]=x0.x; xv[1]=x0.y; xv[2]=x0.z; xv[3]=x0.w;
                xv[4]=x1.x; xv[5]=x1.y; xv[6]=x1.z; xv[7]=x1.w;
                yv[0]=y0.x; yv[1]=y0.y; yv[2]=y0.z; yv[3]=y0.w;
                yv[4]=y1.x; yv[5]=y1.y; yv[6]=y1.z; yv[7]=y1.w;
            }
            short8 ah0, al0, ah1, al1;
#pragma unroll
            for (int j = 0; j < 8; ++j) {
                unsigned short hi, lo;
                split2(xv[j], hi, lo); ah0[j] = (short)hi; al0[j] = (short)lo;
                split2(yv[j], hi, lo); ah1[j] = (short)hi; al1[j] = (short)lo;
            }
#pragma unroll
            for (int ct2 = 0; ct2 < 2; ++ct2) {
                floatx4 acc = floatx4{0.f, 0.f, 0.f, 0.f};
                acc = __builtin_amdgcn_mfma_f32_16x16x32_bf16(ah0, pbh[ct2][0], acc, 0, 0, 0);
                acc = __builtin_amdgcn_mfma_f32_16x16x32_bf16(ah1, pbh[ct2][1], acc, 0, 0, 0);
                acc = __builtin_amdgcn_mfma_f32_16x16x32_bf16(ah0, pbl[ct2][0], acc, 0, 0, 0);
                acc = __builtin_amdgcn_mfma_f32_16x16x32_bf16(ah1, pbl[ct2][1], acc, 0, 0, 0);
                acc = __builtin_amdgcn_mfma_f32_16x16x32_bf16(al0, pbh[ct2][0], acc, 0, 0, 0);
                acc = __builtin_amdgcn_mfma_f32_16x16x32_bf16(al1, pbh[ct2][1], acc, 0, 0, 0);
#pragma unroll
                for (int r = 0; r < 4; ++r)
                    dd[(row0 + r) * 128 + h * 32 + ct2 * 16 + (lane & 15)] = acc[r];
            }
        }
    }
    if (t < 128) {                    // diag: (side, h, row)
        const int h = t >> 5, row = (t >> 1) & 15, side = t & 1;
        const float* dat = side ? kd : qd;
        float s = 0.f;
        for (int d = 0; d < 64; ++d) { float x = dat[row * 264 + h * 64 + d]; s += x * x; }
        (side ? dgk : dgq)[h * 16 + row] = 0.5f * s;
    }
    __syncthreads();

    // P3a: per-(h,row) maxes
    if (t < 64) {
        const int h = t >> 4, row = t & 15;
        float mx = ddq[row * 128 + h * 32];
        for (int m = 1; m < 30; ++m) mx = fmaxf(mx, ddq[row * 128 + h * 32 + m]);
        qmx[t] = mx;
    } else if (t < 128) {
        const int u = t - 64, h = u >> 4, row = u & 15;
        float mx = -3.4e38f;
        if (n0 + row < N)
            for (int m = 0; m < 30; ++m) mx = fmaxf(mx, ddk[row * 128 + h * 32 + m]);
        kmx[u] = mx;
    }
    __syncthreads();

    if (t < 4) {
        float mx = kmx[t * 16];
        for (int row = 1; row < 16; ++row) mx = fmaxf(mx, kmx[t * 16 + row]);
        blockmax[blockIdx.x * 4 + t] = mx;
    }
    for (int idx = t; idx < 1920; idx += 256) {
        const int row = idx / 120, r = idx % 120, h = r / 30, m = r % 30;
        if (n0 + row < N) {
            float val = RATIO * (expf(ddq[row * 128 + h * 32 + m] - dgq[h * 16 + row] - qmx[h * 16 + row]) + NEPS);
            qp16[(long)(n0 + row) * 120 + r] = __float2bfloat16(val);
            argk[(long)(n0 + row) * 120 + r] = ddk[row * 128 + h * 32 + m] - dgk[h * 16 + row];
        }
    }
}

__global__ __launch_bounds__(256) void k1b_redmax(
    const float* __restrict__ blockmax, float* __restrict__ headmax, int ntiles)
{
    __shared__ float red[4 * 256];
    const int t = threadIdx.x;
    float lm[4] = {-3.4e38f, -3.4e38f, -3.4e38f, -3.4e38f};
    for (int i = t; i < ntiles; i += 256) {
#pragma unroll
        for (int hh = 0; hh < 4; ++hh) lm[hh] = fmaxf(lm[hh], blockmax[i * 4 + hh]);
    }
#pragma unroll
    for (int hh = 0; hh < 4; ++hh) red[hh * 256 + t] = lm[hh];
    __syncthreads();
    if (t < 4) {
        float mx = red[t * 256];
        for (int i = 1; i < 256; ++i) mx = fmaxf(mx, red[t * 256 + i]);
        headmax[t] = mx;
    }
}

// ---- k2: MFMA accumulate (unchanged from round 5) ----
__global__ __launch_bounds__(256) void k2_kvs(
    const float* __restrict__ argk, const float* __restrict__ gum,
    const __hip_bfloat16* __restrict__ v16, const float* __restrict__ tau,
    const float* __restrict__ headmax,
    float* __restrict__ kvs, float* __restrict__ kssum, int N, int nchunk)
{
    __shared__ alignas(16) unsigned short P[320 * 72];
    __shared__ alignas(16) unsigned short Vt[80 * 72];
    __shared__ float kpL[64 * 33];
    __shared__ float geL[64 * 13];

    const int t = threadIdx.x;
    const int h = blockIdx.x >> 7;
    const int chunk = blockIdx.x & 127;
    const int n0 = chunk * nchunk;
    const int n1 = (n0 + nchunk < N) ? (n0 + nchunk) : N;
    const float MX = headmax[h];
    const float itau = 1.0f / tau[0];
    const int wave = t >> 6, lane = t & 63;

    floatx4 acc[5][5];
#pragma unroll
    for (int q = 0; q < 5; ++q)
#pragma unroll
        for (int dt = 0; dt < 5; ++dt) acc[q][dt] = floatx4{0.f, 0.f, 0.f, 0.f};

    if (t < 64) Vt[64 * 72 + t] = f2bf(1.0f);
    for (int i = t; i < 15 * 72; i += 256) Vt[65 * 72 + i] = 0;

    const int ntile = (n1 - n0 + 63) >> 6;
    for (int tt = 0; tt < ntile; ++tt) {
        const int nb = n0 + tt * 64;
        __syncthreads();
        for (int i = t; i < 1920; i += 256) {
            int r = i / 30, m = i % 30;
            kpL[r * 33 + m] = (nb + r < n1)
                ? RATIO * (expf(argk[(long)(nb + r) * 120 + h * 30 + m] - MX) + NEPS) : 0.f;
        }
        for (int i = t; i < 640; i += 256) {
            int r = i / 10, k = i % 10;
            geL[r * 13 + k] = (nb + r < n1)
                ? expf(gum[(long)(nb + r) * 40 + h * 10 + k] * itau) : 0.f;
        }
        for (int i = t; i < 2048; i += 256) {
            int n = i >> 5, dp = (i & 31) * 2;
            unsigned int u = (nb + n < n1)
                ? *reinterpret_cast<const unsigned int*>(v16 + (long)(nb + n) * 256 + h * 64 + dp)
                : 0u;
            Vt[dp * 72 + n] = (unsigned short)(u & 0xffffu);
            Vt[(dp + 1) * 72 + n] = (unsigned short)(u >> 16);
        }
        __syncthreads();
        for (int i = t; i < 20480; i += 256) {
            int km = i >> 6, n = i & 63;
            float val = 0.f;
            if (km < 300) {
                int m = km % 30, k = km / 30;
                val = kpL[n * 33 + m] * geL[n * 13 + k];
            }
            P[km * 72 + n] = f2bf(val);
        }
        __syncthreads();
#pragma unroll
        for (int nh = 0; nh < 2; ++nh) {
            const int ko = nh * 32 + (lane >> 4) * 8;
            short8 b[5];
#pragma unroll
            for (int dt = 0; dt < 5; ++dt)
                b[dt] = *reinterpret_cast<const short8*>(&Vt[(dt * 16 + (lane & 15)) * 72 + ko]);
#pragma unroll
            for (int q = 0; q < 5; ++q) {
                short8 a = *reinterpret_cast<const short8*>(
                    &P[((wave * 5 + q) * 16 + (lane & 15)) * 72 + ko]);
#pragma unroll
                for (int dt = 0; dt < 5; ++dt)
                    acc[q][dt] = __builtin_amdgcn_mfma_f32_16x16x32_bf16(a, b[dt], acc[q][dt], 0, 0, 0);
            }
        }
    }

    float* kvh = kvs + h * 19200;
#pragma unroll
    for (int q = 0; q < 5; ++q) {
        const int kmb = (wave * 5 + q) * 16 + (lane >> 4) * 4;
#pragma unroll
        for (int r = 0; r < 4; ++r) {
            const int km = kmb + r;
            if (km < 300) {
#pragma unroll
                for (int dt = 0; dt < 4; ++dt)
                    atomicAdd(&kvh[km * 64 + dt * 16 + (lane & 15)], acc[q][dt][r]);
                if ((lane & 15) == 0)
                    atomicAdd(&kssum[h * 300 + km], acc[q][4][r]);
            }
        }
    }
}

// ---- k3: unchanged from round 5 ----
__global__ __launch_bounds__(512) void k3_out(
    const __hip_bfloat16* __restrict__ qp16, const float* __restrict__ kvs,
    const float* __restrict__ kssum, const float* __restrict__ Wo,
    const float* __restrict__ bo, float* __restrict__ out, int N)
{
    __shared__ alignas(16) float SA[19200];
    __shared__ alignas(16) float zl[32 * 260];
    __shared__ float qpl[32 * 30];
    __shared__ float idl[32 * 10];
    __shared__ float ksl[300];
    __shared__ alignas(16) float bol[64];

    const int t = threadIdx.x;
    const int n0 = blockIdx.x * 32;
    const int r = t >> 4, d4 = t & 15;

    for (int h = 0; h < 4; ++h) {
        __syncthreads();
        for (int i = t; i < 19200; i += 512) SA[i] = kvs[h * 19200 + i];
        if (t < 300) ksl[t] = kssum[h * 300 + t];
        for (int i = t; i < 960; i += 512) {
            int rr = i / 30, m = i % 30;
            long n = n0 + rr;
            qpl[i] = (n < N) ? __bfloat162float(qp16[n * 120 + h * 30 + m]) : 1.0f;
        }
        __syncthreads();
        if (t < 320) {
            const int rr = t / 10, kk = t % 10;
            float s = 0.f;
#pragma unroll
            for (int m = 0; m < 30; ++m) s += qpl[rr * 30 + m] * ksl[kk * 30 + m];
            idl[t] = 1.0f / s;
        }
        __syncthreads();
        {
            const float* qr = &qpl[r * 30];
            const float* ir = &idl[r * 10];
            const float4* SA4 = reinterpret_cast<const float4*>(SA);
            float sx = 0.f, sy = 0.f, sz = 0.f, sw = 0.f;
#pragma unroll
            for (int kk = 0; kk < 10; ++kk) {
                float ax = 0.f, ay = 0.f, az = 0.f, aw = 0.f;
#pragma unroll
                for (int m = 0; m < 30; ++m) {
                    float4 b = SA4[(kk * 30 + m) * 16 + d4];
                    float q = qr[m];
                    ax += q * b.x; ay += q * b.y; az += q * b.z; aw += q * b.w;
                }
                float w = ir[kk];
                sx += ax * w; sy += ay * w; sz += az * w; sw += aw * w;
            }
            float4 zv; zv.x = 0.1f * sx; zv.y = 0.1f * sy; zv.z = 0.1f * sz; zv.w = 0.1f * sw;
            reinterpret_cast<float4*>(zl)[r * 65 + h * 16 + d4] = zv;
        }
    }
    __syncthreads();
    for (int i = t; i < 16384; i += 512) SA[i] = Wo[i];
    if (t < 64) bol[t] = bo[t];
    __syncthreads();
    {
        const float4* W4 = reinterpret_cast<const float4*>(SA);
        float4 o = reinterpret_cast<const float4*>(bol)[d4];
        const float* zr = &zl[r * 260];
#pragma unroll 8
        for (int c = 0; c < 256; ++c) {
            float zv = zr[c];
            float4 w = W4[c * 16 + d4];
            o.x += zv * w.x; o.y += zv * w.y; o.z += zv * w.z; o.w += zv * w.w;
        }
        long n = n0 + r;
        if (n < N) {
            *reinterpret_cast<float4*>(out + n * 64 + d4 * 4) = o;
        }
    }
}

extern "C" void kernel_launch(void* const* d_in, const int* in_sizes, int n_in,
                              void* d_out, int out_size, void* d_ws, size_t ws_size,
                              hipStream_t stream)
{
    const float* z    = (const float*)d_in[0];
    const float* Wq   = (const float*)d_in[1];
    const float* bq   = (const float*)d_in[2];
    const float* Wk   = (const float*)d_in[3];
    const float* bk   = (const float*)d_in[4];
    const float* Wv   = (const float*)d_in[5];
    const float* bv   = (const float*)d_in[6];
    const float* Wo   = (const float*)d_in[7];
    const float* bo   = (const float*)d_in[8];
    const float* proj = (const float*)d_in[9];
    const float* gum  = (const float*)d_in[10];
    const float* tau  = (const float*)d_in[11];
    float* out = (float*)d_out;

    const int N = in_sizes[0] / 64;          // 50000
    const int ntiles = (N + 15) / 16;        // 3125
    const int nchunk = (N + 127) / 128;      // 391
    const int nblk3  = (N + 31) / 32;        // 1563

    char* wsb = (char*)d_ws;
    size_t off = 0;
    __hip_bfloat16* qp16 = (__hip_bfloat16*)(wsb);
    off += ((size_t)N * 120 * 2 + 255) & ~(size_t)255;
    __hip_bfloat16* v16 = (__hip_bfloat16*)(wsb + off);
    off += ((size_t)N * 256 * 2 + 255) & ~(size_t)255;
    float* argk = (float*)(wsb + off);
    off += ((size_t)N * 120 * 4 + 255) & ~(size_t)255;
    float* kvs      = (float*)(wsb + off);
    float* kssum    = kvs + 76800;
    float* headmax  = kssum + 1200;
    float* blockmax = headmax + 4;
    off += ((size_t)(76800 + 1200 + 4 + (size_t)ntiles * 4) * 4 + 255) & ~(size_t)255;
    unsigned short* Wfh = (unsigned short*)(wsb + off); off += 49152 * 2;
    unsigned short* Wfl = (unsigned short*)(wsb + off); off += 49152 * 2;
    unsigned short* Pfh = (unsigned short*)(wsb + off); off += 2048 * 2;
    unsigned short* Pfl = (unsigned short*)(wsb + off);

    k_prep<<<dim3(25), dim3(256), 0, stream>>>(Wq, Wk, Wv, proj, Wfh, Wfl, Pfh, Pfl);
    k0_zero<<<dim3((78000 + 255) / 256), dim3(256), 0, stream>>>(kvs, 78000);
    k1_feat<<<dim3(ntiles), dim3(256), 0, stream>>>(z, bq, bk, bv, Wfh, Wfl, Pfh, Pfl, tau,
                                                    qp16, v16, argk, blockmax, N);
    k1b_redmax<<<dim3(1), dim3(256), 0, stream>>>(blockmax, headmax, ntiles);
    k2_kvs<<<dim3(512), dim3(256), 0, stream>>>(argk, gum, v16, tau, headmax,
                                                kvs, kssum, N, nchunk);
    k3_out<<<dim3(nblk3), dim3(512), 0, stream>>>(qp16, kvs, kssum, Wo, bo, out, N);
}

// Round 7
// 415.414 us; speedup vs baseline: 16.8349x; 1.3184x over previous
//
#include <hip/hip_runtime.h>
#include <hip/hip_bf16.h>

// NodeFormerConv: Performer/Gumbel attention. fp32-equivalent math, fp32 output.
//   k_prep: split Wq|Wk|Wv, proj, Wo into MFMA-fragment-ordered hi/lo bf16
//   k0   zero kvs[4][300][64] + kssum[4][300]
//   k1   per 16-row tile, MFMA (hi/lo 3-pass): QKV gemm -> qd/kd LDS + v16;
//        phi gemm -> ddq/ddk; diag; exp -> qp16, argk, blockmax
//   k1b  blockmax -> headmax[4]
//   k2   MFMA accumulate: P[320x72]bf16 (kp*ge), Vt[80x72]bf16 (+ones row) ->
//        kvs[300x64] += P@V, kssum += P@1 per head
//   k3   MFMA: per 32-row block, heads sequential: B=kvs_h hi/lo frags (LDS union
//        with NUM), NUM=qp16@B (K=30 in one K-step), den on VALU, combine -> zl;
//        then out = zl@Wo (hi/lo 3-pass MFMA) + bo (f32)

#define NEPS  1e-6f
#define RATIO 0.18257418583505536f   // 1/sqrt(30)
#define DNORM 0.35355339059327378f   // 64^-0.25

typedef __attribute__((ext_vector_type(8))) short short8;
typedef __attribute__((ext_vector_type(4))) float floatx4;

__device__ inline unsigned short f2bf(float x) {
    __hip_bfloat16 b = __float2bfloat16(x);
    return __builtin_bit_cast(unsigned short, b);
}
__device__ inline float bf2f(unsigned short h) {
    return __builtin_bit_cast(float, (unsigned int)h << 16);
}
__device__ inline void split2(float v, unsigned short& hi, unsigned short& lo) {
    unsigned short h = f2bf(v);
    hi = h; lo = f2bf(v - bf2f(h));
}

__global__ __launch_bounds__(256) void k0_zero(float* __restrict__ p, int count) {
    int id = blockIdx.x * 256 + threadIdx.x;
    if (id < count) p[id] = 0.f;
}

// ---- k_prep: fragment-ordered hi/lo splits ----
// Wf: [(ct*2+ks)*512 + lane*8 + j], col=ct*16+(lane&15), k=ks*32+(lane>>4)*8+j
// Pf: same, 2 ct (m-cols) x 2 ks
// Wof: [(ct*8+ks)*512 + lane*8 + j], col(d)=ct*16+(lane&15), k(c)=ks*32+(lane>>4)*8+j
__global__ __launch_bounds__(256) void k_prep(
    const float* __restrict__ Wq, const float* __restrict__ Wk, const float* __restrict__ Wv,
    const float* __restrict__ proj, const float* __restrict__ Wo,
    unsigned short* __restrict__ Wfh, unsigned short* __restrict__ Wfl,
    unsigned short* __restrict__ Pfh, unsigned short* __restrict__ Pfl,
    unsigned short* __restrict__ Wofh, unsigned short* __restrict__ Wofl)
{
    const int b = blockIdx.x, t = threadIdx.x;
    if (b < 24) {
        const int slot = b * 256 + t;
        const int lane = slot & 63;
        const int ctks = slot >> 6;
        const int ct = ctks >> 1, ks = ctks & 1;
        const int col = ct * 16 + (lane & 15);
        const int k0 = ks * 32 + (lane >> 4) * 8;
        const float* W = (col < 256) ? Wq : (col < 512) ? Wk : Wv;
        const int cm = col & 255;
#pragma unroll
        for (int j = 0; j < 8; ++j) {
            float w = W[(k0 + j) * 256 + cm];
            unsigned short hi, lo; split2(w, hi, lo);
            Wfh[slot * 8 + j] = hi;
            Wfl[slot * 8 + j] = lo;
        }
    } else if (b == 24) {                       // proj frags
        const int lane = t & 63;
        const int ctks = t >> 6;
        const int ct2 = ctks >> 1, ks = ctks & 1;
        const int m = ct2 * 16 + (lane & 15);
        const int k0 = ks * 32 + (lane >> 4) * 8;
#pragma unroll
        for (int j = 0; j < 8; ++j) {
            float p = (m < 30) ? proj[m * 64 + k0 + j] : 0.f;
            unsigned short hi, lo; split2(p, hi, lo);
            Pfh[t * 8 + j] = hi;
            Pfl[t * 8 + j] = lo;
        }
    } else {                                    // Wo frags: 32 slots x 512
        for (int idx = t; idx < 2048; idx += 256) {
            const int slot = idx >> 6, l = idx & 63;
            const int ct = slot >> 3, ks = slot & 7;
            const int col = ct * 16 + (l & 15);
            const int k0 = ks * 32 + (l >> 4) * 8;
#pragma unroll
            for (int j = 0; j < 8; ++j) {
                float w = Wo[(k0 + j) * 64 + col];
                unsigned short hi, lo; split2(w, hi, lo);
                Wofh[slot * 512 + l * 8 + j] = hi;
                Wofl[slot * 512 + l * 8 + j] = lo;
            }
        }
    }
}

// ---- k1: per 16-row tile, MFMA QKV + phi (hi/lo 3-pass) — unchanged from round 6 ----
__global__ __launch_bounds__(256) void k1_feat(
    const float* __restrict__ z,
    const float* __restrict__ bq, const float* __restrict__ bk, const float* __restrict__ bv,
    const unsigned short* __restrict__ Wfh, const unsigned short* __restrict__ Wfl,
    const unsigned short* __restrict__ Pfh, const unsigned short* __restrict__ Pfl,
    const float* __restrict__ tau,
    __hip_bfloat16* __restrict__ qp16, __hip_bfloat16* __restrict__ v16,
    float* __restrict__ argk, float* __restrict__ blockmax, int N)
{
    __shared__ alignas(16) unsigned short zh[16 * 72];
    __shared__ alignas(16) unsigned short zl_[16 * 72];
    __shared__ alignas(16) float qd[16 * 264];
    __shared__ alignas(16) float kd[16 * 264];
    __shared__ float ddq[16 * 128];
    __shared__ float ddk[16 * 128];
    __shared__ float dgq[64], dgk[64];
    __shared__ float qmx[64], kmx[64];

    const int t = threadIdx.x;
    const int n0 = blockIdx.x * 16;
    const int wave = t >> 6, lane = t & 63;
    const float dsc = rsqrtf(tau[0]) * DNORM;

    for (int i = t; i < 1024; i += 256) {
        int r = i >> 6, c = i & 63;
        float v = (n0 + r < N) ? z[(long)(n0 + r) * 64 + c] : 0.f;
        unsigned short hi, lo; split2(v, hi, lo);
        zh[r * 72 + c] = hi;
        zl_[r * 72 + c] = lo;
    }
    __syncthreads();

    {
        const int abase = (lane & 15) * 72 + (lane >> 4) * 8;
        short8 ah0 = *reinterpret_cast<const short8*>(&zh[abase]);
        short8 ah1 = *reinterpret_cast<const short8*>(&zh[abase + 32]);
        short8 al0 = *reinterpret_cast<const short8*>(&zl_[abase]);
        short8 al1 = *reinterpret_cast<const short8*>(&zl_[abase + 32]);
        const int row0 = (lane >> 4) * 4;
#pragma unroll 2
        for (int ci = 0; ci < 12; ++ci) {
            const int ct = wave * 12 + ci;
            short8 bh0 = *reinterpret_cast<const short8*>(&Wfh[(ct * 2 + 0) * 512 + lane * 8]);
            short8 bh1 = *reinterpret_cast<const short8*>(&Wfh[(ct * 2 + 1) * 512 + lane * 8]);
            short8 bl0 = *reinterpret_cast<const short8*>(&Wfl[(ct * 2 + 0) * 512 + lane * 8]);
            short8 bl1 = *reinterpret_cast<const short8*>(&Wfl[(ct * 2 + 1) * 512 + lane * 8]);
            floatx4 acc = floatx4{0.f, 0.f, 0.f, 0.f};
            acc = __builtin_amdgcn_mfma_f32_16x16x32_bf16(ah0, bh0, acc, 0, 0, 0);
            acc = __builtin_amdgcn_mfma_f32_16x16x32_bf16(ah1, bh1, acc, 0, 0, 0);
            acc = __builtin_amdgcn_mfma_f32_16x16x32_bf16(ah0, bl0, acc, 0, 0, 0);
            acc = __builtin_amdgcn_mfma_f32_16x16x32_bf16(ah1, bl1, acc, 0, 0, 0);
            acc = __builtin_amdgcn_mfma_f32_16x16x32_bf16(al0, bh0, acc, 0, 0, 0);
            acc = __builtin_amdgcn_mfma_f32_16x16x32_bf16(al1, bh1, acc, 0, 0, 0);
            const int c = ct * 16 + (lane & 15);
            if (c < 256) {
                const float bb = bq[c];
#pragma unroll
                for (int r = 0; r < 4; ++r) qd[(row0 + r) * 264 + c] = (acc[r] + bb) * dsc;
            } else if (c < 512) {
                const float bb = bk[c - 256];
#pragma unroll
                for (int r = 0; r < 4; ++r) kd[(row0 + r) * 264 + (c - 256)] = (acc[r] + bb) * dsc;
            } else {
                const float bb = bv[c - 512];
#pragma unroll
                for (int r = 0; r < 4; ++r)
                    if (n0 + row0 + r < N)
                        v16[(long)(n0 + row0 + r) * 256 + (c - 512)] = __float2bfloat16(acc[r] + bb);
            }
        }
    }
    __syncthreads();

    {
        short8 pbh[2][2], pbl[2][2];
#pragma unroll
        for (int ct2 = 0; ct2 < 2; ++ct2)
#pragma unroll
            for (int ks = 0; ks < 2; ++ks) {
                pbh[ct2][ks] = *reinterpret_cast<const short8*>(&Pfh[(ct2 * 2 + ks) * 512 + lane * 8]);
                pbl[ct2][ks] = *reinterpret_cast<const short8*>(&Pfl[(ct2 * 2 + ks) * 512 + lane * 8]);
            }
        const int h = wave;
        const int row0 = (lane >> 4) * 4;
#pragma unroll
        for (int side = 0; side < 2; ++side) {
            const float* dat = side ? kd : qd;
            float* dd = side ? ddk : ddq;
            const int rbase = (lane & 15) * 264 + h * 64 + (lane >> 4) * 8;
            float xv[8], yv[8];
            {
                float4 x0 = *reinterpret_cast<const float4*>(&dat[rbase]);
                float4 x1 = *reinterpret_cast<const float4*>(&dat[rbase + 4]);
                float4 y0 = *reinterpret_cast<const float4*>(&dat[rbase + 32]);
                float4 y1 = *reinterpret_cast<const float4*>(&dat[rbase + 36]);
                xv[0]=x0.x; xv[1]=x0.y; xv[2]=x0.z; xv[3]=x0.w;
                xv[4]=x1.x; xv[5]=x1.y; xv[6]=x1.z; xv[7]=x1.w;
                yv[0]=y0.x; yv[1]=y0.y; yv[2]=y0.z; yv[3]=y0.w;
                yv[4]=y1.x; yv[5]=y1.y; yv[6]=y1.z; yv[7]=y1.w;
            }
            short8 ah0, al0, ah1, al1;
#pragma unroll
            for (int j = 0; j < 8; ++j) {
                unsigned short hi, lo;
                split2(xv[j], hi, lo); ah0[j] = (short)hi; al0[j] = (short)lo;
                split2(yv[j], hi, lo); ah1[j] = (short)hi; al1[j] = (short)lo;
            }
#pragma unroll
            for (int ct2 = 0; ct2 < 2; ++ct2) {
                floatx4 acc = floatx4{0.f, 0.f, 0.f, 0.f};
                acc = __builtin_amdgcn_mfma_f32_16x16x32_bf16(ah0, pbh[ct2][0], acc, 0, 0, 0);
                acc = __builtin_amdgcn_mfma_f32_16x16x32_bf16(ah1, pbh[ct2][1], acc, 0, 0, 0);
                acc = __builtin_amdgcn_mfma_f32_16x16x32_bf16(ah0, pbl[ct2][0], acc, 0, 0, 0);
                acc = __builtin_amdgcn_mfma_f32_16x16x32_bf16(ah1, pbl[ct2][1], acc, 0, 0, 0);
                acc = __builtin_amdgcn_mfma_f32_16x16x32_bf16(al0, pbh[ct2][0], acc, 0, 0, 0);
                acc = __builtin_amdgcn_mfma_f32_16x16x32_bf16(al1, pbh[ct2][1], acc, 0, 0, 0);
#pragma unroll
                for (int r = 0; r < 4; ++r)
                    dd[(row0 + r) * 128 + h * 32 + ct2 * 16 + (lane & 15)] = acc[r];
            }
        }
    }
    if (t < 128) {
        const int h = t >> 5, row = (t >> 1) & 15, side = t & 1;
        const float* dat = side ? kd : qd;
        float s = 0.f;
        for (int d = 0; d < 64; ++d) { float x = dat[row * 264 + h * 64 + d]; s += x * x; }
        (side ? dgk : dgq)[h * 16 + row] = 0.5f * s;
    }
    __syncthreads();

    if (t < 64) {
        const int h = t >> 4, row = t & 15;
        float mx = ddq[row * 128 + h * 32];
        for (int m = 1; m < 30; ++m) mx = fmaxf(mx, ddq[row * 128 + h * 32 + m]);
        qmx[t] = mx;
    } else if (t < 128) {
        const int u = t - 64, h = u >> 4, row = u & 15;
        float mx = -3.4e38f;
        if (n0 + row < N)
            for (int m = 0; m < 30; ++m) mx = fmaxf(mx, ddk[row * 128 + h * 32 + m]);
        kmx[u] = mx;
    }
    __syncthreads();

    if (t < 4) {
        float mx = kmx[t * 16];
        for (int row = 1; row < 16; ++row) mx = fmaxf(mx, kmx[t * 16 + row]);
        blockmax[blockIdx.x * 4 + t] = mx;
    }
    for (int idx = t; idx < 1920; idx += 256) {
        const int row = idx / 120, r = idx % 120, h = r / 30, m = r % 30;
        if (n0 + row < N) {
            float val = RATIO * (expf(ddq[row * 128 + h * 32 + m] - dgq[h * 16 + row] - qmx[h * 16 + row]) + NEPS);
            qp16[(long)(n0 + row) * 120 + r] = __float2bfloat16(val);
            argk[(long)(n0 + row) * 120 + r] = ddk[row * 128 + h * 32 + m] - dgk[h * 16 + row];
        }
    }
}

__global__ __launch_bounds__(256) void k1b_redmax(
    const float* __restrict__ blockmax, float* __restrict__ headmax, int ntiles)
{
    __shared__ float red[4 * 256];
    const int t = threadIdx.x;
    float lm[4] = {-3.4e38f, -3.4e38f, -3.4e38f, -3.4e38f};
    for (int i = t; i < ntiles; i += 256) {
#pragma unroll
        for (int hh = 0; hh < 4; ++hh) lm[hh] = fmaxf(lm[hh], blockmax[i * 4 + hh]);
    }
#pragma unroll
    for (int hh = 0; hh < 4; ++hh) red[hh * 256 + t] = lm[hh];
    __syncthreads();
    if (t < 4) {
        float mx = red[t * 256];
        for (int i = 1; i < 256; ++i) mx = fmaxf(mx, red[t * 256 + i]);
        headmax[t] = mx;
    }
}

// ---- k2: MFMA accumulate (unchanged from round 5) ----
__global__ __launch_bounds__(256) void k2_kvs(
    const float* __restrict__ argk, const float* __restrict__ gum,
    const __hip_bfloat16* __restrict__ v16, const float* __restrict__ tau,
    const float* __restrict__ headmax,
    float* __restrict__ kvs, float* __restrict__ kssum, int N, int nchunk)
{
    __shared__ alignas(16) unsigned short P[320 * 72];
    __shared__ alignas(16) unsigned short Vt[80 * 72];
    __shared__ float kpL[64 * 33];
    __shared__ float geL[64 * 13];

    const int t = threadIdx.x;
    const int h = blockIdx.x >> 7;
    const int chunk = blockIdx.x & 127;
    const int n0 = chunk * nchunk;
    const int n1 = (n0 + nchunk < N) ? (n0 + nchunk) : N;
    const float MX = headmax[h];
    const float itau = 1.0f / tau[0];
    const int wave = t >> 6, lane = t & 63;

    floatx4 acc[5][5];
#pragma unroll
    for (int q = 0; q < 5; ++q)
#pragma unroll
        for (int dt = 0; dt < 5; ++dt) acc[q][dt] = floatx4{0.f, 0.f, 0.f, 0.f};

    if (t < 64) Vt[64 * 72 + t] = f2bf(1.0f);
    for (int i = t; i < 15 * 72; i += 256) Vt[65 * 72 + i] = 0;

    const int ntile = (n1 - n0 + 63) >> 6;
    for (int tt = 0; tt < ntile; ++tt) {
        const int nb = n0 + tt * 64;
        __syncthreads();
        for (int i = t; i < 1920; i += 256) {
            int r = i / 30, m = i % 30;
            kpL[r * 33 + m] = (nb + r < n1)
                ? RATIO * (expf(argk[(long)(nb + r) * 120 + h * 30 + m] - MX) + NEPS) : 0.f;
        }
        for (int i = t; i < 640; i += 256) {
            int r = i / 10, k = i % 10;
            geL[r * 13 + k] = (nb + r < n1)
                ? expf(gum[(long)(nb + r) * 40 + h * 10 + k] * itau) : 0.f;
        }
        for (int i = t; i < 2048; i += 256) {
            int n = i >> 5, dp = (i & 31) * 2;
            unsigned int u = (nb + n < n1)
                ? *reinterpret_cast<const unsigned int*>(v16 + (long)(nb + n) * 256 + h * 64 + dp)
                : 0u;
            Vt[dp * 72 + n] = (unsigned short)(u & 0xffffu);
            Vt[(dp + 1) * 72 + n] = (unsigned short)(u >> 16);
        }
        __syncthreads();
        for (int i = t; i < 20480; i += 256) {
            int km = i >> 6, n = i & 63;
            float val = 0.f;
            if (km < 300) {
                int m = km % 30, k = km / 30;
                val = kpL[n * 33 + m] * geL[n * 13 + k];
            }
            P[km * 72 + n] = f2bf(val);
        }
        __syncthreads();
#pragma unroll
        for (int nh = 0; nh < 2; ++nh) {
            const int ko = nh * 32 + (lane >> 4) * 8;
            short8 b[5];
#pragma unroll
            for (int dt = 0; dt < 5; ++dt)
                b[dt] = *reinterpret_cast<const short8*>(&Vt[(dt * 16 + (lane & 15)) * 72 + ko]);
#pragma unroll
            for (int q = 0; q < 5; ++q) {
                short8 a = *reinterpret_cast<const short8*>(
                    &P[((wave * 5 + q) * 16 + (lane & 15)) * 72 + ko]);
#pragma unroll
                for (int dt = 0; dt < 5; ++dt)
                    acc[q][dt] = __builtin_amdgcn_mfma_f32_16x16x32_bf16(a, b[dt], acc[q][dt], 0, 0, 0);
            }
        }
    }

    float* kvh = kvs + h * 19200;
#pragma unroll
    for (int q = 0; q < 5; ++q) {
        const int kmb = (wave * 5 + q) * 16 + (lane >> 4) * 4;
#pragma unroll
        for (int r = 0; r < 4; ++r) {
            const int km = kmb + r;
            if (km < 300) {
#pragma unroll
                for (int dt = 0; dt < 4; ++dt)
                    atomicAdd(&kvh[km * 64 + dt * 16 + (lane & 15)], acc[q][dt][r]);
                if ((lane & 15) == 0)
                    atomicAdd(&kssum[h * 300 + km], acc[q][4][r]);
            }
        }
    }
}

// ---- k3: MFMA numerator + Wo. 512 thr (8 waves), 32 rows/block.
// Per head: B-frags (kvs hi/lo, K=30 one step) in union LDS -> NUM=qp16@B
// (wave w: ct 5w..5w+4, rt 0..1) -> NUM to union -> combine w/ VALU den -> zl.
// Then out = zl @ Wo (hi/lo 3-pass) + bo.
__global__ __launch_bounds__(512) void k3_out(
    const __hip_bfloat16* __restrict__ qp16, const float* __restrict__ kvs,
    const float* __restrict__ kssum,
    const unsigned short* __restrict__ Wofh, const unsigned short* __restrict__ Wofl,
    const float* __restrict__ bo, float* __restrict__ out, int N)
{
    __shared__ alignas(16) float U[32 * 656];   // union: B-frags (ushort) / NUM f32
    __shared__ alignas(16) float zl[32 * 260];
    __shared__ float qpl[32 * 30];
    __shared__ float idl[320];
    __shared__ float ksl[300];

    unsigned short* Bfh = reinterpret_cast<unsigned short*>(U);
    unsigned short* Bfl = Bfh + 20480;

    const int t = threadIdx.x;
    const int n0 = blockIdx.x * 32;
    const int wave = t >> 6, lane = t & 63;

    for (int h = 0; h < 4; ++h) {
        __syncthreads();                         // A: prev head's U/idl readers done
        // build B-frags from kvs_h (L2-hot); pad m-slots 30,31 are garbage-but-finite
        // (masked by A=0). 40 ct x 64 lanes x 8 j.
        {
            const float* kvh = kvs + h * 19200;
            for (int idx = t; idx < 2560; idx += 512) {
                const int ct = idx >> 6, l = idx & 63;
                const int col = ct * 16 + (l & 15);
                const int k = col >> 6, d = col & 63;
                const int mb = (l >> 4) * 8;
                const float* src = kvh + (k * 30 + mb) * 64 + d;
                short8 hi, lo;
#pragma unroll
                for (int j = 0; j < 8; ++j) {
                    float v = src[j * 64];
                    unsigned short h2, l2; split2(v, h2, l2);
                    hi[j] = (short)h2; lo[j] = (short)l2;
                }
                *reinterpret_cast<short8*>(&Bfh[idx * 8]) = hi;
                *reinterpret_cast<short8*>(&Bfl[idx * 8]) = lo;
            }
        }
        if (t < 300) ksl[t] = kssum[h * 300 + t];
        for (int i = t; i < 960; i += 512) {
            int rr = i / 30, m = i % 30;
            int n = n0 + rr; if (n >= N) n = N - 1;
            qpl[i] = bf2f(((const unsigned short*)qp16)[(long)n * 120 + h * 30 + m]);
        }
        __syncthreads();                         // B: frags/ksl/qpl ready

        // A-frags: qp16 rows (exact bf16 reuse -> num/den cancellation)
        short8 aQ[2];
#pragma unroll
        for (int rt = 0; rt < 2; ++rt) {
            int n = n0 + rt * 16 + (lane & 15); if (n >= N) n = N - 1;
            const unsigned int* qrow = reinterpret_cast<const unsigned int*>(
                (const unsigned short*)qp16 + (long)n * 120 + h * 30 + (lane >> 4) * 8);
            short8 a;
#pragma unroll
            for (int jj = 0; jj < 4; ++jj) {
                unsigned int u = qrow[jj];
                a[jj * 2] = (short)(u & 0xffffu);
                a[jj * 2 + 1] = (short)(u >> 16);
            }
            if ((lane >> 4) == 3) { a[6] = 0; a[7] = 0; }   // m = 30,31
            aQ[rt] = a;
        }
        floatx4 acc[2][5];
#pragma unroll
        for (int rt = 0; rt < 2; ++rt)
#pragma unroll
            for (int q = 0; q < 5; ++q) acc[rt][q] = floatx4{0.f, 0.f, 0.f, 0.f};
#pragma unroll
        for (int q = 0; q < 5; ++q) {
            const int ct = wave * 5 + q;
            short8 bh = *reinterpret_cast<const short8*>(&Bfh[(ct * 64 + lane) * 8]);
            short8 bl = *reinterpret_cast<const short8*>(&Bfl[(ct * 64 + lane) * 8]);
            acc[0][q] = __builtin_amdgcn_mfma_f32_16x16x32_bf16(aQ[0], bh, acc[0][q], 0, 0, 0);
            acc[0][q] = __builtin_amdgcn_mfma_f32_16x16x32_bf16(aQ[0], bl, acc[0][q], 0, 0, 0);
            acc[1][q] = __builtin_amdgcn_mfma_f32_16x16x32_bf16(aQ[1], bh, acc[1][q], 0, 0, 0);
            acc[1][q] = __builtin_amdgcn_mfma_f32_16x16x32_bf16(aQ[1], bl, acc[1][q], 0, 0, 0);
        }
        // den on VALU (concurrent with MFMA issue)
        if (t < 320) {
            const int rr = t / 10, kk = t % 10;
            float s = 0.f;
#pragma unroll
            for (int m = 0; m < 30; ++m) s += qpl[rr * 30 + m] * ksl[kk * 30 + m];
            idl[t] = 1.0f / s;
        }
        __syncthreads();                         // C: all B-frag reads done
        // NUM -> union (stride 656 f32)
#pragma unroll
        for (int rt = 0; rt < 2; ++rt)
#pragma unroll
            for (int q = 0; q < 5; ++q) {
                const int ct = wave * 5 + q;
                const int row = rt * 16 + (lane >> 4) * 4;
                const int col = ct * 16 + (lane & 15);
#pragma unroll
                for (int r = 0; r < 4; ++r)
                    U[(row + r) * 656 + col] = acc[rt][q][r];
            }
        __syncthreads();                         // D: NUM ready
        // combine: zl[row][h*64+d] = 0.1 * sum_k NUM[row][k*64+d] / den[row][k]
        {
            const int row = t >> 4, dd = t & 15;
            const float4* U4 = reinterpret_cast<const float4*>(U);
            float4 s = float4{0.f, 0.f, 0.f, 0.f};
#pragma unroll
            for (int k = 0; k < 10; ++k) {
                float4 nm = U4[row * 164 + k * 16 + dd];
                float w = idl[row * 10 + k];
                s.x += nm.x * w; s.y += nm.y * w; s.z += nm.z * w; s.w += nm.w * w;
            }
            float4 zv; zv.x = 0.1f * s.x; zv.y = 0.1f * s.y; zv.z = 0.1f * s.z; zv.w = 0.1f * s.w;
            reinterpret_cast<float4*>(zl)[row * 65 + h * 16 + dd] = zv;
        }
    }
    __syncthreads();                             // zl complete
    // Wo phase: wave w -> rt = w>>2, ct = w&3; out tile [16 rows x 16 d]
    {
        const int rt = wave >> 2, ct = wave & 3;
        floatx4 o = floatx4{0.f, 0.f, 0.f, 0.f};
#pragma unroll
        for (int ks = 0; ks < 8; ++ks) {
            const float* zr = &zl[(rt * 16 + (lane & 15)) * 260 + ks * 32 + (lane >> 4) * 8];
            float4 x0 = *reinterpret_cast<const float4*>(zr);
            float4 x1 = *reinterpret_cast<const float4*>(zr + 4);
            float xv[8] = {x0.x, x0.y, x0.z, x0.w, x1.x, x1.y, x1.z, x1.w};
            short8 ah, al;
#pragma unroll
            for (int j = 0; j < 8; ++j) {
                unsigned short hi, lo; split2(xv[j], hi, lo);
                ah[j] = (short)hi; al[j] = (short)lo;
            }
            const int slot = ct * 8 + ks;
            short8 bh = *reinterpret_cast<const short8*>(&Wofh[slot * 512 + lane * 8]);
            short8 bl = *reinterpret_cast<const short8*>(&Wofl[slot * 512 + lane * 8]);
            o = __builtin_amdgcn_mfma_f32_16x16x32_bf16(ah, bh, o, 0, 0, 0);
            o = __builtin_amdgcn_mfma_f32_16x16x32_bf16(ah, bl, o, 0, 0, 0);
            o = __builtin_amdgcn_mfma_f32_16x16x32_bf16(al, bh, o, 0, 0, 0);
        }
        const int col = ct * 16 + (lane & 15);
        const float bb = bo[col];
#pragma unroll
        for (int r = 0; r < 4; ++r) {
            const int n = n0 + rt * 16 + (lane >> 4) * 4 + r;
            if (n < N) out[(long)n * 64 + col] = o[r] + bb;
        }
    }
}

extern "C" void kernel_launch(void* const* d_in, const int* in_sizes, int n_in,
                              void* d_out, int out_size, void* d_ws, size_t ws_size,
                              hipStream_t stream)
{
    const float* z    = (const float*)d_in[0];
    const float* Wq   = (const float*)d_in[1];
    const float* bq   = (const float*)d_in[2];
    const float* Wk   = (const float*)d_in[3];
    const float* bk   = (const float*)d_in[4];
    const float* Wv   = (const float*)d_in[5];
    const float* bv   = (const float*)d_in[6];
    const float* Wo   = (const float*)d_in[7];
    const float* bo   = (const float*)d_in[8];
    const float* proj = (const float*)d_in[9];
    const float* gum  = (const float*)d_in[10];
    const float* tau  = (const float*)d_in[11];
    float* out = (float*)d_out;

    const int N = in_sizes[0] / 64;          // 50000
    const int ntiles = (N + 15) / 16;        // 3125
    const int nchunk = (N + 127) / 128;      // 391
    const int nblk3  = (N + 31) / 32;        // 1563

    char* wsb = (char*)d_ws;
    size_t off = 0;
    __hip_bfloat16* qp16 = (__hip_bfloat16*)(wsb);
    off += ((size_t)N * 120 * 2 + 255) & ~(size_t)255;
    __hip_bfloat16* v16 = (__hip_bfloat16*)(wsb + off);
    off += ((size_t)N * 256 * 2 + 255) & ~(size_t)255;
    float* argk = (float*)(wsb + off);
    off += ((size_t)N * 120 * 4 + 255) & ~(size_t)255;
    float* kvs      = (float*)(wsb + off);
    float* kssum    = kvs + 76800;
    float* headmax  = kssum + 1200;
    float* blockmax = headmax + 4;
    off += ((size_t)(76800 + 1200 + 4 + (size_t)ntiles * 4) * 4 + 255) & ~(size_t)255;
    unsigned short* Wfh = (unsigned short*)(wsb + off); off += 49152 * 2;
    unsigned short* Wfl = (unsigned short*)(wsb + off); off += 49152 * 2;
    unsigned short* Pfh = (unsigned short*)(wsb + off); off += 2048 * 2;
    unsigned short* Pfl = (unsigned short*)(wsb + off); off += 2048 * 2;
    unsigned short* Wofh = (unsigned short*)(wsb + off); off += 16384 * 2;
    unsigned short* Wofl = (unsigned short*)(wsb + off);

    k_prep<<<dim3(26), dim3(256), 0, stream>>>(Wq, Wk, Wv, proj, Wo,
                                               Wfh, Wfl, Pfh, Pfl, Wofh, Wofl);
    k0_zero<<<dim3((78000 + 255) / 256), dim3(256), 0, stream>>>(kvs, 78000);
    k1_feat<<<dim3(ntiles), dim3(256), 0, stream>>>(z, bq, bk, bv, Wfh, Wfl, Pfh, Pfl, tau,
                                                    qp16, v16, argk, blockmax, N);
    k1b_redmax<<<dim3(1), dim3(256), 0, stream>>>(blockmax, headmax, ntiles);
    k2_kvs<<<dim3(512), dim3(256), 0, stream>>>(argk, gum, v16, tau, headmax,
                                                kvs, kssum, N, nchunk);
    k3_out<<<dim3(nblk3), dim3(512), 0, stream>>>(qp16, kvs, kssum, Wofh, Wofl, bo, out, N);
}

// Round 8
// 407.531 us; speedup vs baseline: 17.1605x; 1.0193x over previous
//
#include <hip/hip_runtime.h>
#include <hip/hip_bf16.h>

// NodeFormerConv: Performer/Gumbel attention. fp32-equivalent math, fp32 output.
//   k_prep: split Wq|Wk|Wv, proj, Wo into MFMA-fragment-ordered hi/lo bf16
//   k0   zero kvs[4][300][64] + kssum[4][300]
//   k1   per 16-row tile, MFMA (hi/lo 3-pass): QKV gemm -> qd/kd LDS + v16;
//        phi gemm -> ddq/ddk; diag; exp -> qp16, argk, blockmax
//   k1b  blockmax -> headmax[4]
//   k2   MFMA accumulate, register-built A-frags: a[j]=bf16(kp[n,m]*ge[k,n]) read
//        straight from kpL/geT LDS; B=Vt (+ones row). No P array, 2 barriers/tile.
//   k3   MFMA: per 32-row block, heads sequential: NUM=qp16@kvs_h (hi/lo), den VALU,
//        combine -> zl; out = zl@Wo (hi/lo 3-pass) + bo (f32)

#define NEPS  1e-6f
#define RATIO 0.18257418583505536f   // 1/sqrt(30)
#define DNORM 0.35355339059327378f   // 64^-0.25

typedef __attribute__((ext_vector_type(8))) short short8;
typedef __attribute__((ext_vector_type(4))) float floatx4;

__device__ inline unsigned short f2bf(float x) {
    __hip_bfloat16 b = __float2bfloat16(x);
    return __builtin_bit_cast(unsigned short, b);
}
__device__ inline float bf2f(unsigned short h) {
    return __builtin_bit_cast(float, (unsigned int)h << 16);
}
__device__ inline void split2(float v, unsigned short& hi, unsigned short& lo) {
    unsigned short h = f2bf(v);
    hi = h; lo = f2bf(v - bf2f(h));
}

__global__ __launch_bounds__(256) void k0_zero(float* __restrict__ p, int count) {
    int id = blockIdx.x * 256 + threadIdx.x;
    if (id < count) p[id] = 0.f;
}

// ---- k_prep: fragment-ordered hi/lo splits (unchanged from round 7) ----
__global__ __launch_bounds__(256) void k_prep(
    const float* __restrict__ Wq, const float* __restrict__ Wk, const float* __restrict__ Wv,
    const float* __restrict__ proj, const float* __restrict__ Wo,
    unsigned short* __restrict__ Wfh, unsigned short* __restrict__ Wfl,
    unsigned short* __restrict__ Pfh, unsigned short* __restrict__ Pfl,
    unsigned short* __restrict__ Wofh, unsigned short* __restrict__ Wofl)
{
    const int b = blockIdx.x, t = threadIdx.x;
    if (b < 24) {
        const int slot = b * 256 + t;
        const int lane = slot & 63;
        const int ctks = slot >> 6;
        const int ct = ctks >> 1, ks = ctks & 1;
        const int col = ct * 16 + (lane & 15);
        const int k0 = ks * 32 + (lane >> 4) * 8;
        const float* W = (col < 256) ? Wq : (col < 512) ? Wk : Wv;
        const int cm = col & 255;
#pragma unroll
        for (int j = 0; j < 8; ++j) {
            float w = W[(k0 + j) * 256 + cm];
            unsigned short hi, lo; split2(w, hi, lo);
            Wfh[slot * 8 + j] = hi;
            Wfl[slot * 8 + j] = lo;
        }
    } else if (b == 24) {
        const int lane = t & 63;
        const int ctks = t >> 6;
        const int ct2 = ctks >> 1, ks = ctks & 1;
        const int m = ct2 * 16 + (lane & 15);
        const int k0 = ks * 32 + (lane >> 4) * 8;
#pragma unroll
        for (int j = 0; j < 8; ++j) {
            float p = (m < 30) ? proj[m * 64 + k0 + j] : 0.f;
            unsigned short hi, lo; split2(p, hi, lo);
            Pfh[t * 8 + j] = hi;
            Pfl[t * 8 + j] = lo;
        }
    } else {
        for (int idx = t; idx < 2048; idx += 256) {
            const int slot = idx >> 6, l = idx & 63;
            const int ct = slot >> 3, ks = slot & 7;
            const int col = ct * 16 + (l & 15);
            const int k0 = ks * 32 + (l >> 4) * 8;
#pragma unroll
            for (int j = 0; j < 8; ++j) {
                float w = Wo[(k0 + j) * 64 + col];
                unsigned short hi, lo; split2(w, hi, lo);
                Wofh[slot * 512 + l * 8 + j] = hi;
                Wofl[slot * 512 + l * 8 + j] = lo;
            }
        }
    }
}

// ---- k1: per 16-row tile, MFMA QKV + phi (hi/lo 3-pass) — unchanged from round 6 ----
__global__ __launch_bounds__(256) void k1_feat(
    const float* __restrict__ z,
    const float* __restrict__ bq, const float* __restrict__ bk, const float* __restrict__ bv,
    const unsigned short* __restrict__ Wfh, const unsigned short* __restrict__ Wfl,
    const unsigned short* __restrict__ Pfh, const unsigned short* __restrict__ Pfl,
    const float* __restrict__ tau,
    __hip_bfloat16* __restrict__ qp16, __hip_bfloat16* __restrict__ v16,
    float* __restrict__ argk, float* __restrict__ blockmax, int N)
{
    __shared__ alignas(16) unsigned short zh[16 * 72];
    __shared__ alignas(16) unsigned short zl_[16 * 72];
    __shared__ alignas(16) float qd[16 * 264];
    __shared__ alignas(16) float kd[16 * 264];
    __shared__ float ddq[16 * 128];
    __shared__ float ddk[16 * 128];
    __shared__ float dgq[64], dgk[64];
    __shared__ float qmx[64], kmx[64];

    const int t = threadIdx.x;
    const int n0 = blockIdx.x * 16;
    const int wave = t >> 6, lane = t & 63;
    const float dsc = rsqrtf(tau[0]) * DNORM;

    for (int i = t; i < 1024; i += 256) {
        int r = i >> 6, c = i & 63;
        float v = (n0 + r < N) ? z[(long)(n0 + r) * 64 + c] : 0.f;
        unsigned short hi, lo; split2(v, hi, lo);
        zh[r * 72 + c] = hi;
        zl_[r * 72 + c] = lo;
    }
    __syncthreads();

    {
        const int abase = (lane & 15) * 72 + (lane >> 4) * 8;
        short8 ah0 = *reinterpret_cast<const short8*>(&zh[abase]);
        short8 ah1 = *reinterpret_cast<const short8*>(&zh[abase + 32]);
        short8 al0 = *reinterpret_cast<const short8*>(&zl_[abase]);
        short8 al1 = *reinterpret_cast<const short8*>(&zl_[abase + 32]);
        const int row0 = (lane >> 4) * 4;
#pragma unroll 2
        for (int ci = 0; ci < 12; ++ci) {
            const int ct = wave * 12 + ci;
            short8 bh0 = *reinterpret_cast<const short8*>(&Wfh[(ct * 2 + 0) * 512 + lane * 8]);
            short8 bh1 = *reinterpret_cast<const short8*>(&Wfh[(ct * 2 + 1) * 512 + lane * 8]);
            short8 bl0 = *reinterpret_cast<const short8*>(&Wfl[(ct * 2 + 0) * 512 + lane * 8]);
            short8 bl1 = *reinterpret_cast<const short8*>(&Wfl[(ct * 2 + 1) * 512 + lane * 8]);
            floatx4 acc = floatx4{0.f, 0.f, 0.f, 0.f};
            acc = __builtin_amdgcn_mfma_f32_16x16x32_bf16(ah0, bh0, acc, 0, 0, 0);
            acc = __builtin_amdgcn_mfma_f32_16x16x32_bf16(ah1, bh1, acc, 0, 0, 0);
            acc = __builtin_amdgcn_mfma_f32_16x16x32_bf16(ah0, bl0, acc, 0, 0, 0);
            acc = __builtin_amdgcn_mfma_f32_16x16x32_bf16(ah1, bl1, acc, 0, 0, 0);
            acc = __builtin_amdgcn_mfma_f32_16x16x32_bf16(al0, bh0, acc, 0, 0, 0);
            acc = __builtin_amdgcn_mfma_f32_16x16x32_bf16(al1, bh1, acc, 0, 0, 0);
            const int c = ct * 16 + (lane & 15);
            if (c < 256) {
                const float bb = bq[c];
#pragma unroll
                for (int r = 0; r < 4; ++r) qd[(row0 + r) * 264 + c] = (acc[r] + bb) * dsc;
            } else if (c < 512) {
                const float bb = bk[c - 256];
#pragma unroll
                for (int r = 0; r < 4; ++r) kd[(row0 + r) * 264 + (c - 256)] = (acc[r] + bb) * dsc;
            } else {
                const float bb = bv[c - 512];
#pragma unroll
                for (int r = 0; r < 4; ++r)
                    if (n0 + row0 + r < N)
                        v16[(long)(n0 + row0 + r) * 256 + (c - 512)] = __float2bfloat16(acc[r] + bb);
            }
        }
    }
    __syncthreads();

    {
        short8 pbh[2][2], pbl[2][2];
#pragma unroll
        for (int ct2 = 0; ct2 < 2; ++ct2)
#pragma unroll
            for (int ks = 0; ks < 2; ++ks) {
                pbh[ct2][ks] = *reinterpret_cast<const short8*>(&Pfh[(ct2 * 2 + ks) * 512 + lane * 8]);
                pbl[ct2][ks] = *reinterpret_cast<const short8*>(&Pfl[(ct2 * 2 + ks) * 512 + lane * 8]);
            }
        const int h = wave;
        const int row0 = (lane >> 4) * 4;
#pragma unroll
        for (int side = 0; side < 2; ++side) {
            const float* dat = side ? kd : qd;
            float* dd = side ? ddk : ddq;
            const int rbase = (lane & 15) * 264 + h * 64 + (lane >> 4) * 8;
            float xv[8], yv[8];
            {
                float4 x0 = *reinterpret_cast<const float4*>(&dat[rbase]);
                float4 x1 = *reinterpret_cast<const float4*>(&dat[rbase + 4]);
                float4 y0 = *reinterpret_cast<const float4*>(&dat[rbase + 32]);
                float4 y1 = *reinterpret_cast<const float4*>(&dat[rbase + 36]);
                xv[0]=x0.x; xv[1]=x0.y; xv[2]=x0.z; xv[3]=x0.w;
                xv[4]=x1.x; xv[5]=x1.y; xv[6]=x1.z; xv[7]=x1.w;
                yv[0]=y0.x; yv[1]=y0.y; yv[2]=y0.z; yv[3]=y0.w;
                yv[4]=y1.x; yv[5]=y1.y; yv[6]=y1.z; yv[7]=y1.w;
            }
            short8 ah0, al0, ah1, al1;
#pragma unroll
            for (int j = 0; j < 8; ++j) {
                unsigned short hi, lo;
                split2(xv[j], hi, lo); ah0[j] = (short)hi; al0[j] = (short)lo;
                split2(yv[j], hi, lo); ah1[j] = (short)hi; al1[j] = (short)lo;
            }
#pragma unroll
            for (int ct2 = 0; ct2 < 2; ++ct2) {
                floatx4 acc = floatx4{0.f, 0.f, 0.f, 0.f};
                acc = __builtin_amdgcn_mfma_f32_16x16x32_bf16(ah0, pbh[ct2][0], acc, 0, 0, 0);
                acc = __builtin_amdgcn_mfma_f32_16x16x32_bf16(ah1, pbh[ct2][1], acc, 0, 0, 0);
                acc = __builtin_amdgcn_mfma_f32_16x16x32_bf16(ah0, pbl[ct2][0], acc, 0, 0, 0);
                acc = __builtin_amdgcn_mfma_f32_16x16x32_bf16(ah1, pbl[ct2][1], acc, 0, 0, 0);
                acc = __builtin_amdgcn_mfma_f32_16x16x32_bf16(al0, pbh[ct2][0], acc, 0, 0, 0);
                acc = __builtin_amdgcn_mfma_f32_16x16x32_bf16(al1, pbh[ct2][1], acc, 0, 0, 0);
#pragma unroll
                for (int r = 0; r < 4; ++r)
                    dd[(row0 + r) * 128 + h * 32 + ct2 * 16 + (lane & 15)] = acc[r];
            }
        }
    }
    if (t < 128) {
        const int h = t >> 5, row = (t >> 1) & 15, side = t & 1;
        const float* dat = side ? kd : qd;
        float s = 0.f;
        for (int d = 0; d < 64; ++d) { float x = dat[row * 264 + h * 64 + d]; s += x * x; }
        (side ? dgk : dgq)[h * 16 + row] = 0.5f * s;
    }
    __syncthreads();

    if (t < 64) {
        const int h = t >> 4, row = t & 15;
        float mx = ddq[row * 128 + h * 32];
        for (int m = 1; m < 30; ++m) mx = fmaxf(mx, ddq[row * 128 + h * 32 + m]);
        qmx[t] = mx;
    } else if (t < 128) {
        const int u = t - 64, h = u >> 4, row = u & 15;
        float mx = -3.4e38f;
        if (n0 + row < N)
            for (int m = 0; m < 30; ++m) mx = fmaxf(mx, ddk[row * 128 + h * 32 + m]);
        kmx[u] = mx;
    }
    __syncthreads();

    if (t < 4) {
        float mx = kmx[t * 16];
        for (int row = 1; row < 16; ++row) mx = fmaxf(mx, kmx[t * 16 + row]);
        blockmax[blockIdx.x * 4 + t] = mx;
    }
    for (int idx = t; idx < 1920; idx += 256) {
        const int row = idx / 120, r = idx % 120, h = r / 30, m = r % 30;
        if (n0 + row < N) {
            float val = RATIO * (expf(ddq[row * 128 + h * 32 + m] - dgq[h * 16 + row] - qmx[h * 16 + row]) + NEPS);
            qp16[(long)(n0 + row) * 120 + r] = __float2bfloat16(val);
            argk[(long)(n0 + row) * 120 + r] = ddk[row * 128 + h * 32 + m] - dgk[h * 16 + row];
        }
    }
}

__global__ __launch_bounds__(256) void k1b_redmax(
    const float* __restrict__ blockmax, float* __restrict__ headmax, int ntiles)
{
    __shared__ float red[4 * 256];
    const int t = threadIdx.x;
    float lm[4] = {-3.4e38f, -3.4e38f, -3.4e38f, -3.4e38f};
    for (int i = t; i < ntiles; i += 256) {
#pragma unroll
        for (int hh = 0; hh < 4; ++hh) lm[hh] = fmaxf(lm[hh], blockmax[i * 4 + hh]);
    }
#pragma unroll
    for (int hh = 0; hh < 4; ++hh) red[hh * 256 + t] = lm[hh];
    __syncthreads();
    if (t < 4) {
        float mx = red[t * 256];
        for (int i = 1; i < 256; ++i) mx = fmaxf(mx, red[t * 256 + i]);
        headmax[t] = mx;
    }
}

// ---- k2: MFMA accumulate with register-built A-fragments (no P array) ----
// kpL[n][m] f32 stride 33; geT[k][n] f32 stride 72 (rows 10-12 zeroed);
// Vt[d'][n] bf16 stride 72 (row 64 = ones, 65-79 zero).
// 4 waves; wave w owns km-tiles ct=5w..5w+4 x 5 d-tiles; acc[5][5] f32x4.
// A-frag: lane l, frag (q,nh): row=ct*16+(l&15) -> m=row%30,k=row/30 (lane consts);
//         n = nh*32+(l>>4)*8+j -> a[j]=bf16(kpL[n][m]*geT[k][n]).
__global__ __launch_bounds__(256) void k2_kvs(
    const float* __restrict__ argk, const float* __restrict__ gum,
    const __hip_bfloat16* __restrict__ v16, const float* __restrict__ tau,
    const float* __restrict__ headmax,
    float* __restrict__ kvs, float* __restrict__ kssum, int N, int nchunk)
{
    __shared__ alignas(16) unsigned short Vt[80 * 72];   // 23040 B
    __shared__ float kpL[64 * 33];                       //  8448 B
    __shared__ alignas(16) float geT[13 * 72];           //  3744 B

    const int t = threadIdx.x;
    const int h = blockIdx.x >> 7;       // 4 heads x 128 chunks
    const int chunk = blockIdx.x & 127;
    const int n0 = chunk * nchunk;
    const int n1 = (n0 + nchunk < N) ? (n0 + nchunk) : N;
    const float MX = headmax[h];
    const float itau = 1.0f / tau[0];
    const int wave = t >> 6, lane = t & 63;
    const int l15 = lane & 15, l4 = lane >> 4;

    floatx4 acc[5][5];
#pragma unroll
    for (int q = 0; q < 5; ++q)
#pragma unroll
        for (int dt = 0; dt < 5; ++dt) acc[q][dt] = floatx4{0.f, 0.f, 0.f, 0.f};

    // per-lane constants for the 5 owned km-rows
    int mq[5], kq[5];
#pragma unroll
    for (int q = 0; q < 5; ++q) {
        int row = (wave * 5 + q) * 16 + l15;
        mq[q] = row % 30;
        kq[q] = row / 30;                // <= 10; geT row 10..12 are zeros
    }

    if (t < 64) Vt[64 * 72 + t] = f2bf(1.0f);          // ones row -> kssum column
    for (int i = t; i < 15 * 72; i += 256) Vt[65 * 72 + i] = 0;
    for (int i = t; i < 3 * 72; i += 256) geT[10 * 72 + i] = 0.f;

    const int ntile = (n1 - n0 + 63) >> 6;
    for (int tt = 0; tt < ntile; ++tt) {
        const int nb = n0 + tt * 64;
        __syncthreads();                               // B0: prev MFMA reads done
        // stage kp (n-major, stride 33)
        for (int i = t; i < 1920; i += 256) {
            int r = i / 30, m = i % 30;
            kpL[r * 33 + m] = (nb + r < n1)
                ? RATIO * (expf(argk[(long)(nb + r) * 120 + h * 30 + m] - MX) + NEPS) : 0.f;
        }
        // stage ge transposed: [k][n] stride 72 (n-contiguous for float4 reads)
        for (int i = t; i < 640; i += 256) {
            int k = i >> 6, n = i & 63;
            geT[k * 72 + n] = (nb + n < n1)
                ? expf(gum[(long)(nb + n) * 40 + h * 10 + k] * itau) : 0.f;
        }
        // stage Vt
        for (int i = t; i < 2048; i += 256) {
            int n = i >> 5, dp = (i & 31) * 2;
            unsigned int u = (nb + n < n1)
                ? *reinterpret_cast<const unsigned int*>(v16 + (long)(nb + n) * 256 + h * 64 + dp)
                : 0u;
            Vt[dp * 72 + n] = (unsigned short)(u & 0xffffu);
            Vt[(dp + 1) * 72 + n] = (unsigned short)(u >> 16);
        }
        __syncthreads();                               // B1: staging ready
#pragma unroll
        for (int nh = 0; nh < 2; ++nh) {
            const int nbase = nh * 32 + l4 * 8;
            short8 b[5];
#pragma unroll
            for (int dt = 0; dt < 5; ++dt)
                b[dt] = *reinterpret_cast<const short8*>(&Vt[(dt * 16 + l15) * 72 + nbase]);
#pragma unroll
            for (int q = 0; q < 5; ++q) {
                float4 g0 = *reinterpret_cast<const float4*>(&geT[kq[q] * 72 + nbase]);
                float4 g1 = *reinterpret_cast<const float4*>(&geT[kq[q] * 72 + nbase + 4]);
                const float gg[8] = {g0.x, g0.y, g0.z, g0.w, g1.x, g1.y, g1.z, g1.w};
                short8 a;
#pragma unroll
                for (int j = 0; j < 8; ++j) {
                    float kp = kpL[(nbase + j) * 33 + mq[q]];
                    a[j] = (short)f2bf(kp * gg[j]);
                }
#pragma unroll
                for (int dt = 0; dt < 5; ++dt)
                    acc[q][dt] = __builtin_amdgcn_mfma_f32_16x16x32_bf16(a, b[dt], acc[q][dt], 0, 0, 0);
            }
        }
    }

    // flush: D[row=(l4)*4+r][col=l15]
    float* kvh = kvs + h * 19200;
#pragma unroll
    for (int q = 0; q < 5; ++q) {
        const int kmb = (wave * 5 + q) * 16 + l4 * 4;
#pragma unroll
        for (int r = 0; r < 4; ++r) {
            const int km = kmb + r;
            if (km < 300) {
#pragma unroll
                for (int dt = 0; dt < 4; ++dt)
                    atomicAdd(&kvh[km * 64 + dt * 16 + l15], acc[q][dt][r]);
                if (l15 == 0)
                    atomicAdd(&kssum[h * 300 + km], acc[q][4][r]);
            }
        }
    }
}

// ---- k3: MFMA numerator + Wo (unchanged from round 7) ----
__global__ __launch_bounds__(512) void k3_out(
    const __hip_bfloat16* __restrict__ qp16, const float* __restrict__ kvs,
    const float* __restrict__ kssum,
    const unsigned short* __restrict__ Wofh, const unsigned short* __restrict__ Wofl,
    const float* __restrict__ bo, float* __restrict__ out, int N)
{
    __shared__ alignas(16) float U[32 * 656];
    __shared__ alignas(16) float zl[32 * 260];
    __shared__ float qpl[32 * 30];
    __shared__ float idl[320];
    __shared__ float ksl[300];

    unsigned short* Bfh = reinterpret_cast<unsigned short*>(U);
    unsigned short* Bfl = Bfh + 20480;

    const int t = threadIdx.x;
    const int n0 = blockIdx.x * 32;
    const int wave = t >> 6, lane = t & 63;

    for (int h = 0; h < 4; ++h) {
        __syncthreads();
        {
            const float* kvh = kvs + h * 19200;
            for (int idx = t; idx < 2560; idx += 512) {
                const int ct = idx >> 6, l = idx & 63;
                const int col = ct * 16 + (l & 15);
                const int k = col >> 6, d = col & 63;
                const int mb = (l >> 4) * 8;
                const float* src = kvh + (k * 30 + mb) * 64 + d;
                short8 hi, lo;
#pragma unroll
                for (int j = 0; j < 8; ++j) {
                    float v = src[j * 64];
                    unsigned short h2, l2; split2(v, h2, l2);
                    hi[j] = (short)h2; lo[j] = (short)l2;
                }
                *reinterpret_cast<short8*>(&Bfh[idx * 8]) = hi;
                *reinterpret_cast<short8*>(&Bfl[idx * 8]) = lo;
            }
        }
        if (t < 300) ksl[t] = kssum[h * 300 + t];
        for (int i = t; i < 960; i += 512) {
            int rr = i / 30, m = i % 30;
            int n = n0 + rr; if (n >= N) n = N - 1;
            qpl[i] = bf2f(((const unsigned short*)qp16)[(long)n * 120 + h * 30 + m]);
        }
        __syncthreads();

        short8 aQ[2];
#pragma unroll
        for (int rt = 0; rt < 2; ++rt) {
            int n = n0 + rt * 16 + (lane & 15); if (n >= N) n = N - 1;
            const unsigned int* qrow = reinterpret_cast<const unsigned int*>(
                (const unsigned short*)qp16 + (long)n * 120 + h * 30 + (lane >> 4) * 8);
            short8 a;
#pragma unroll
            for (int jj = 0; jj < 4; ++jj) {
                unsigned int u = qrow[jj];
                a[jj * 2] = (short)(u & 0xffffu);
                a[jj * 2 + 1] = (short)(u >> 16);
            }
            if ((lane >> 4) == 3) { a[6] = 0; a[7] = 0; }
            aQ[rt] = a;
        }
        floatx4 acc[2][5];
#pragma unroll
        for (int rt = 0; rt < 2; ++rt)
#pragma unroll
            for (int q = 0; q < 5; ++q) acc[rt][q] = floatx4{0.f, 0.f, 0.f, 0.f};
#pragma unroll
        for (int q = 0; q < 5; ++q) {
            const int ct = wave * 5 + q;
            short8 bh = *reinterpret_cast<const short8*>(&Bfh[(ct * 64 + lane) * 8]);
            short8 bl = *reinterpret_cast<const short8*>(&Bfl[(ct * 64 + lane) * 8]);
            acc[0][q] = __builtin_amdgcn_mfma_f32_16x16x32_bf16(aQ[0], bh, acc[0][q], 0, 0, 0);
            acc[0][q] = __builtin_amdgcn_mfma_f32_16x16x32_bf16(aQ[0], bl, acc[0][q], 0, 0, 0);
            acc[1][q] = __builtin_amdgcn_mfma_f32_16x16x32_bf16(aQ[1], bh, acc[1][q], 0, 0, 0);
            acc[1][q] = __builtin_amdgcn_mfma_f32_16x16x32_bf16(aQ[1], bl, acc[1][q], 0, 0, 0);
        }
        if (t < 320) {
            const int rr = t / 10, kk = t % 10;
            float s = 0.f;
#pragma unroll
            for (int m = 0; m < 30; ++m) s += qpl[rr * 30 + m] * ksl[kk * 30 + m];
            idl[t] = 1.0f / s;
        }
        __syncthreads();
#pragma unroll
        for (int rt = 0; rt < 2; ++rt)
#pragma unroll
            for (int q = 0; q < 5; ++q) {
                const int ct = wave * 5 + q;
                const int row = rt * 16 + (lane >> 4) * 4;
                const int col = ct * 16 + (lane & 15);
#pragma unroll
                for (int r = 0; r < 4; ++r)
                    U[(row + r) * 656 + col] = acc[rt][q][r];
            }
        __syncthreads();
        {
            const int row = t >> 4, dd = t & 15;
            const float4* U4 = reinterpret_cast<const float4*>(U);
            float4 s = float4{0.f, 0.f, 0.f, 0.f};
#pragma unroll
            for (int k = 0; k < 10; ++k) {
                float4 nm = U4[row * 164 + k * 16 + dd];
                float w = idl[row * 10 + k];
                s.x += nm.x * w; s.y += nm.y * w; s.z += nm.z * w; s.w += nm.w * w;
            }
            float4 zv; zv.x = 0.1f * s.x; zv.y = 0.1f * s.y; zv.z = 0.1f * s.z; zv.w = 0.1f * s.w;
            reinterpret_cast<float4*>(zl)[row * 65 + h * 16 + dd] = zv;
        }
    }
    __syncthreads();
    {
        const int rt = wave >> 2, ct = wave & 3;
        floatx4 o = floatx4{0.f, 0.f, 0.f, 0.f};
#pragma unroll
        for (int ks = 0; ks < 8; ++ks) {
            const float* zr = &zl[(rt * 16 + (lane & 15)) * 260 + ks * 32 + (lane >> 4) * 8];
            float4 x0 = *reinterpret_cast<const float4*>(zr);
            float4 x1 = *reinterpret_cast<const float4*>(zr + 4);
            float xv[8] = {x0.x, x0.y, x0.z, x0.w, x1.x, x1.y, x1.z, x1.w};
            short8 ah, al;
#pragma unroll
            for (int j = 0; j < 8; ++j) {
                unsigned short hi, lo; split2(xv[j], hi, lo);
                ah[j] = (short)hi; al[j] = (short)lo;
            }
            const int slot = ct * 8 + ks;
            short8 bh = *reinterpret_cast<const short8*>(&Wofh[slot * 512 + lane * 8]);
            short8 bl = *reinterpret_cast<const short8*>(&Wofl[slot * 512 + lane * 8]);
            o = __builtin_amdgcn_mfma_f32_16x16x32_bf16(ah, bh, o, 0, 0, 0);
            o = __builtin_amdgcn_mfma_f32_16x16x32_bf16(ah, bl, o, 0, 0, 0);
            o = __builtin_amdgcn_mfma_f32_16x16x32_bf16(al, bh, o, 0, 0, 0);
        }
        const int col = ct * 16 + (lane & 15);
        const float bb = bo[col];
#pragma unroll
        for (int r = 0; r < 4; ++r) {
            const int n = n0 + rt * 16 + (lane >> 4) * 4 + r;
            if (n < N) out[(long)n * 64 + col] = o[r] + bb;
        }
    }
}

extern "C" void kernel_launch(void* const* d_in, const int* in_sizes, int n_in,
                              void* d_out, int out_size, void* d_ws, size_t ws_size,
                              hipStream_t stream)
{
    const float* z    = (const float*)d_in[0];
    const float* Wq   = (const float*)d_in[1];
    const float* bq   = (const float*)d_in[2];
    const float* Wk   = (const float*)d_in[3];
    const float* bk   = (const float*)d_in[4];
    const float* Wv   = (const float*)d_in[5];
    const float* bv   = (const float*)d_in[6];
    const float* Wo   = (const float*)d_in[7];
    const float* bo   = (const float*)d_in[8];
    const float* proj = (const float*)d_in[9];
    const float* gum  = (const float*)d_in[10];
    const float* tau  = (const float*)d_in[11];
    float* out = (float*)d_out;

    const int N = in_sizes[0] / 64;          // 50000
    const int ntiles = (N + 15) / 16;        // 3125
    const int nchunk = (N + 127) / 128;      // 391
    const int nblk3  = (N + 31) / 32;        // 1563

    char* wsb = (char*)d_ws;
    size_t off = 0;
    __hip_bfloat16* qp16 = (__hip_bfloat16*)(wsb);
    off += ((size_t)N * 120 * 2 + 255) & ~(size_t)255;
    __hip_bfloat16* v16 = (__hip_bfloat16*)(wsb + off);
    off += ((size_t)N * 256 * 2 + 255) & ~(size_t)255;
    float* argk = (float*)(wsb + off);
    off += ((size_t)N * 120 * 4 + 255) & ~(size_t)255;
    float* kvs      = (float*)(wsb + off);
    float* kssum    = kvs + 76800;
    float* headmax  = kssum + 1200;
    float* blockmax = headmax + 4;
    off += ((size_t)(76800 + 1200 + 4 + (size_t)ntiles * 4) * 4 + 255) & ~(size_t)255;
    unsigned short* Wfh = (unsigned short*)(wsb + off); off += 49152 * 2;
    unsigned short* Wfl = (unsigned short*)(wsb + off); off += 49152 * 2;
    unsigned short* Pfh = (unsigned short*)(wsb + off); off += 2048 * 2;
    unsigned short* Pfl = (unsigned short*)(wsb + off); off += 2048 * 2;
    unsigned short* Wofh = (unsigned short*)(wsb + off); off += 16384 * 2;
    unsigned short* Wofl = (unsigned short*)(wsb + off);

    k_prep<<<dim3(26), dim3(256), 0, stream>>>(Wq, Wk, Wv, proj, Wo,
                                               Wfh, Wfl, Pfh, Pfl, Wofh, Wofl);
    k0_zero<<<dim3((78000 + 255) / 256), dim3(256), 0, stream>>>(kvs, 78000);
    k1_feat<<<dim3(ntiles), dim3(256), 0, stream>>>(z, bq, bk, bv, Wfh, Wfl, Pfh, Pfl, tau,
                                                    qp16, v16, argk, blockmax, N);
    k1b_redmax<<<dim3(1), dim3(256), 0, stream>>>(blockmax, headmax, ntiles);
    k2_kvs<<<dim3(512), dim3(256), 0, stream>>>(argk, gum, v16, tau, headmax,
                                                kvs, kssum, N, nchunk);
    k3_out<<<dim3(nblk3), dim3(512), 0, stream>>>(qp16, kvs, kssum, Wofh, Wofl, bo, out, N);
}

// Round 9
// 357.186 us; speedup vs baseline: 19.5792x; 1.1409x over previous
//
#include <hip/hip_runtime.h>
#include <hip/hip_bf16.h>

// NodeFormerConv: Performer/Gumbel attention. fp32-equivalent math, fp32 output.
//   k_prep: split Wq|Wk|Wv, proj, Wo into MFMA-fragment-ordered hi/lo bf16
//   k0   zero kvs[4][300][64] + kssum[4][300]
//   k1   per 16-row tile, MFMA (hi/lo 3-pass): QKV gemm -> qd/kd LDS + v16;
//        phi gemm -> ddq/ddk; diag; exp -> qp16, argk, blockmax
//   k1b  blockmax -> headmax[4]
//   k2   MFMA accumulate, batched+prefetched staging: tile loads land in regs
//        (unrolled, one waitcnt), next tile issued under the MFMA phase;
//        A-frags built in regs from kpL/geT; B=Vt (+ones row).
//   k3   MFMA: per 32-row block, heads sequential: NUM=qp16@kvs_h (hi/lo), den VALU,
//        combine -> zl; out = zl@Wo (hi/lo 3-pass) + bo (f32)

#define NEPS  1e-6f
#define RATIO 0.18257418583505536f   // 1/sqrt(30)
#define DNORM 0.35355339059327378f   // 64^-0.25

typedef __attribute__((ext_vector_type(8))) short short8;
typedef __attribute__((ext_vector_type(4))) float floatx4;

__device__ inline unsigned short f2bf(float x) {
    __hip_bfloat16 b = __float2bfloat16(x);
    return __builtin_bit_cast(unsigned short, b);
}
__device__ inline float bf2f(unsigned short h) {
    return __builtin_bit_cast(float, (unsigned int)h << 16);
}
__device__ inline void split2(float v, unsigned short& hi, unsigned short& lo) {
    unsigned short h = f2bf(v);
    hi = h; lo = f2bf(v - bf2f(h));
}

__global__ __launch_bounds__(256) void k0_zero(float* __restrict__ p, int count) {
    int id = blockIdx.x * 256 + threadIdx.x;
    if (id < count) p[id] = 0.f;
}

// ---- k_prep: fragment-ordered hi/lo splits (unchanged) ----
__global__ __launch_bounds__(256) void k_prep(
    const float* __restrict__ Wq, const float* __restrict__ Wk, const float* __restrict__ Wv,
    const float* __restrict__ proj, const float* __restrict__ Wo,
    unsigned short* __restrict__ Wfh, unsigned short* __restrict__ Wfl,
    unsigned short* __restrict__ Pfh, unsigned short* __restrict__ Pfl,
    unsigned short* __restrict__ Wofh, unsigned short* __restrict__ Wofl)
{
    const int b = blockIdx.x, t = threadIdx.x;
    if (b < 24) {
        const int slot = b * 256 + t;
        const int lane = slot & 63;
        const int ctks = slot >> 6;
        const int ct = ctks >> 1, ks = ctks & 1;
        const int col = ct * 16 + (lane & 15);
        const int k0 = ks * 32 + (lane >> 4) * 8;
        const float* W = (col < 256) ? Wq : (col < 512) ? Wk : Wv;
        const int cm = col & 255;
#pragma unroll
        for (int j = 0; j < 8; ++j) {
            float w = W[(k0 + j) * 256 + cm];
            unsigned short hi, lo; split2(w, hi, lo);
            Wfh[slot * 8 + j] = hi;
            Wfl[slot * 8 + j] = lo;
        }
    } else if (b == 24) {
        const int lane = t & 63;
        const int ctks = t >> 6;
        const int ct2 = ctks >> 1, ks = ctks & 1;
        const int m = ct2 * 16 + (lane & 15);
        const int k0 = ks * 32 + (lane >> 4) * 8;
#pragma unroll
        for (int j = 0; j < 8; ++j) {
            float p = (m < 30) ? proj[m * 64 + k0 + j] : 0.f;
            unsigned short hi, lo; split2(p, hi, lo);
            Pfh[t * 8 + j] = hi;
            Pfl[t * 8 + j] = lo;
        }
    } else {
        for (int idx = t; idx < 2048; idx += 256) {
            const int slot = idx >> 6, l = idx & 63;
            const int ct = slot >> 3, ks = slot & 7;
            const int col = ct * 16 + (l & 15);
            const int k0 = ks * 32 + (l >> 4) * 8;
#pragma unroll
            for (int j = 0; j < 8; ++j) {
                float w = Wo[(k0 + j) * 64 + col];
                unsigned short hi, lo; split2(w, hi, lo);
                Wofh[slot * 512 + l * 8 + j] = hi;
                Wofl[slot * 512 + l * 8 + j] = lo;
            }
        }
    }
}

// ---- k1: per 16-row tile, MFMA QKV + phi (hi/lo 3-pass) — unchanged ----
__global__ __launch_bounds__(256) void k1_feat(
    const float* __restrict__ z,
    const float* __restrict__ bq, const float* __restrict__ bk, const float* __restrict__ bv,
    const unsigned short* __restrict__ Wfh, const unsigned short* __restrict__ Wfl,
    const unsigned short* __restrict__ Pfh, const unsigned short* __restrict__ Pfl,
    const float* __restrict__ tau,
    __hip_bfloat16* __restrict__ qp16, __hip_bfloat16* __restrict__ v16,
    float* __restrict__ argk, float* __restrict__ blockmax, int N)
{
    __shared__ alignas(16) unsigned short zh[16 * 72];
    __shared__ alignas(16) unsigned short zl_[16 * 72];
    __shared__ alignas(16) float qd[16 * 264];
    __shared__ alignas(16) float kd[16 * 264];
    __shared__ float ddq[16 * 128];
    __shared__ float ddk[16 * 128];
    __shared__ float dgq[64], dgk[64];
    __shared__ float qmx[64], kmx[64];

    const int t = threadIdx.x;
    const int n0 = blockIdx.x * 16;
    const int wave = t >> 6, lane = t & 63;
    const float dsc = rsqrtf(tau[0]) * DNORM;

    for (int i = t; i < 1024; i += 256) {
        int r = i >> 6, c = i & 63;
        float v = (n0 + r < N) ? z[(long)(n0 + r) * 64 + c] : 0.f;
        unsigned short hi, lo; split2(v, hi, lo);
        zh[r * 72 + c] = hi;
        zl_[r * 72 + c] = lo;
    }
    __syncthreads();

    {
        const int abase = (lane & 15) * 72 + (lane >> 4) * 8;
        short8 ah0 = *reinterpret_cast<const short8*>(&zh[abase]);
        short8 ah1 = *reinterpret_cast<const short8*>(&zh[abase + 32]);
        short8 al0 = *reinterpret_cast<const short8*>(&zl_[abase]);
        short8 al1 = *reinterpret_cast<const short8*>(&zl_[abase + 32]);
        const int row0 = (lane >> 4) * 4;
#pragma unroll 2
        for (int ci = 0; ci < 12; ++ci) {
            const int ct = wave * 12 + ci;
            short8 bh0 = *reinterpret_cast<const short8*>(&Wfh[(ct * 2 + 0) * 512 + lane * 8]);
            short8 bh1 = *reinterpret_cast<const short8*>(&Wfh[(ct * 2 + 1) * 512 + lane * 8]);
            short8 bl0 = *reinterpret_cast<const short8*>(&Wfl[(ct * 2 + 0) * 512 + lane * 8]);
            short8 bl1 = *reinterpret_cast<const short8*>(&Wfl[(ct * 2 + 1) * 512 + lane * 8]);
            floatx4 acc = floatx4{0.f, 0.f, 0.f, 0.f};
            acc = __builtin_amdgcn_mfma_f32_16x16x32_bf16(ah0, bh0, acc, 0, 0, 0);
            acc = __builtin_amdgcn_mfma_f32_16x16x32_bf16(ah1, bh1, acc, 0, 0, 0);
            acc = __builtin_amdgcn_mfma_f32_16x16x32_bf16(ah0, bl0, acc, 0, 0, 0);
            acc = __builtin_amdgcn_mfma_f32_16x16x32_bf16(ah1, bl1, acc, 0, 0, 0);
            acc = __builtin_amdgcn_mfma_f32_16x16x32_bf16(al0, bh0, acc, 0, 0, 0);
            acc = __builtin_amdgcn_mfma_f32_16x16x32_bf16(al1, bh1, acc, 0, 0, 0);
            const int c = ct * 16 + (lane & 15);
            if (c < 256) {
                const float bb = bq[c];
#pragma unroll
                for (int r = 0; r < 4; ++r) qd[(row0 + r) * 264 + c] = (acc[r] + bb) * dsc;
            } else if (c < 512) {
                const float bb = bk[c - 256];
#pragma unroll
                for (int r = 0; r < 4; ++r) kd[(row0 + r) * 264 + (c - 256)] = (acc[r] + bb) * dsc;
            } else {
                const float bb = bv[c - 512];
#pragma unroll
                for (int r = 0; r < 4; ++r)
                    if (n0 + row0 + r < N)
                        v16[(long)(n0 + row0 + r) * 256 + (c - 512)] = __float2bfloat16(acc[r] + bb);
            }
        }
    }
    __syncthreads();

    {
        short8 pbh[2][2], pbl[2][2];
#pragma unroll
        for (int ct2 = 0; ct2 < 2; ++ct2)
#pragma unroll
            for (int ks = 0; ks < 2; ++ks) {
                pbh[ct2][ks] = *reinterpret_cast<const short8*>(&Pfh[(ct2 * 2 + ks) * 512 + lane * 8]);
                pbl[ct2][ks] = *reinterpret_cast<const short8*>(&Pfl[(ct2 * 2 + ks) * 512 + lane * 8]);
            }
        const int h = wave;
        const int row0 = (lane >> 4) * 4;
#pragma unroll
        for (int side = 0; side < 2; ++side) {
            const float* dat = side ? kd : qd;
            float* dd = side ? ddk : ddq;
            const int rbase = (lane & 15) * 264 + h * 64 + (lane >> 4) * 8;
            float xv[8], yv[8];
            {
                float4 x0 = *reinterpret_cast<const float4*>(&dat[rbase]);
                float4 x1 = *reinterpret_cast<const float4*>(&dat[rbase + 4]);
                float4 y0 = *reinterpret_cast<const float4*>(&dat[rbase + 32]);
                float4 y1 = *reinterpret_cast<const float4*>(&dat[rbase + 36]);
                xv[0]=x0.x; xv[1]=x0.y; xv[2]=x0.z; xv[3]=x0.w;
                xv[4]=x1.x; xv[5]=x1.y; xv[6]=x1.z; xv[7]=x1.w;
                yv[0]=y0.x; yv[1]=y0.y; yv[2]=y0.z; yv[3]=y0.w;
                yv[4]=y1.x; yv[5]=y1.y; yv[6]=y1.z; yv[7]=y1.w;
            }
            short8 ah0, al0, ah1, al1;
#pragma unroll
            for (int j = 0; j < 8; ++j) {
                unsigned short hi, lo;
                split2(xv[j], hi, lo); ah0[j] = (short)hi; al0[j] = (short)lo;
                split2(yv[j], hi, lo); ah1[j] = (short)hi; al1[j] = (short)lo;
            }
#pragma unroll
            for (int ct2 = 0; ct2 < 2; ++ct2) {
                floatx4 acc = floatx4{0.f, 0.f, 0.f, 0.f};
                acc = __builtin_amdgcn_mfma_f32_16x16x32_bf16(ah0, pbh[ct2][0], acc, 0, 0, 0);
                acc = __builtin_amdgcn_mfma_f32_16x16x32_bf16(ah1, pbh[ct2][1], acc, 0, 0, 0);
                acc = __builtin_amdgcn_mfma_f32_16x16x32_bf16(ah0, pbl[ct2][0], acc, 0, 0, 0);
                acc = __builtin_amdgcn_mfma_f32_16x16x32_bf16(ah1, pbl[ct2][1], acc, 0, 0, 0);
                acc = __builtin_amdgcn_mfma_f32_16x16x32_bf16(al0, pbh[ct2][0], acc, 0, 0, 0);
                acc = __builtin_amdgcn_mfma_f32_16x16x32_bf16(al1, pbh[ct2][1], acc, 0, 0, 0);
#pragma unroll
                for (int r = 0; r < 4; ++r)
                    dd[(row0 + r) * 128 + h * 32 + ct2 * 16 + (lane & 15)] = acc[r];
            }
        }
    }
    if (t < 128) {
        const int h = t >> 5, row = (t >> 1) & 15, side = t & 1;
        const float* dat = side ? kd : qd;
        float s = 0.f;
        for (int d = 0; d < 64; ++d) { float x = dat[row * 264 + h * 64 + d]; s += x * x; }
        (side ? dgk : dgq)[h * 16 + row] = 0.5f * s;
    }
    __syncthreads();

    if (t < 64) {
        const int h = t >> 4, row = t & 15;
        float mx = ddq[row * 128 + h * 32];
        for (int m = 1; m < 30; ++m) mx = fmaxf(mx, ddq[row * 128 + h * 32 + m]);
        qmx[t] = mx;
    } else if (t < 128) {
        const int u = t - 64, h = u >> 4, row = u & 15;
        float mx = -3.4e38f;
        if (n0 + row < N)
            for (int m = 0; m < 30; ++m) mx = fmaxf(mx, ddk[row * 128 + h * 32 + m]);
        kmx[u] = mx;
    }
    __syncthreads();

    if (t < 4) {
        float mx = kmx[t * 16];
        for (int row = 1; row < 16; ++row) mx = fmaxf(mx, kmx[t * 16 + row]);
        blockmax[blockIdx.x * 4 + t] = mx;
    }
    for (int idx = t; idx < 1920; idx += 256) {
        const int row = idx / 120, r = idx % 120, h = r / 30, m = r % 30;
        if (n0 + row < N) {
            float val = RATIO * (expf(ddq[row * 128 + h * 32 + m] - dgq[h * 16 + row] - qmx[h * 16 + row]) + NEPS);
            qp16[(long)(n0 + row) * 120 + r] = __float2bfloat16(val);
            argk[(long)(n0 + row) * 120 + r] = ddk[row * 128 + h * 32 + m] - dgk[h * 16 + row];
        }
    }
}

__global__ __launch_bounds__(256) void k1b_redmax(
    const float* __restrict__ blockmax, float* __restrict__ headmax, int ntiles)
{
    __shared__ float red[4 * 256];
    const int t = threadIdx.x;
    float lm[4] = {-3.4e38f, -3.4e38f, -3.4e38f, -3.4e38f};
    for (int i = t; i < ntiles; i += 256) {
#pragma unroll
        for (int hh = 0; hh < 4; ++hh) lm[hh] = fmaxf(lm[hh], blockmax[i * 4 + hh]);
    }
#pragma unroll
    for (int hh = 0; hh < 4; ++hh) red[hh * 256 + t] = lm[hh];
    __syncthreads();
    if (t < 4) {
        float mx = red[t * 256];
        for (int i = 1; i < 256; ++i) mx = fmaxf(mx, red[t * 256 + i]);
        headmax[t] = mx;
    }
}

// ---- k2: MFMA accumulate with batched + prefetched staging ----
// Staging per tile lands in regs (unrolled batch, one waitcnt); next tile's
// loads are issued right after the staging barrier so they fly under the
// A-build + 50 MFMAs. LDS layouts as round 8.
__global__ __launch_bounds__(256) void k2_kvs(
    const float* __restrict__ argk, const float* __restrict__ gum,
    const __hip_bfloat16* __restrict__ v16, const float* __restrict__ tau,
    const float* __restrict__ headmax,
    float* __restrict__ kvs, float* __restrict__ kssum, int N, int nchunk)
{
    __shared__ alignas(16) unsigned short Vt[80 * 72];   // 11520 B
    __shared__ float kpL[64 * 33];                       //  8448 B
    __shared__ alignas(16) float geT[13 * 72];           //  3744 B

    const int t = threadIdx.x;
    const int h = blockIdx.x >> 7;       // 4 heads x 128 chunks
    const int chunk = blockIdx.x & 127;
    const int n0 = chunk * nchunk;
    const int n1 = (n0 + nchunk < N) ? (n0 + nchunk) : N;
    const float MX = headmax[h];
    const float itau = 1.0f / tau[0];
    const int wave = t >> 6, lane = t & 63;
    const int l15 = lane & 15, l4 = lane >> 4;

    // per-thread staging coordinates (loop-invariant)
    int ar_r[8], ar_m[8];                 // argk: i = t + 256u, i < 1920
#pragma unroll
    for (int u = 0; u < 8; ++u) { int i = t + 256 * u; ar_r[u] = i / 30; ar_m[u] = i % 30; }
    int gu_k[3], gu_n[3];                 // gum: i < 640
#pragma unroll
    for (int u = 0; u < 3; ++u) { int i = t + 256 * u; gu_k[u] = i >> 6; gu_n[u] = i & 63; }
    int v_n[8], v_dp[8];                  // v16: i < 2048
#pragma unroll
    for (int u = 0; u < 8; ++u) { int i = t + 256 * u; v_n[u] = i >> 5; v_dp[u] = (i & 31) * 2; }

    float ra[8], rg[3];
    unsigned int rv[8];

    floatx4 acc[5][5];
#pragma unroll
    for (int q = 0; q < 5; ++q)
#pragma unroll
        for (int dt = 0; dt < 5; ++dt) acc[q][dt] = floatx4{0.f, 0.f, 0.f, 0.f};

    int mq[5], kq[5];
#pragma unroll
    for (int q = 0; q < 5; ++q) {
        int row = (wave * 5 + q) * 16 + l15;
        mq[q] = row % 30;
        kq[q] = row / 30;                 // <= 10; geT rows 10..12 are zeros
    }

    if (t < 64) Vt[64 * 72 + t] = f2bf(1.0f);           // ones row -> kssum column
    for (int i = t; i < 15 * 72; i += 256) Vt[65 * 72 + i] = 0;
    for (int i = t; i < 3 * 72; i += 256) geT[10 * 72 + i] = 0.f;

    const int ntile = (n1 - n0 + 63) >> 6;

    // prologue: prefetch tile 0 (clamped addresses; validity re-derived at write)
#define K2_LOAD(nb_)                                                              \
    do {                                                                          \
        _Pragma("unroll")                                                         \
        for (int u = 0; u < 8; ++u) {                                             \
            int n = (nb_) + ar_r[u]; n = (n < n1) ? n : (n1 - 1);                  \
            ra[u] = argk[(long)n * 120 + h * 30 + ar_m[u]];                       \
        }                                                                         \
        _Pragma("unroll")                                                         \
        for (int u = 0; u < 3; ++u) {                                             \
            int n = (nb_) + gu_n[u]; n = (n < n1) ? n : (n1 - 1);                  \
            rg[u] = gum[(long)n * 40 + h * 10 + gu_k[u]];                         \
        }                                                                         \
        _Pragma("unroll")                                                         \
        for (int u = 0; u < 8; ++u) {                                             \
            int n = (nb_) + v_n[u]; n = (n < n1) ? n : (n1 - 1);                   \
            rv[u] = *reinterpret_cast<const unsigned int*>(                       \
                v16 + (long)n * 256 + h * 64 + v_dp[u]);                          \
        }                                                                         \
    } while (0)

    K2_LOAD(n0);

    for (int tt = 0; tt < ntile; ++tt) {
        const int nb = n0 + tt * 64;
        __syncthreads();                               // B0: prev MFMA reads done
        // write staged regs -> LDS (waitcnt on the batch happens here, once)
#pragma unroll
        for (int u = 0; u < 8; ++u) {
            if (u < 7 || t < 128) {                    // i < 1920
                bool ok = (nb + ar_r[u] < n1);
                kpL[ar_r[u] * 33 + ar_m[u]] =
                    ok ? RATIO * (__expf(ra[u] - MX) + NEPS) : 0.f;
            }
        }
#pragma unroll
        for (int u = 0; u < 3; ++u) {
            if (u < 2 || t < 128) {                    // i < 640
                bool ok = (nb + gu_n[u] < n1);
                geT[gu_k[u] * 72 + gu_n[u]] = ok ? __expf(rg[u] * itau) : 0.f;
            }
        }
#pragma unroll
        for (int u = 0; u < 8; ++u) {
            bool ok = (nb + v_n[u] < n1);
            unsigned int uu = ok ? rv[u] : 0u;
            Vt[v_dp[u] * 72 + v_n[u]] = (unsigned short)(uu & 0xffffu);
            Vt[(v_dp[u] + 1) * 72 + v_n[u]] = (unsigned short)(uu >> 16);
        }
        __syncthreads();                               // B1: staging visible
        if (tt + 1 < ntile) K2_LOAD(nb + 64);          // prefetch next tile (in flight)

        // A-build + MFMA (reads LDS of tile tt)
#pragma unroll
        for (int nh = 0; nh < 2; ++nh) {
            const int nbase = nh * 32 + l4 * 8;
            short8 b[5];
#pragma unroll
            for (int dt = 0; dt < 5; ++dt)
                b[dt] = *reinterpret_cast<const short8*>(&Vt[(dt * 16 + l15) * 72 + nbase]);
#pragma unroll
            for (int q = 0; q < 5; ++q) {
                float4 g0 = *reinterpret_cast<const float4*>(&geT[kq[q] * 72 + nbase]);
                float4 g1 = *reinterpret_cast<const float4*>(&geT[kq[q] * 72 + nbase + 4]);
                const float gg[8] = {g0.x, g0.y, g0.z, g0.w, g1.x, g1.y, g1.z, g1.w};
                short8 a;
#pragma unroll
                for (int j = 0; j < 8; ++j) {
                    float kp = kpL[(nbase + j) * 33 + mq[q]];
                    a[j] = (short)f2bf(kp * gg[j]);
                }
#pragma unroll
                for (int dt = 0; dt < 5; ++dt)
                    acc[q][dt] = __builtin_amdgcn_mfma_f32_16x16x32_bf16(a, b[dt], acc[q][dt], 0, 0, 0);
            }
        }
    }
#undef K2_LOAD

    // flush: D[row=(l4)*4+r][col=l15]
    float* kvh = kvs + h * 19200;
#pragma unroll
    for (int q = 0; q < 5; ++q) {
        const int kmb = (wave * 5 + q) * 16 + l4 * 4;
#pragma unroll
        for (int r = 0; r < 4; ++r) {
            const int km = kmb + r;
            if (km < 300) {
#pragma unroll
                for (int dt = 0; dt < 4; ++dt)
                    atomicAdd(&kvh[km * 64 + dt * 16 + l15], acc[q][dt][r]);
                if (l15 == 0)
                    atomicAdd(&kssum[h * 300 + km], acc[q][4][r]);
            }
        }
    }
}

// ---- k3: MFMA numerator + Wo (unchanged) ----
__global__ __launch_bounds__(512) void k3_out(
    const __hip_bfloat16* __restrict__ qp16, const float* __restrict__ kvs,
    const float* __restrict__ kssum,
    const unsigned short* __restrict__ Wofh, const unsigned short* __restrict__ Wofl,
    const float* __restrict__ bo, float* __restrict__ out, int N)
{
    __shared__ alignas(16) float U[32 * 656];
    __shared__ alignas(16) float zl[32 * 260];
    __shared__ float qpl[32 * 30];
    __shared__ float idl[320];
    __shared__ float ksl[300];

    unsigned short* Bfh = reinterpret_cast<unsigned short*>(U);
    unsigned short* Bfl = Bfh + 20480;

    const int t = threadIdx.x;
    const int n0 = blockIdx.x * 32;
    const int wave = t >> 6, lane = t & 63;

    for (int h = 0; h < 4; ++h) {
        __syncthreads();
        {
            const float* kvh = kvs + h * 19200;
            for (int idx = t; idx < 2560; idx += 512) {
                const int ct = idx >> 6, l = idx & 63;
                const int col = ct * 16 + (l & 15);
                const int k = col >> 6, d = col & 63;
                const int mb = (l >> 4) * 8;
                const float* src = kvh + (k * 30 + mb) * 64 + d;
                short8 hi, lo;
#pragma unroll
                for (int j = 0; j < 8; ++j) {
                    float v = src[j * 64];
                    unsigned short h2, l2; split2(v, h2, l2);
                    hi[j] = (short)h2; lo[j] = (short)l2;
                }
                *reinterpret_cast<short8*>(&Bfh[idx * 8]) = hi;
                *reinterpret_cast<short8*>(&Bfl[idx * 8]) = lo;
            }
        }
        if (t < 300) ksl[t] = kssum[h * 300 + t];
        for (int i = t; i < 960; i += 512) {
            int rr = i / 30, m = i % 30;
            int n = n0 + rr; if (n >= N) n = N - 1;
            qpl[i] = bf2f(((const unsigned short*)qp16)[(long)n * 120 + h * 30 + m]);
        }
        __syncthreads();

        short8 aQ[2];
#pragma unroll
        for (int rt = 0; rt < 2; ++rt) {
            int n = n0 + rt * 16 + (lane & 15); if (n >= N) n = N - 1;
            const unsigned int* qrow = reinterpret_cast<const unsigned int*>(
                (const unsigned short*)qp16 + (long)n * 120 + h * 30 + (lane >> 4) * 8);
            short8 a;
#pragma unroll
            for (int jj = 0; jj < 4; ++jj) {
                unsigned int u = qrow[jj];
                a[jj * 2] = (short)(u & 0xffffu);
                a[jj * 2 + 1] = (short)(u >> 16);
            }
            if ((lane >> 4) == 3) { a[6] = 0; a[7] = 0; }
            aQ[rt] = a;
        }
        floatx4 acc[2][5];
#pragma unroll
        for (int rt = 0; rt < 2; ++rt)
#pragma unroll
            for (int q = 0; q < 5; ++q) acc[rt][q] = floatx4{0.f, 0.f, 0.f, 0.f};
#pragma unroll
        for (int q = 0; q < 5; ++q) {
            const int ct = wave * 5 + q;
            short8 bh = *reinterpret_cast<const short8*>(&Bfh[(ct * 64 + lane) * 8]);
            short8 bl = *reinterpret_cast<const short8*>(&Bfl[(ct * 64 + lane) * 8]);
            acc[0][q] = __builtin_amdgcn_mfma_f32_16x16x32_bf16(aQ[0], bh, acc[0][q], 0, 0, 0);
            acc[0][q] = __builtin_amdgcn_mfma_f32_16x16x32_bf16(aQ[0], bl, acc[0][q], 0, 0, 0);
            acc[1][q] = __builtin_amdgcn_mfma_f32_16x16x32_bf16(aQ[1], bh, acc[1][q], 0, 0, 0);
            acc[1][q] = __builtin_amdgcn_mfma_f32_16x16x32_bf16(aQ[1], bl, acc[1][q], 0, 0, 0);
        }
        if (t < 320) {
            const int rr = t / 10, kk = t % 10;
            float s = 0.f;
#pragma unroll
            for (int m = 0; m < 30; ++m) s += qpl[rr * 30 + m] * ksl[kk * 30 + m];
            idl[t] = 1.0f / s;
        }
        __syncthreads();
#pragma unroll
        for (int rt = 0; rt < 2; ++rt)
#pragma unroll
            for (int q = 0; q < 5; ++q) {
                const int ct = wave * 5 + q;
                const int row = rt * 16 + (lane >> 4) * 4;
                const int col = ct * 16 + (lane & 15);
#pragma unroll
                for (int r = 0; r < 4; ++r)
                    U[(row + r) * 656 + col] = acc[rt][q][r];
            }
        __syncthreads();
        {
            const int row = t >> 4, dd = t & 15;
            const float4* U4 = reinterpret_cast<const float4*>(U);
            float4 s = float4{0.f, 0.f, 0.f, 0.f};
#pragma unroll
            for (int k = 0; k < 10; ++k) {
                float4 nm = U4[row * 164 + k * 16 + dd];
                float w = idl[row * 10 + k];
                s.x += nm.x * w; s.y += nm.y * w; s.z += nm.z * w; s.w += nm.w * w;
            }
            float4 zv; zv.x = 0.1f * s.x; zv.y = 0.1f * s.y; zv.z = 0.1f * s.z; zv.w = 0.1f * s.w;
            reinterpret_cast<float4*>(zl)[row * 65 + h * 16 + dd] = zv;
        }
    }
    __syncthreads();
    {
        const int rt = wave >> 2, ct = wave & 3;
        floatx4 o = floatx4{0.f, 0.f, 0.f, 0.f};
#pragma unroll
        for (int ks = 0; ks < 8; ++ks) {
            const float* zr = &zl[(rt * 16 + (lane & 15)) * 260 + ks * 32 + (lane >> 4) * 8];
            float4 x0 = *reinterpret_cast<const float4*>(zr);
            float4 x1 = *reinterpret_cast<const float4*>(zr + 4);
            float xv[8] = {x0.x, x0.y, x0.z, x0.w, x1.x, x1.y, x1.z, x1.w};
            short8 ah, al;
#pragma unroll
            for (int j = 0; j < 8; ++j) {
                unsigned short hi, lo; split2(xv[j], hi, lo);
                ah[j] = (short)hi; al[j] = (short)lo;
            }
            const int slot = ct * 8 + ks;
            short8 bh = *reinterpret_cast<const short8*>(&Wofh[slot * 512 + lane * 8]);
            short8 bl = *reinterpret_cast<const short8*>(&Wofl[slot * 512 + lane * 8]);
            o = __builtin_amdgcn_mfma_f32_16x16x32_bf16(ah, bh, o, 0, 0, 0);
            o = __builtin_amdgcn_mfma_f32_16x16x32_bf16(ah, bl, o, 0, 0, 0);
            o = __builtin_amdgcn_mfma_f32_16x16x32_bf16(al, bh, o, 0, 0, 0);
        }
        const int col = ct * 16 + (lane & 15);
        const float bb = bo[col];
#pragma unroll
        for (int r = 0; r < 4; ++r) {
            const int n = n0 + rt * 16 + (lane >> 4) * 4 + r;
            if (n < N) out[(long)n * 64 + col] = o[r] + bb;
        }
    }
}

extern "C" void kernel_launch(void* const* d_in, const int* in_sizes, int n_in,
                              void* d_out, int out_size, void* d_ws, size_t ws_size,
                              hipStream_t stream)
{
    const float* z    = (const float*)d_in[0];
    const float* Wq   = (const float*)d_in[1];
    const float* bq   = (const float*)d_in[2];
    const float* Wk   = (const float*)d_in[3];
    const float* bk   = (const float*)d_in[4];
    const float* Wv   = (const float*)d_in[5];
    const float* bv   = (const float*)d_in[6];
    const float* Wo   = (const float*)d_in[7];
    const float* bo   = (const float*)d_in[8];
    const float* proj = (const float*)d_in[9];
    const float* gum  = (const float*)d_in[10];
    const float* tau  = (const float*)d_in[11];
    float* out = (float*)d_out;

    const int N = in_sizes[0] / 64;          // 50000
    const int ntiles = (N + 15) / 16;        // 3125
    const int nchunk = (N + 127) / 128;      // 391
    const int nblk3  = (N + 31) / 32;        // 1563

    char* wsb = (char*)d_ws;
    size_t off = 0;
    __hip_bfloat16* qp16 = (__hip_bfloat16*)(wsb);
    off += ((size_t)N * 120 * 2 + 255) & ~(size_t)255;
    __hip_bfloat16* v16 = (__hip_bfloat16*)(wsb + off);
    off += ((size_t)N * 256 * 2 + 255) & ~(size_t)255;
    float* argk = (float*)(wsb + off);
    off += ((size_t)N * 120 * 4 + 255) & ~(size_t)255;
    float* kvs      = (float*)(wsb + off);
    float* kssum    = kvs + 76800;
    float* headmax  = kssum + 1200;
    float* blockmax = headmax + 4;
    off += ((size_t)(76800 + 1200 + 4 + (size_t)ntiles * 4) * 4 + 255) & ~(size_t)255;
    unsigned short* Wfh = (unsigned short*)(wsb + off); off += 49152 * 2;
    unsigned short* Wfl = (unsigned short*)(wsb + off); off += 49152 * 2;
    unsigned short* Pfh = (unsigned short*)(wsb + off); off += 2048 * 2;
    unsigned short* Pfl = (unsigned short*)(wsb + off); off += 2048 * 2;
    unsigned short* Wofh = (unsigned short*)(wsb + off); off += 16384 * 2;
    unsigned short* Wofl = (unsigned short*)(wsb + off);

    k_prep<<<dim3(26), dim3(256), 0, stream>>>(Wq, Wk, Wv, proj, Wo,
                                               Wfh, Wfl, Pfh, Pfl, Wofh, Wofl);
    k0_zero<<<dim3((78000 + 255) / 256), dim3(256), 0, stream>>>(kvs, 78000);
    k1_feat<<<dim3(ntiles), dim3(256), 0, stream>>>(z, bq, bk, bv, Wfh, Wfl, Pfh, Pfl, tau,
                                                    qp16, v16, argk, blockmax, N);
    k1b_redmax<<<dim3(1), dim3(256), 0, stream>>>(blockmax, headmax, ntiles);
    k2_kvs<<<dim3(512), dim3(256), 0, stream>>>(argk, gum, v16, tau, headmax,
                                                kvs, kssum, N, nchunk);
    k3_out<<<dim3(nblk3), dim3(512), 0, stream>>>(qp16, kvs, kssum, Wofh, Wofl, bo, out, N);
}

// Round 10
// 282.174 us; speedup vs baseline: 24.7841x; 1.2658x over previous
//
#include <hip/hip_runtime.h>
#include <hip/hip_bf16.h>

// NodeFormerConv: Performer/Gumbel attention. fp32-equivalent math, fp32 output.
//   k_prep: split Wq|Wk|Wv, proj, Wo into MFMA-fragment-ordered hi/lo bf16
//   k0   zero kvs[4][300][64] + kssum[4][300]
//   k1   per 16-row tile, MFMA (hi/lo 3-pass): QKV gemm -> qd/kd LDS + v16;
//        phi gemm -> ddq/ddk; diag; exp -> qp16, argk, blockmax
//   k1b  blockmax -> headmax[4]
//   k2   MFMA accumulate, batched+prefetched staging; A-frags built in regs.
//   k2b  split kvs into fragment-ordered hi/lo bf16 (once, global)
//   k3   per 32-row block: den for all heads up front; per head: B-frags from
//        global (coalesced), NUM MFMA, idl applied IN-REGISTER (k is wave-const),
//        17KB part exchange -> zl; then out = zl@Wo (hi/lo 3-pass) + bo (f32)

#define NEPS  1e-6f
#define RATIO 0.18257418583505536f   // 1/sqrt(30)
#define DNORM 0.35355339059327378f   // 64^-0.25

typedef __attribute__((ext_vector_type(8))) short short8;
typedef __attribute__((ext_vector_type(4))) float floatx4;

__device__ inline unsigned short f2bf(float x) {
    __hip_bfloat16 b = __float2bfloat16(x);
    return __builtin_bit_cast(unsigned short, b);
}
__device__ inline float bf2f(unsigned short h) {
    return __builtin_bit_cast(float, (unsigned int)h << 16);
}
__device__ inline void split2(float v, unsigned short& hi, unsigned short& lo) {
    unsigned short h = f2bf(v);
    hi = h; lo = f2bf(v - bf2f(h));
}

__global__ __launch_bounds__(256) void k0_zero(float* __restrict__ p, int count) {
    int id = blockIdx.x * 256 + threadIdx.x;
    if (id < count) p[id] = 0.f;
}

// ---- k_prep: fragment-ordered hi/lo splits (unchanged) ----
__global__ __launch_bounds__(256) void k_prep(
    const float* __restrict__ Wq, const float* __restrict__ Wk, const float* __restrict__ Wv,
    const float* __restrict__ proj, const float* __restrict__ Wo,
    unsigned short* __restrict__ Wfh, unsigned short* __restrict__ Wfl,
    unsigned short* __restrict__ Pfh, unsigned short* __restrict__ Pfl,
    unsigned short* __restrict__ Wofh, unsigned short* __restrict__ Wofl)
{
    const int b = blockIdx.x, t = threadIdx.x;
    if (b < 24) {
        const int slot = b * 256 + t;
        const int lane = slot & 63;
        const int ctks = slot >> 6;
        const int ct = ctks >> 1, ks = ctks & 1;
        const int col = ct * 16 + (lane & 15);
        const int k0 = ks * 32 + (lane >> 4) * 8;
        const float* W = (col < 256) ? Wq : (col < 512) ? Wk : Wv;
        const int cm = col & 255;
#pragma unroll
        for (int j = 0; j < 8; ++j) {
            float w = W[(k0 + j) * 256 + cm];
            unsigned short hi, lo; split2(w, hi, lo);
            Wfh[slot * 8 + j] = hi;
            Wfl[slot * 8 + j] = lo;
        }
    } else if (b == 24) {
        const int lane = t & 63;
        const int ctks = t >> 6;
        const int ct2 = ctks >> 1, ks = ctks & 1;
        const int m = ct2 * 16 + (lane & 15);
        const int k0 = ks * 32 + (lane >> 4) * 8;
#pragma unroll
        for (int j = 0; j < 8; ++j) {
            float p = (m < 30) ? proj[m * 64 + k0 + j] : 0.f;
            unsigned short hi, lo; split2(p, hi, lo);
            Pfh[t * 8 + j] = hi;
            Pfl[t * 8 + j] = lo;
        }
    } else {
        for (int idx = t; idx < 2048; idx += 256) {
            const int slot = idx >> 6, l = idx & 63;
            const int ct = slot >> 3, ks = slot & 7;
            const int col = ct * 16 + (l & 15);
            const int k0 = ks * 32 + (l >> 4) * 8;
#pragma unroll
            for (int j = 0; j < 8; ++j) {
                float w = Wo[(k0 + j) * 64 + col];
                unsigned short hi, lo; split2(w, hi, lo);
                Wofh[slot * 512 + l * 8 + j] = hi;
                Wofl[slot * 512 + l * 8 + j] = lo;
            }
        }
    }
}

// ---- k1: per 16-row tile, MFMA QKV + phi (hi/lo 3-pass) — unchanged ----
__global__ __launch_bounds__(256) void k1_feat(
    const float* __restrict__ z,
    const float* __restrict__ bq, const float* __restrict__ bk, const float* __restrict__ bv,
    const unsigned short* __restrict__ Wfh, const unsigned short* __restrict__ Wfl,
    const unsigned short* __restrict__ Pfh, const unsigned short* __restrict__ Pfl,
    const float* __restrict__ tau,
    __hip_bfloat16* __restrict__ qp16, __hip_bfloat16* __restrict__ v16,
    float* __restrict__ argk, float* __restrict__ blockmax, int N)
{
    __shared__ alignas(16) unsigned short zh[16 * 72];
    __shared__ alignas(16) unsigned short zl_[16 * 72];
    __shared__ alignas(16) float qd[16 * 264];
    __shared__ alignas(16) float kd[16 * 264];
    __shared__ float ddq[16 * 128];
    __shared__ float ddk[16 * 128];
    __shared__ float dgq[64], dgk[64];
    __shared__ float qmx[64], kmx[64];

    const int t = threadIdx.x;
    const int n0 = blockIdx.x * 16;
    const int wave = t >> 6, lane = t & 63;
    const float dsc = rsqrtf(tau[0]) * DNORM;

    for (int i = t; i < 1024; i += 256) {
        int r = i >> 6, c = i & 63;
        float v = (n0 + r < N) ? z[(long)(n0 + r) * 64 + c] : 0.f;
        unsigned short hi, lo; split2(v, hi, lo);
        zh[r * 72 + c] = hi;
        zl_[r * 72 + c] = lo;
    }
    __syncthreads();

    {
        const int abase = (lane & 15) * 72 + (lane >> 4) * 8;
        short8 ah0 = *reinterpret_cast<const short8*>(&zh[abase]);
        short8 ah1 = *reinterpret_cast<const short8*>(&zh[abase + 32]);
        short8 al0 = *reinterpret_cast<const short8*>(&zl_[abase]);
        short8 al1 = *reinterpret_cast<const short8*>(&zl_[abase + 32]);
        const int row0 = (lane >> 4) * 4;
#pragma unroll 2
        for (int ci = 0; ci < 12; ++ci) {
            const int ct = wave * 12 + ci;
            short8 bh0 = *reinterpret_cast<const short8*>(&Wfh[(ct * 2 + 0) * 512 + lane * 8]);
            short8 bh1 = *reinterpret_cast<const short8*>(&Wfh[(ct * 2 + 1) * 512 + lane * 8]);
            short8 bl0 = *reinterpret_cast<const short8*>(&Wfl[(ct * 2 + 0) * 512 + lane * 8]);
            short8 bl1 = *reinterpret_cast<const short8*>(&Wfl[(ct * 2 + 1) * 512 + lane * 8]);
            floatx4 acc = floatx4{0.f, 0.f, 0.f, 0.f};
            acc = __builtin_amdgcn_mfma_f32_16x16x32_bf16(ah0, bh0, acc, 0, 0, 0);
            acc = __builtin_amdgcn_mfma_f32_16x16x32_bf16(ah1, bh1, acc, 0, 0, 0);
            acc = __builtin_amdgcn_mfma_f32_16x16x32_bf16(ah0, bl0, acc, 0, 0, 0);
            acc = __builtin_amdgcn_mfma_f32_16x16x32_bf16(ah1, bl1, acc, 0, 0, 0);
            acc = __builtin_amdgcn_mfma_f32_16x16x32_bf16(al0, bh0, acc, 0, 0, 0);
            acc = __builtin_amdgcn_mfma_f32_16x16x32_bf16(al1, bh1, acc, 0, 0, 0);
            const int c = ct * 16 + (lane & 15);
            if (c < 256) {
                const float bb = bq[c];
#pragma unroll
                for (int r = 0; r < 4; ++r) qd[(row0 + r) * 264 + c] = (acc[r] + bb) * dsc;
            } else if (c < 512) {
                const float bb = bk[c - 256];
#pragma unroll
                for (int r = 0; r < 4; ++r) kd[(row0 + r) * 264 + (c - 256)] = (acc[r] + bb) * dsc;
            } else {
                const float bb = bv[c - 512];
#pragma unroll
                for (int r = 0; r < 4; ++r)
                    if (n0 + row0 + r < N)
                        v16[(long)(n0 + row0 + r) * 256 + (c - 512)] = __float2bfloat16(acc[r] + bb);
            }
        }
    }
    __syncthreads();

    {
        short8 pbh[2][2], pbl[2][2];
#pragma unroll
        for (int ct2 = 0; ct2 < 2; ++ct2)
#pragma unroll
            for (int ks = 0; ks < 2; ++ks) {
                pbh[ct2][ks] = *reinterpret_cast<const short8*>(&Pfh[(ct2 * 2 + ks) * 512 + lane * 8]);
                pbl[ct2][ks] = *reinterpret_cast<const short8*>(&Pfl[(ct2 * 2 + ks) * 512 + lane * 8]);
            }
        const int h = wave;
        const int row0 = (lane >> 4) * 4;
#pragma unroll
        for (int side = 0; side < 2; ++side) {
            const float* dat = side ? kd : qd;
            float* dd = side ? ddk : ddq;
            const int rbase = (lane & 15) * 264 + h * 64 + (lane >> 4) * 8;
            float xv[8], yv[8];
            {
                float4 x0 = *reinterpret_cast<const float4*>(&dat[rbase]);
                float4 x1 = *reinterpret_cast<const float4*>(&dat[rbase + 4]);
                float4 y0 = *reinterpret_cast<const float4*>(&dat[rbase + 32]);
                float4 y1 = *reinterpret_cast<const float4*>(&dat[rbase + 36]);
                xv[0]=x0.x; xv[1]=x0.y; xv[2]=x0.z; xv[3]=x0.w;
                xv[4]=x1.x; xv[5]=x1.y; xv[6]=x1.z; xv[7]=x1.w;
                yv[0]=y0.x; yv[1]=y0.y; yv[2]=y0.z; yv[3]=y0.w;
                yv[4]=y1.x; yv[5]=y1.y; yv[6]=y1.z; yv[7]=y1.w;
            }
            short8 ah0, al0, ah1, al1;
#pragma unroll
            for (int j = 0; j < 8; ++j) {
                unsigned short hi, lo;
                split2(xv[j], hi, lo); ah0[j] = (short)hi; al0[j] = (short)lo;
                split2(yv[j], hi, lo); ah1[j] = (short)hi; al1[j] = (short)lo;
            }
#pragma unroll
            for (int ct2 = 0; ct2 < 2; ++ct2) {
                floatx4 acc = floatx4{0.f, 0.f, 0.f, 0.f};
                acc = __builtin_amdgcn_mfma_f32_16x16x32_bf16(ah0, pbh[ct2][0], acc, 0, 0, 0);
                acc = __builtin_amdgcn_mfma_f32_16x16x32_bf16(ah1, pbh[ct2][1], acc, 0, 0, 0);
                acc = __builtin_amdgcn_mfma_f32_16x16x32_bf16(ah0, pbl[ct2][0], acc, 0, 0, 0);
                acc = __builtin_amdgcn_mfma_f32_16x16x32_bf16(ah1, pbl[ct2][1], acc, 0, 0, 0);
                acc = __builtin_amdgcn_mfma_f32_16x16x32_bf16(al0, pbh[ct2][0], acc, 0, 0, 0);
                acc = __builtin_amdgcn_mfma_f32_16x16x32_bf16(al1, pbh[ct2][1], acc, 0, 0, 0);
#pragma unroll
                for (int r = 0; r < 4; ++r)
                    dd[(row0 + r) * 128 + h * 32 + ct2 * 16 + (lane & 15)] = acc[r];
            }
        }
    }
    if (t < 128) {
        const int h = t >> 5, row = (t >> 1) & 15, side = t & 1;
        const float* dat = side ? kd : qd;
        float s = 0.f;
        for (int d = 0; d < 64; ++d) { float x = dat[row * 264 + h * 64 + d]; s += x * x; }
        (side ? dgk : dgq)[h * 16 + row] = 0.5f * s;
    }
    __syncthreads();

    if (t < 64) {
        const int h = t >> 4, row = t & 15;
        float mx = ddq[row * 128 + h * 32];
        for (int m = 1; m < 30; ++m) mx = fmaxf(mx, ddq[row * 128 + h * 32 + m]);
        qmx[t] = mx;
    } else if (t < 128) {
        const int u = t - 64, h = u >> 4, row = u & 15;
        float mx = -3.4e38f;
        if (n0 + row < N)
            for (int m = 0; m < 30; ++m) mx = fmaxf(mx, ddk[row * 128 + h * 32 + m]);
        kmx[u] = mx;
    }
    __syncthreads();

    if (t < 4) {
        float mx = kmx[t * 16];
        for (int row = 1; row < 16; ++row) mx = fmaxf(mx, kmx[t * 16 + row]);
        blockmax[blockIdx.x * 4 + t] = mx;
    }
    for (int idx = t; idx < 1920; idx += 256) {
        const int row = idx / 120, r = idx % 120, h = r / 30, m = r % 30;
        if (n0 + row < N) {
            float val = RATIO * (expf(ddq[row * 128 + h * 32 + m] - dgq[h * 16 + row] - qmx[h * 16 + row]) + NEPS);
            qp16[(long)(n0 + row) * 120 + r] = __float2bfloat16(val);
            argk[(long)(n0 + row) * 120 + r] = ddk[row * 128 + h * 32 + m] - dgk[h * 16 + row];
        }
    }
}

__global__ __launch_bounds__(256) void k1b_redmax(
    const float* __restrict__ blockmax, float* __restrict__ headmax, int ntiles)
{
    __shared__ float red[4 * 256];
    const int t = threadIdx.x;
    float lm[4] = {-3.4e38f, -3.4e38f, -3.4e38f, -3.4e38f};
    for (int i = t; i < ntiles; i += 256) {
#pragma unroll
        for (int hh = 0; hh < 4; ++hh) lm[hh] = fmaxf(lm[hh], blockmax[i * 4 + hh]);
    }
#pragma unroll
    for (int hh = 0; hh < 4; ++hh) red[hh * 256 + t] = lm[hh];
    __syncthreads();
    if (t < 4) {
        float mx = red[t * 256];
        for (int i = 1; i < 256; ++i) mx = fmaxf(mx, red[t * 256 + i]);
        headmax[t] = mx;
    }
}

// ---- k2: MFMA accumulate with batched + prefetched staging (unchanged) ----
__global__ __launch_bounds__(256) void k2_kvs(
    const float* __restrict__ argk, const float* __restrict__ gum,
    const __hip_bfloat16* __restrict__ v16, const float* __restrict__ tau,
    const float* __restrict__ headmax,
    float* __restrict__ kvs, float* __restrict__ kssum, int N, int nchunk)
{
    __shared__ alignas(16) unsigned short Vt[80 * 72];
    __shared__ float kpL[64 * 33];
    __shared__ alignas(16) float geT[13 * 72];

    const int t = threadIdx.x;
    const int h = blockIdx.x >> 7;
    const int chunk = blockIdx.x & 127;
    const int n0 = chunk * nchunk;
    const int n1 = (n0 + nchunk < N) ? (n0 + nchunk) : N;
    const float MX = headmax[h];
    const float itau = 1.0f / tau[0];
    const int wave = t >> 6, lane = t & 63;
    const int l15 = lane & 15, l4 = lane >> 4;

    int ar_r[8], ar_m[8];
#pragma unroll
    for (int u = 0; u < 8; ++u) { int i = t + 256 * u; ar_r[u] = i / 30; ar_m[u] = i % 30; }
    int gu_k[3], gu_n[3];
#pragma unroll
    for (int u = 0; u < 3; ++u) { int i = t + 256 * u; gu_k[u] = i >> 6; gu_n[u] = i & 63; }
    int v_n[8], v_dp[8];
#pragma unroll
    for (int u = 0; u < 8; ++u) { int i = t + 256 * u; v_n[u] = i >> 5; v_dp[u] = (i & 31) * 2; }

    float ra[8], rg[3];
    unsigned int rv[8];

    floatx4 acc[5][5];
#pragma unroll
    for (int q = 0; q < 5; ++q)
#pragma unroll
        for (int dt = 0; dt < 5; ++dt) acc[q][dt] = floatx4{0.f, 0.f, 0.f, 0.f};

    int mq[5], kq[5];
#pragma unroll
    for (int q = 0; q < 5; ++q) {
        int row = (wave * 5 + q) * 16 + l15;
        mq[q] = row % 30;
        kq[q] = row / 30;
    }

    if (t < 64) Vt[64 * 72 + t] = f2bf(1.0f);
    for (int i = t; i < 15 * 72; i += 256) Vt[65 * 72 + i] = 0;
    for (int i = t; i < 3 * 72; i += 256) geT[10 * 72 + i] = 0.f;

    const int ntile = (n1 - n0 + 63) >> 6;

#define K2_LOAD(nb_)                                                              \
    do {                                                                          \
        _Pragma("unroll")                                                         \
        for (int u = 0; u < 8; ++u) {                                             \
            int n = (nb_) + ar_r[u]; n = (n < n1) ? n : (n1 - 1);                  \
            ra[u] = argk[(long)n * 120 + h * 30 + ar_m[u]];                       \
        }                                                                         \
        _Pragma("unroll")                                                         \
        for (int u = 0; u < 3; ++u) {                                             \
            int n = (nb_) + gu_n[u]; n = (n < n1) ? n : (n1 - 1);                  \
            rg[u] = gum[(long)n * 40 + h * 10 + gu_k[u]];                         \
        }                                                                         \
        _Pragma("unroll")                                                         \
        for (int u = 0; u < 8; ++u) {                                             \
            int n = (nb_) + v_n[u]; n = (n < n1) ? n : (n1 - 1);                   \
            rv[u] = *reinterpret_cast<const unsigned int*>(                       \
                v16 + (long)n * 256 + h * 64 + v_dp[u]);                          \
        }                                                                         \
    } while (0)

    K2_LOAD(n0);

    for (int tt = 0; tt < ntile; ++tt) {
        const int nb = n0 + tt * 64;
        __syncthreads();
#pragma unroll
        for (int u = 0; u < 8; ++u) {
            if (u < 7 || t < 128) {
                bool ok = (nb + ar_r[u] < n1);
                kpL[ar_r[u] * 33 + ar_m[u]] =
                    ok ? RATIO * (__expf(ra[u] - MX) + NEPS) : 0.f;
            }
        }
#pragma unroll
        for (int u = 0; u < 3; ++u) {
            if (u < 2 || t < 128) {
                bool ok = (nb + gu_n[u] < n1);
                geT[gu_k[u] * 72 + gu_n[u]] = ok ? __expf(rg[u] * itau) : 0.f;
            }
        }
#pragma unroll
        for (int u = 0; u < 8; ++u) {
            bool ok = (nb + v_n[u] < n1);
            unsigned int uu = ok ? rv[u] : 0u;
            Vt[v_dp[u] * 72 + v_n[u]] = (unsigned short)(uu & 0xffffu);
            Vt[(v_dp[u] + 1) * 72 + v_n[u]] = (unsigned short)(uu >> 16);
        }
        __syncthreads();
        if (tt + 1 < ntile) K2_LOAD(nb + 64);

#pragma unroll
        for (int nh = 0; nh < 2; ++nh) {
            const int nbase = nh * 32 + l4 * 8;
            short8 b[5];
#pragma unroll
            for (int dt = 0; dt < 5; ++dt)
                b[dt] = *reinterpret_cast<const short8*>(&Vt[(dt * 16 + l15) * 72 + nbase]);
#pragma unroll
            for (int q = 0; q < 5; ++q) {
                float4 g0 = *reinterpret_cast<const float4*>(&geT[kq[q] * 72 + nbase]);
                float4 g1 = *reinterpret_cast<const float4*>(&geT[kq[q] * 72 + nbase + 4]);
                const float gg[8] = {g0.x, g0.y, g0.z, g0.w, g1.x, g1.y, g1.z, g1.w};
                short8 a;
#pragma unroll
                for (int j = 0; j < 8; ++j) {
                    float kp = kpL[(nbase + j) * 33 + mq[q]];
                    a[j] = (short)f2bf(kp * gg[j]);
                }
#pragma unroll
                for (int dt = 0; dt < 5; ++dt)
                    acc[q][dt] = __builtin_amdgcn_mfma_f32_16x16x32_bf16(a, b[dt], acc[q][dt], 0, 0, 0);
            }
        }
    }
#undef K2_LOAD

    float* kvh = kvs + h * 19200;
#pragma unroll
    for (int q = 0; q < 5; ++q) {
        const int kmb = (wave * 5 + q) * 16 + l4 * 4;
#pragma unroll
        for (int r = 0; r < 4; ++r) {
            const int km = kmb + r;
            if (km < 300) {
#pragma unroll
                for (int dt = 0; dt < 4; ++dt)
                    atomicAdd(&kvh[km * 64 + dt * 16 + l15], acc[q][dt][r]);
                if (l15 == 0)
                    atomicAdd(&kssum[h * 300 + km], acc[q][4][r]);
            }
        }
    }
}

// ---- k2b: split kvs into fragment-ordered hi/lo bf16 (once) ----
// slot = h*2560 + ct*64 + lane; col = ct*16+(lane&15) -> k=col>>6,d=col&63;
// m = (lane>>4)*8 + j (m>=30 -> 0).
__global__ __launch_bounds__(256) void k2b_frag(
    const float* __restrict__ kvs,
    unsigned short* __restrict__ Bfh, unsigned short* __restrict__ Bfl)
{
    const int slot = blockIdx.x * 256 + threadIdx.x;
    if (slot >= 10240) return;
    const int h = slot / 2560;
    const int rem = slot % 2560;
    const int ct = rem >> 6, lane = rem & 63;
    const int col = ct * 16 + (lane & 15);
    const int k = col >> 6, d = col & 63;
    const int mb = (lane >> 4) * 8;
    const float* src = kvs + h * 19200 + (k * 30 + mb) * 64 + d;
    short8 hi8, lo8;
#pragma unroll
    for (int j = 0; j < 8; ++j) {
        float v = (mb + j < 30) ? src[j * 64] : 0.f;
        unsigned short hh, ll; split2(v, hh, ll);
        hi8[j] = (short)hh; lo8[j] = (short)ll;
    }
    *reinterpret_cast<short8*>(&Bfh[(long)slot * 8]) = hi8;
    *reinterpret_cast<short8*>(&Bfl[(long)slot * 8]) = lo8;
}

// ---- k3: den up front; per head: B-frags from global, NUM MFMA, in-register
// idl scale (k wave-constant), part[2][32][68] exchange -> zl; then zl@Wo + bo ----
__global__ __launch_bounds__(512) void k3_out(
    const __hip_bfloat16* __restrict__ qp16,
    const unsigned short* __restrict__ Bfh, const unsigned short* __restrict__ Bfl,
    const float* __restrict__ kssum,
    const unsigned short* __restrict__ Wofh, const unsigned short* __restrict__ Wofl,
    const float* __restrict__ bo, float* __restrict__ out, int N)
{
    __shared__ alignas(16) unsigned short qpall[32 * 136]; // [row][h*32+m], bf16 bits
    __shared__ float ksall[1200];
    __shared__ float idla[4 * 320];                        // [h][row*10+k]
    __shared__ alignas(16) float part[2][32][68];
    __shared__ alignas(16) float zl[32 * 260];

    const int t = threadIdx.x;
    const int n0 = blockIdx.x * 32;
    const int wave = t >> 6, lane = t & 63;
    const int g = wave & 3, khalf = wave >> 2;
    const int l15 = lane & 15, l4 = lane >> 4;

    // stage qpall (bf16 bits) + ksall
    for (int i = t; i < 1200; i += 512) ksall[i] = kssum[i];
    for (int i = t; i < 32 * 60; i += 512) {     // 60 dwords = 120 ushort per row
        int rr = i / 60, dw = i % 60;
        int n = n0 + rr; if (n >= N) n = N - 1;
        unsigned int u = *reinterpret_cast<const unsigned int*>(
            (const unsigned short*)qp16 + (long)n * 120 + dw * 2);
        int h = dw / 15, md = (dw % 15) * 2;     // head-local m pair
        qpall[rr * 136 + h * 32 + md] = (unsigned short)(u & 0xffffu);
        qpall[rr * 136 + h * 32 + md + 1] = (unsigned short)(u >> 16);
    }
    __syncthreads();

    // den for all heads: 1280 products
    for (int i = t; i < 1280; i += 512) {
        int h = i / 320, rem = i % 320;
        int rr = rem / 10, kk = rem % 10;
        const unsigned short* qr = &qpall[rr * 136 + h * 32];
        const float* kr = &ksall[h * 300 + kk * 30];
        float s = 0.f;
#pragma unroll
        for (int m = 0; m < 30; ++m) s += bf2f(qr[m]) * kr[m];
        idla[i] = 1.0f / s;
    }
    __syncthreads();

    for (int h = 0; h < 4; ++h) {
        // B-frags for this wave's 5 ct tiles (coalesced global, L2-hot)
        short8 bh[5], bl[5];
#pragma unroll
        for (int q = 0; q < 5; ++q) {
            const int ct = (khalf * 5 + q) * 4 + g;
            const long off = ((long)(h * 40 + ct) * 64 + lane) * 8;
            bh[q] = *reinterpret_cast<const short8*>(Bfh + off);
            bl[q] = *reinterpret_cast<const short8*>(Bfl + off);
        }
        // A-frags from qpall (dword reads; 16B alignment not guaranteed)
        short8 aQ[2];
#pragma unroll
        for (int rt = 0; rt < 2; ++rt) {
            const unsigned int* qrow = reinterpret_cast<const unsigned int*>(
                &qpall[(rt * 16 + l15) * 136 + h * 32 + l4 * 8]);
            short8 a;
#pragma unroll
            for (int jj = 0; jj < 4; ++jj) {
                unsigned int u = qrow[jj];
                a[jj * 2] = (short)(u & 0xffffu);
                a[jj * 2 + 1] = (short)(u >> 16);
            }
            if (l4 == 3) { a[6] = 0; a[7] = 0; }   // m = 30,31 pad
            aQ[rt] = a;
        }
        floatx4 acc[2][5];
#pragma unroll
        for (int rt = 0; rt < 2; ++rt)
#pragma unroll
            for (int q = 0; q < 5; ++q) acc[rt][q] = floatx4{0.f, 0.f, 0.f, 0.f};
#pragma unroll
        for (int q = 0; q < 5; ++q) {
            acc[0][q] = __builtin_amdgcn_mfma_f32_16x16x32_bf16(aQ[0], bh[q], acc[0][q], 0, 0, 0);
            acc[0][q] = __builtin_amdgcn_mfma_f32_16x16x32_bf16(aQ[0], bl[q], acc[0][q], 0, 0, 0);
            acc[1][q] = __builtin_amdgcn_mfma_f32_16x16x32_bf16(aQ[1], bh[q], acc[1][q], 0, 0, 0);
            acc[1][q] = __builtin_amdgcn_mfma_f32_16x16x32_bf16(aQ[1], bl[q], acc[1][q], 0, 0, 0);
        }
        // in-register idl scale + k-sum (idl reads are 16-lane broadcasts)
#pragma unroll
        for (int rt = 0; rt < 2; ++rt)
#pragma unroll
            for (int r = 0; r < 4; ++r) {
                const int row = rt * 16 + l4 * 4 + r;
                float s = 0.f;
#pragma unroll
                for (int q = 0; q < 5; ++q)
                    s += acc[rt][q][r] * idla[h * 320 + row * 10 + khalf * 5 + q];
                part[khalf][row][g * 16 + l15] = s;
            }
        __syncthreads();                          // part ready
        {
            const int row = t >> 4, d4 = t & 15;
            float4 p0 = *reinterpret_cast<const float4*>(&part[0][row][d4 * 4]);
            float4 p1 = *reinterpret_cast<const float4*>(&part[1][row][d4 * 4]);
            float4 zv;
            zv.x = 0.1f * (p0.x + p1.x); zv.y = 0.1f * (p0.y + p1.y);
            zv.z = 0.1f * (p0.z + p1.z); zv.w = 0.1f * (p0.w + p1.w);
            reinterpret_cast<float4*>(zl)[row * 65 + h * 16 + d4] = zv;
        }
        __syncthreads();                          // part free for next head
    }
    // Wo phase: wave w -> rt = w>>2, ct = w&3
    {
        const int rt = wave >> 2, ct = wave & 3;
        floatx4 o = floatx4{0.f, 0.f, 0.f, 0.f};
#pragma unroll
        for (int ks = 0; ks < 8; ++ks) {
            const float* zr = &zl[(rt * 16 + l15) * 260 + ks * 32 + l4 * 8];
            float4 x0 = *reinterpret_cast<const float4*>(zr);
            float4 x1 = *reinterpret_cast<const float4*>(zr + 4);
            float xv[8] = {x0.x, x0.y, x0.z, x0.w, x1.x, x1.y, x1.z, x1.w};
            short8 ah, al;
#pragma unroll
            for (int j = 0; j < 8; ++j) {
                unsigned short hi, lo; split2(xv[j], hi, lo);
                ah[j] = (short)hi; al[j] = (short)lo;
            }
            const int slot = ct * 8 + ks;
            short8 wbh = *reinterpret_cast<const short8*>(&Wofh[slot * 512 + lane * 8]);
            short8 wbl = *reinterpret_cast<const short8*>(&Wofl[slot * 512 + lane * 8]);
            o = __builtin_amdgcn_mfma_f32_16x16x32_bf16(ah, wbh, o, 0, 0, 0);
            o = __builtin_amdgcn_mfma_f32_16x16x32_bf16(ah, wbl, o, 0, 0, 0);
            o = __builtin_amdgcn_mfma_f32_16x16x32_bf16(al, wbh, o, 0, 0, 0);
        }
        const int col = ct * 16 + l15;
        const float bb = bo[col];
#pragma unroll
        for (int r = 0; r < 4; ++r) {
            const int n = n0 + rt * 16 + l4 * 4 + r;
            if (n < N) out[(long)n * 64 + col] = o[r] + bb;
        }
    }
}

extern "C" void kernel_launch(void* const* d_in, const int* in_sizes, int n_in,
                              void* d_out, int out_size, void* d_ws, size_t ws_size,
                              hipStream_t stream)
{
    const float* z    = (const float*)d_in[0];
    const float* Wq   = (const float*)d_in[1];
    const float* bq   = (const float*)d_in[2];
    const float* Wk   = (const float*)d_in[3];
    const float* bk   = (const float*)d_in[4];
    const float* Wv   = (const float*)d_in[5];
    const float* bv   = (const float*)d_in[6];
    const float* Wo   = (const float*)d_in[7];
    const float* bo   = (const float*)d_in[8];
    const float* proj = (const float*)d_in[9];
    const float* gum  = (const float*)d_in[10];
    const float* tau  = (const float*)d_in[11];
    float* out = (float*)d_out;

    const int N = in_sizes[0] / 64;          // 50000
    const int ntiles = (N + 15) / 16;        // 3125
    const int nchunk = (N + 127) / 128;      // 391
    const int nblk3  = (N + 31) / 32;        // 1563

    char* wsb = (char*)d_ws;
    size_t off = 0;
    __hip_bfloat16* qp16 = (__hip_bfloat16*)(wsb);
    off += ((size_t)N * 120 * 2 + 255) & ~(size_t)255;
    __hip_bfloat16* v16 = (__hip_bfloat16*)(wsb + off);
    off += ((size_t)N * 256 * 2 + 255) & ~(size_t)255;
    float* argk = (float*)(wsb + off);
    off += ((size_t)N * 120 * 4 + 255) & ~(size_t)255;
    float* kvs      = (float*)(wsb + off);
    float* kssum    = kvs + 76800;
    float* headmax  = kssum + 1200;
    float* blockmax = headmax + 4;
    off += ((size_t)(76800 + 1200 + 4 + (size_t)ntiles * 4) * 4 + 255) & ~(size_t)255;
    unsigned short* Wfh = (unsigned short*)(wsb + off); off += 49152 * 2;
    unsigned short* Wfl = (unsigned short*)(wsb + off); off += 49152 * 2;
    unsigned short* Pfh = (unsigned short*)(wsb + off); off += 2048 * 2;
    unsigned short* Pfl = (unsigned short*)(wsb + off); off += 2048 * 2;
    unsigned short* Wofh = (unsigned short*)(wsb + off); off += 16384 * 2;
    unsigned short* Wofl = (unsigned short*)(wsb + off); off += 16384 * 2;
    unsigned short* Bfh  = (unsigned short*)(wsb + off); off += 81920 * 2;
    unsigned short* Bfl  = (unsigned short*)(wsb + off);

    k_prep<<<dim3(26), dim3(256), 0, stream>>>(Wq, Wk, Wv, proj, Wo,
                                               Wfh, Wfl, Pfh, Pfl, Wofh, Wofl);
    k0_zero<<<dim3((78000 + 255) / 256), dim3(256), 0, stream>>>(kvs, 78000);
    k1_feat<<<dim3(ntiles), dim3(256), 0, stream>>>(z, bq, bk, bv, Wfh, Wfl, Pfh, Pfl, tau,
                                                    qp16, v16, argk, blockmax, N);
    k1b_redmax<<<dim3(1), dim3(256), 0, stream>>>(blockmax, headmax, ntiles);
    k2_kvs<<<dim3(512), dim3(256), 0, stream>>>(argk, gum, v16, tau, headmax,
                                                kvs, kssum, N, nchunk);
    k2b_frag<<<dim3(40), dim3(256), 0, stream>>>(kvs, Bfh, Bfl);
    k3_out<<<dim3(nblk3), dim3(512), 0, stream>>>(qp16, Bfh, Bfl, kssum,
                                                  Wofh, Wofl, bo, out, N);
}

// Round 11
// 233.868 us; speedup vs baseline: 29.9033x; 1.2066x over previous
//
#include <hip/hip_runtime.h>
#include <hip/hip_bf16.h>

// NodeFormerConv: Performer/Gumbel attention. fp32-equivalent math, fp32 output.
//   k_prep: split Wq|Wk|Wv, proj, Wo into MFMA-fragment-ordered hi/lo bf16
//   (k0   zero kvs/kssum — only in atomic-fallback mode)
//   k1   per 16-row tile, MFMA (hi/lo 3-pass): QKV gemm -> qd/kd LDS + v16;
//        phi gemm -> ddq/ddk; diag; exp -> qp16, argk, blockmax
//   k1b  blockmax -> headmax[4]
//   k2   MFMA accumulate, batched+prefetched staging; flush -> private slab
//        (plain stores) if ws fits, else atomicAdd fallback
//   k2r  reduce 128 chunk-slabs per head -> kvs, kssum (two-stage mode)
//   k2b  split kvs into fragment-ordered hi/lo bf16 (once, global)
//   k3   per 32-row block: den up front; per head B-frags from global, NUM MFMA,
//        in-register idl scale, part exchange -> zl; out = zl@Wo + bo (f32)

#define NEPS  1e-6f
#define RATIO 0.18257418583505536f   // 1/sqrt(30)
#define DNORM 0.35355339059327378f   // 64^-0.25

typedef __attribute__((ext_vector_type(8))) short short8;
typedef __attribute__((ext_vector_type(4))) float floatx4;

__device__ inline unsigned short f2bf(float x) {
    __hip_bfloat16 b = __float2bfloat16(x);
    return __builtin_bit_cast(unsigned short, b);
}
__device__ inline float bf2f(unsigned short h) {
    return __builtin_bit_cast(float, (unsigned int)h << 16);
}
__device__ inline void split2(float v, unsigned short& hi, unsigned short& lo) {
    unsigned short h = f2bf(v);
    hi = h; lo = f2bf(v - bf2f(h));
}

__global__ __launch_bounds__(256) void k0_zero(float* __restrict__ p, int count) {
    int id = blockIdx.x * 256 + threadIdx.x;
    if (id < count) p[id] = 0.f;
}

// ---- k_prep: fragment-ordered hi/lo splits (unchanged) ----
__global__ __launch_bounds__(256) void k_prep(
    const float* __restrict__ Wq, const float* __restrict__ Wk, const float* __restrict__ Wv,
    const float* __restrict__ proj, const float* __restrict__ Wo,
    unsigned short* __restrict__ Wfh, unsigned short* __restrict__ Wfl,
    unsigned short* __restrict__ Pfh, unsigned short* __restrict__ Pfl,
    unsigned short* __restrict__ Wofh, unsigned short* __restrict__ Wofl)
{
    const int b = blockIdx.x, t = threadIdx.x;
    if (b < 24) {
        const int slot = b * 256 + t;
        const int lane = slot & 63;
        const int ctks = slot >> 6;
        const int ct = ctks >> 1, ks = ctks & 1;
        const int col = ct * 16 + (lane & 15);
        const int k0 = ks * 32 + (lane >> 4) * 8;
        const float* W = (col < 256) ? Wq : (col < 512) ? Wk : Wv;
        const int cm = col & 255;
#pragma unroll
        for (int j = 0; j < 8; ++j) {
            float w = W[(k0 + j) * 256 + cm];
            unsigned short hi, lo; split2(w, hi, lo);
            Wfh[slot * 8 + j] = hi;
            Wfl[slot * 8 + j] = lo;
        }
    } else if (b == 24) {
        const int lane = t & 63;
        const int ctks = t >> 6;
        const int ct2 = ctks >> 1, ks = ctks & 1;
        const int m = ct2 * 16 + (lane & 15);
        const int k0 = ks * 32 + (lane >> 4) * 8;
#pragma unroll
        for (int j = 0; j < 8; ++j) {
            float p = (m < 30) ? proj[m * 64 + k0 + j] : 0.f;
            unsigned short hi, lo; split2(p, hi, lo);
            Pfh[t * 8 + j] = hi;
            Pfl[t * 8 + j] = lo;
        }
    } else {
        for (int idx = t; idx < 2048; idx += 256) {
            const int slot = idx >> 6, l = idx & 63;
            const int ct = slot >> 3, ks = slot & 7;
            const int col = ct * 16 + (l & 15);
            const int k0 = ks * 32 + (l >> 4) * 8;
#pragma unroll
            for (int j = 0; j < 8; ++j) {
                float w = Wo[(k0 + j) * 64 + col];
                unsigned short hi, lo; split2(w, hi, lo);
                Wofh[slot * 512 + l * 8 + j] = hi;
                Wofl[slot * 512 + l * 8 + j] = lo;
            }
        }
    }
}

// ---- k1: per 16-row tile, MFMA QKV + phi (hi/lo 3-pass) — unchanged ----
__global__ __launch_bounds__(256) void k1_feat(
    const float* __restrict__ z,
    const float* __restrict__ bq, const float* __restrict__ bk, const float* __restrict__ bv,
    const unsigned short* __restrict__ Wfh, const unsigned short* __restrict__ Wfl,
    const unsigned short* __restrict__ Pfh, const unsigned short* __restrict__ Pfl,
    const float* __restrict__ tau,
    __hip_bfloat16* __restrict__ qp16, __hip_bfloat16* __restrict__ v16,
    float* __restrict__ argk, float* __restrict__ blockmax, int N)
{
    __shared__ alignas(16) unsigned short zh[16 * 72];
    __shared__ alignas(16) unsigned short zl_[16 * 72];
    __shared__ alignas(16) float qd[16 * 264];
    __shared__ alignas(16) float kd[16 * 264];
    __shared__ float ddq[16 * 128];
    __shared__ float ddk[16 * 128];
    __shared__ float dgq[64], dgk[64];
    __shared__ float qmx[64], kmx[64];

    const int t = threadIdx.x;
    const int n0 = blockIdx.x * 16;
    const int wave = t >> 6, lane = t & 63;
    const float dsc = rsqrtf(tau[0]) * DNORM;

    for (int i = t; i < 1024; i += 256) {
        int r = i >> 6, c = i & 63;
        float v = (n0 + r < N) ? z[(long)(n0 + r) * 64 + c] : 0.f;
        unsigned short hi, lo; split2(v, hi, lo);
        zh[r * 72 + c] = hi;
        zl_[r * 72 + c] = lo;
    }
    __syncthreads();

    {
        const int abase = (lane & 15) * 72 + (lane >> 4) * 8;
        short8 ah0 = *reinterpret_cast<const short8*>(&zh[abase]);
        short8 ah1 = *reinterpret_cast<const short8*>(&zh[abase + 32]);
        short8 al0 = *reinterpret_cast<const short8*>(&zl_[abase]);
        short8 al1 = *reinterpret_cast<const short8*>(&zl_[abase + 32]);
        const int row0 = (lane >> 4) * 4;
#pragma unroll 2
        for (int ci = 0; ci < 12; ++ci) {
            const int ct = wave * 12 + ci;
            short8 bh0 = *reinterpret_cast<const short8*>(&Wfh[(ct * 2 + 0) * 512 + lane * 8]);
            short8 bh1 = *reinterpret_cast<const short8*>(&Wfh[(ct * 2 + 1) * 512 + lane * 8]);
            short8 bl0 = *reinterpret_cast<const short8*>(&Wfl[(ct * 2 + 0) * 512 + lane * 8]);
            short8 bl1 = *reinterpret_cast<const short8*>(&Wfl[(ct * 2 + 1) * 512 + lane * 8]);
            floatx4 acc = floatx4{0.f, 0.f, 0.f, 0.f};
            acc = __builtin_amdgcn_mfma_f32_16x16x32_bf16(ah0, bh0, acc, 0, 0, 0);
            acc = __builtin_amdgcn_mfma_f32_16x16x32_bf16(ah1, bh1, acc, 0, 0, 0);
            acc = __builtin_amdgcn_mfma_f32_16x16x32_bf16(ah0, bl0, acc, 0, 0, 0);
            acc = __builtin_amdgcn_mfma_f32_16x16x32_bf16(ah1, bl1, acc, 0, 0, 0);
            acc = __builtin_amdgcn_mfma_f32_16x16x32_bf16(al0, bh0, acc, 0, 0, 0);
            acc = __builtin_amdgcn_mfma_f32_16x16x32_bf16(al1, bh1, acc, 0, 0, 0);
            const int c = ct * 16 + (lane & 15);
            if (c < 256) {
                const float bb = bq[c];
#pragma unroll
                for (int r = 0; r < 4; ++r) qd[(row0 + r) * 264 + c] = (acc[r] + bb) * dsc;
            } else if (c < 512) {
                const float bb = bk[c - 256];
#pragma unroll
                for (int r = 0; r < 4; ++r) kd[(row0 + r) * 264 + (c - 256)] = (acc[r] + bb) * dsc;
            } else {
                const float bb = bv[c - 512];
#pragma unroll
                for (int r = 0; r < 4; ++r)
                    if (n0 + row0 + r < N)
                        v16[(long)(n0 + row0 + r) * 256 + (c - 512)] = __float2bfloat16(acc[r] + bb);
            }
        }
    }
    __syncthreads();

    {
        short8 pbh[2][2], pbl[2][2];
#pragma unroll
        for (int ct2 = 0; ct2 < 2; ++ct2)
#pragma unroll
            for (int ks = 0; ks < 2; ++ks) {
                pbh[ct2][ks] = *reinterpret_cast<const short8*>(&Pfh[(ct2 * 2 + ks) * 512 + lane * 8]);
                pbl[ct2][ks] = *reinterpret_cast<const short8*>(&Pfl[(ct2 * 2 + ks) * 512 + lane * 8]);
            }
        const int h = wave;
        const int row0 = (lane >> 4) * 4;
#pragma unroll
        for (int side = 0; side < 2; ++side) {
            const float* dat = side ? kd : qd;
            float* dd = side ? ddk : ddq;
            const int rbase = (lane & 15) * 264 + h * 64 + (lane >> 4) * 8;
            float xv[8], yv[8];
            {
                float4 x0 = *reinterpret_cast<const float4*>(&dat[rbase]);
                float4 x1 = *reinterpret_cast<const float4*>(&dat[rbase + 4]);
                float4 y0 = *reinterpret_cast<const float4*>(&dat[rbase + 32]);
                float4 y1 = *reinterpret_cast<const float4*>(&dat[rbase + 36]);
                xv[0]=x0.x; xv[1]=x0.y; xv[2]=x0.z; xv[3]=x0.w;
                xv[4]=x1.x; xv[5]=x1.y; xv[6]=x1.z; xv[7]=x1.w;
                yv[0]=y0.x; yv[1]=y0.y; yv[2]=y0.z; yv[3]=y0.w;
                yv[4]=y1.x; yv[5]=y1.y; yv[6]=y1.z; yv[7]=y1.w;
            }
            short8 ah0, al0, ah1, al1;
#pragma unroll
            for (int j = 0; j < 8; ++j) {
                unsigned short hi, lo;
                split2(xv[j], hi, lo); ah0[j] = (short)hi; al0[j] = (short)lo;
                split2(yv[j], hi, lo); ah1[j] = (short)hi; al1[j] = (short)lo;
            }
#pragma unroll
            for (int ct2 = 0; ct2 < 2; ++ct2) {
                floatx4 acc = floatx4{0.f, 0.f, 0.f, 0.f};
                acc = __builtin_amdgcn_mfma_f32_16x16x32_bf16(ah0, pbh[ct2][0], acc, 0, 0, 0);
                acc = __builtin_amdgcn_mfma_f32_16x16x32_bf16(ah1, pbh[ct2][1], acc, 0, 0, 0);
                acc = __builtin_amdgcn_mfma_f32_16x16x32_bf16(ah0, pbl[ct2][0], acc, 0, 0, 0);
                acc = __builtin_amdgcn_mfma_f32_16x16x32_bf16(ah1, pbl[ct2][1], acc, 0, 0, 0);
                acc = __builtin_amdgcn_mfma_f32_16x16x32_bf16(al0, pbh[ct2][0], acc, 0, 0, 0);
                acc = __builtin_amdgcn_mfma_f32_16x16x32_bf16(al1, pbh[ct2][1], acc, 0, 0, 0);
#pragma unroll
                for (int r = 0; r < 4; ++r)
                    dd[(row0 + r) * 128 + h * 32 + ct2 * 16 + (lane & 15)] = acc[r];
            }
        }
    }
    if (t < 128) {
        const int h = t >> 5, row = (t >> 1) & 15, side = t & 1;
        const float* dat = side ? kd : qd;
        float s = 0.f;
        for (int d = 0; d < 64; ++d) { float x = dat[row * 264 + h * 64 + d]; s += x * x; }
        (side ? dgk : dgq)[h * 16 + row] = 0.5f * s;
    }
    __syncthreads();

    if (t < 64) {
        const int h = t >> 4, row = t & 15;
        float mx = ddq[row * 128 + h * 32];
        for (int m = 1; m < 30; ++m) mx = fmaxf(mx, ddq[row * 128 + h * 32 + m]);
        qmx[t] = mx;
    } else if (t < 128) {
        const int u = t - 64, h = u >> 4, row = u & 15;
        float mx = -3.4e38f;
        if (n0 + row < N)
            for (int m = 0; m < 30; ++m) mx = fmaxf(mx, ddk[row * 128 + h * 32 + m]);
        kmx[u] = mx;
    }
    __syncthreads();

    if (t < 4) {
        float mx = kmx[t * 16];
        for (int row = 1; row < 16; ++row) mx = fmaxf(mx, kmx[t * 16 + row]);
        blockmax[blockIdx.x * 4 + t] = mx;
    }
    for (int idx = t; idx < 1920; idx += 256) {
        const int row = idx / 120, r = idx % 120, h = r / 30, m = r % 30;
        if (n0 + row < N) {
            float val = RATIO * (expf(ddq[row * 128 + h * 32 + m] - dgq[h * 16 + row] - qmx[h * 16 + row]) + NEPS);
            qp16[(long)(n0 + row) * 120 + r] = __float2bfloat16(val);
            argk[(long)(n0 + row) * 120 + r] = ddk[row * 128 + h * 32 + m] - dgk[h * 16 + row];
        }
    }
}

__global__ __launch_bounds__(256) void k1b_redmax(
    const float* __restrict__ blockmax, float* __restrict__ headmax, int ntiles)
{
    __shared__ float red[4 * 256];
    const int t = threadIdx.x;
    float lm[4] = {-3.4e38f, -3.4e38f, -3.4e38f, -3.4e38f};
    for (int i = t; i < ntiles; i += 256) {
#pragma unroll
        for (int hh = 0; hh < 4; ++hh) lm[hh] = fmaxf(lm[hh], blockmax[i * 4 + hh]);
    }
#pragma unroll
    for (int hh = 0; hh < 4; ++hh) red[hh * 256 + t] = lm[hh];
    __syncthreads();
    if (t < 4) {
        float mx = red[t * 256];
        for (int i = 1; i < 256; ++i) mx = fmaxf(mx, red[t * 256 + i]);
        headmax[t] = mx;
    }
}

// ---- k2: MFMA accumulate; flush -> private slab (mode 1) or atomics (mode 0) ----
__global__ __launch_bounds__(256) void k2_kvs(
    const float* __restrict__ argk, const float* __restrict__ gum,
    const __hip_bfloat16* __restrict__ v16, const float* __restrict__ tau,
    const float* __restrict__ headmax,
    float* __restrict__ kvs, float* __restrict__ kssum,
    float* __restrict__ part, int mode, int N, int nchunk)
{
    __shared__ alignas(16) unsigned short Vt[80 * 72];
    __shared__ float kpL[64 * 33];
    __shared__ alignas(16) float geT[13 * 72];

    const int t = threadIdx.x;
    const int h = blockIdx.x >> 7;
    const int chunk = blockIdx.x & 127;
    const int n0 = chunk * nchunk;
    const int n1 = (n0 + nchunk < N) ? (n0 + nchunk) : N;
    const float MX = headmax[h];
    const float itau = 1.0f / tau[0];
    const int wave = t >> 6, lane = t & 63;
    const int l15 = lane & 15, l4 = lane >> 4;

    int ar_r[8], ar_m[8];
#pragma unroll
    for (int u = 0; u < 8; ++u) { int i = t + 256 * u; ar_r[u] = i / 30; ar_m[u] = i % 30; }
    int gu_k[3], gu_n[3];
#pragma unroll
    for (int u = 0; u < 3; ++u) { int i = t + 256 * u; gu_k[u] = i >> 6; gu_n[u] = i & 63; }
    int v_n[8], v_dp[8];
#pragma unroll
    for (int u = 0; u < 8; ++u) { int i = t + 256 * u; v_n[u] = i >> 5; v_dp[u] = (i & 31) * 2; }

    float ra[8], rg[3];
    unsigned int rv[8];

    floatx4 acc[5][5];
#pragma unroll
    for (int q = 0; q < 5; ++q)
#pragma unroll
        for (int dt = 0; dt < 5; ++dt) acc[q][dt] = floatx4{0.f, 0.f, 0.f, 0.f};

    int mq[5], kq[5];
#pragma unroll
    for (int q = 0; q < 5; ++q) {
        int row = (wave * 5 + q) * 16 + l15;
        mq[q] = row % 30;
        kq[q] = row / 30;
    }

    if (t < 64) Vt[64 * 72 + t] = f2bf(1.0f);
    for (int i = t; i < 15 * 72; i += 256) Vt[65 * 72 + i] = 0;
    for (int i = t; i < 3 * 72; i += 256) geT[10 * 72 + i] = 0.f;

    const int ntile = (n1 - n0 + 63) >> 6;

#define K2_LOAD(nb_)                                                              \
    do {                                                                          \
        _Pragma("unroll")                                                         \
        for (int u = 0; u < 8; ++u) {                                             \
            int n = (nb_) + ar_r[u]; n = (n < n1) ? n : (n1 - 1);                  \
            ra[u] = argk[(long)n * 120 + h * 30 + ar_m[u]];                       \
        }                                                                         \
        _Pragma("unroll")                                                         \
        for (int u = 0; u < 3; ++u) {                                             \
            int n = (nb_) + gu_n[u]; n = (n < n1) ? n : (n1 - 1);                  \
            rg[u] = gum[(long)n * 40 + h * 10 + gu_k[u]];                         \
        }                                                                         \
        _Pragma("unroll")                                                         \
        for (int u = 0; u < 8; ++u) {                                             \
            int n = (nb_) + v_n[u]; n = (n < n1) ? n : (n1 - 1);                   \
            rv[u] = *reinterpret_cast<const unsigned int*>(                       \
                v16 + (long)n * 256 + h * 64 + v_dp[u]);                          \
        }                                                                         \
    } while (0)

    K2_LOAD(n0);

    for (int tt = 0; tt < ntile; ++tt) {
        const int nb = n0 + tt * 64;
        __syncthreads();
#pragma unroll
        for (int u = 0; u < 8; ++u) {
            if (u < 7 || t < 128) {
                bool ok = (nb + ar_r[u] < n1);
                kpL[ar_r[u] * 33 + ar_m[u]] =
                    ok ? RATIO * (__expf(ra[u] - MX) + NEPS) : 0.f;
            }
        }
#pragma unroll
        for (int u = 0; u < 3; ++u) {
            if (u < 2 || t < 128) {
                bool ok = (nb + gu_n[u] < n1);
                geT[gu_k[u] * 72 + gu_n[u]] = ok ? __expf(rg[u] * itau) : 0.f;
            }
        }
#pragma unroll
        for (int u = 0; u < 8; ++u) {
            bool ok = (nb + v_n[u] < n1);
            unsigned int uu = ok ? rv[u] : 0u;
            Vt[v_dp[u] * 72 + v_n[u]] = (unsigned short)(uu & 0xffffu);
            Vt[(v_dp[u] + 1) * 72 + v_n[u]] = (unsigned short)(uu >> 16);
        }
        __syncthreads();
        if (tt + 1 < ntile) K2_LOAD(nb + 64);

#pragma unroll
        for (int nh = 0; nh < 2; ++nh) {
            const int nbase = nh * 32 + l4 * 8;
            short8 b[5];
#pragma unroll
            for (int dt = 0; dt < 5; ++dt)
                b[dt] = *reinterpret_cast<const short8*>(&Vt[(dt * 16 + l15) * 72 + nbase]);
#pragma unroll
            for (int q = 0; q < 5; ++q) {
                float4 g0 = *reinterpret_cast<const float4*>(&geT[kq[q] * 72 + nbase]);
                float4 g1 = *reinterpret_cast<const float4*>(&geT[kq[q] * 72 + nbase + 4]);
                const float gg[8] = {g0.x, g0.y, g0.z, g0.w, g1.x, g1.y, g1.z, g1.w};
                short8 a;
#pragma unroll
                for (int j = 0; j < 8; ++j) {
                    float kp = kpL[(nbase + j) * 33 + mq[q]];
                    a[j] = (short)f2bf(kp * gg[j]);
                }
#pragma unroll
                for (int dt = 0; dt < 5; ++dt)
                    acc[q][dt] = __builtin_amdgcn_mfma_f32_16x16x32_bf16(a, b[dt], acc[q][dt], 0, 0, 0);
            }
        }
    }
#undef K2_LOAD

    if (mode) {
        // two-stage: plain stores into private slab [19520]
        float* slab = part + (long)blockIdx.x * 19520;
#pragma unroll
        for (int q = 0; q < 5; ++q) {
            const int kmb = (wave * 5 + q) * 16 + l4 * 4;
#pragma unroll
            for (int r = 0; r < 4; ++r) {
                const int km = kmb + r;
                if (km < 300) {
#pragma unroll
                    for (int dt = 0; dt < 4; ++dt)
                        slab[km * 64 + dt * 16 + l15] = acc[q][dt][r];
                    if (l15 == 0) slab[19200 + km] = acc[q][4][r];
                }
            }
        }
    } else {
        float* kvh = kvs + h * 19200;
#pragma unroll
        for (int q = 0; q < 5; ++q) {
            const int kmb = (wave * 5 + q) * 16 + l4 * 4;
#pragma unroll
            for (int r = 0; r < 4; ++r) {
                const int km = kmb + r;
                if (km < 300) {
#pragma unroll
                    for (int dt = 0; dt < 4; ++dt)
                        atomicAdd(&kvh[km * 64 + dt * 16 + l15], acc[q][dt][r]);
                    if (l15 == 0)
                        atomicAdd(&kssum[h * 300 + km], acc[q][4][r]);
                }
            }
        }
    }
}

// ---- k2r: reduce 128 chunk-slabs per head -> kvs, kssum ----
__global__ __launch_bounds__(256) void k2r_reduce(
    const float* __restrict__ part, float* __restrict__ kvs, float* __restrict__ kssum)
{
    const int o = blockIdx.x * 256 + threadIdx.x;
    if (o >= 4 * 19504) return;
    const int h = o / 19504, e = o % 19504;
    const float* p = part + (long)h * 128 * 19520 + e;
    float s = 0.f;
#pragma unroll 8
    for (int c = 0; c < 128; ++c) s += p[(long)c * 19520];
    if (e < 19200) kvs[h * 19200 + e] = s;
    else if (e - 19200 < 300) kssum[h * 300 + (e - 19200)] = s;
}

// ---- k2b: split kvs into fragment-ordered hi/lo bf16 (unchanged) ----
__global__ __launch_bounds__(256) void k2b_frag(
    const float* __restrict__ kvs,
    unsigned short* __restrict__ Bfh, unsigned short* __restrict__ Bfl)
{
    const int slot = blockIdx.x * 256 + threadIdx.x;
    if (slot >= 10240) return;
    const int h = slot / 2560;
    const int rem = slot % 2560;
    const int ct = rem >> 6, lane = rem & 63;
    const int col = ct * 16 + (lane & 15);
    const int k = col >> 6, d = col & 63;
    const int mb = (lane >> 4) * 8;
    const float* src = kvs + h * 19200 + (k * 30 + mb) * 64 + d;
    short8 hi8, lo8;
#pragma unroll
    for (int j = 0; j < 8; ++j) {
        float v = (mb + j < 30) ? src[j * 64] : 0.f;
        unsigned short hh, ll; split2(v, hh, ll);
        hi8[j] = (short)hh; lo8[j] = (short)ll;
    }
    *reinterpret_cast<short8*>(&Bfh[(long)slot * 8]) = hi8;
    *reinterpret_cast<short8*>(&Bfl[(long)slot * 8]) = lo8;
}

// ---- k3: unchanged from round 10 ----
__global__ __launch_bounds__(512) void k3_out(
    const __hip_bfloat16* __restrict__ qp16,
    const unsigned short* __restrict__ Bfh, const unsigned short* __restrict__ Bfl,
    const float* __restrict__ kssum,
    const unsigned short* __restrict__ Wofh, const unsigned short* __restrict__ Wofl,
    const float* __restrict__ bo, float* __restrict__ out, int N)
{
    __shared__ alignas(16) unsigned short qpall[32 * 136];
    __shared__ float ksall[1200];
    __shared__ float idla[4 * 320];
    __shared__ alignas(16) float part[2][32][68];
    __shared__ alignas(16) float zl[32 * 260];

    const int t = threadIdx.x;
    const int n0 = blockIdx.x * 32;
    const int wave = t >> 6, lane = t & 63;
    const int g = wave & 3, khalf = wave >> 2;
    const int l15 = lane & 15, l4 = lane >> 4;

    for (int i = t; i < 1200; i += 512) ksall[i] = kssum[i];
    for (int i = t; i < 32 * 60; i += 512) {
        int rr = i / 60, dw = i % 60;
        int n = n0 + rr; if (n >= N) n = N - 1;
        unsigned int u = *reinterpret_cast<const unsigned int*>(
            (const unsigned short*)qp16 + (long)n * 120 + dw * 2);
        int h = dw / 15, md = (dw % 15) * 2;
        qpall[rr * 136 + h * 32 + md] = (unsigned short)(u & 0xffffu);
        qpall[rr * 136 + h * 32 + md + 1] = (unsigned short)(u >> 16);
    }
    __syncthreads();

    for (int i = t; i < 1280; i += 512) {
        int h = i / 320, rem = i % 320;
        int rr = rem / 10, kk = rem % 10;
        const unsigned short* qr = &qpall[rr * 136 + h * 32];
        const float* kr = &ksall[h * 300 + kk * 30];
        float s = 0.f;
#pragma unroll
        for (int m = 0; m < 30; ++m) s += bf2f(qr[m]) * kr[m];
        idla[i] = 1.0f / s;
    }
    __syncthreads();

    for (int h = 0; h < 4; ++h) {
        short8 bh[5], bl[5];
#pragma unroll
        for (int q = 0; q < 5; ++q) {
            const int ct = (khalf * 5 + q) * 4 + g;
            const long off = ((long)(h * 40 + ct) * 64 + lane) * 8;
            bh[q] = *reinterpret_cast<const short8*>(Bfh + off);
            bl[q] = *reinterpret_cast<const short8*>(Bfl + off);
        }
        short8 aQ[2];
#pragma unroll
        for (int rt = 0; rt < 2; ++rt) {
            const unsigned int* qrow = reinterpret_cast<const unsigned int*>(
                &qpall[(rt * 16 + l15) * 136 + h * 32 + l4 * 8]);
            short8 a;
#pragma unroll
            for (int jj = 0; jj < 4; ++jj) {
                unsigned int u = qrow[jj];
                a[jj * 2] = (short)(u & 0xffffu);
                a[jj * 2 + 1] = (short)(u >> 16);
            }
            if (l4 == 3) { a[6] = 0; a[7] = 0; }
            aQ[rt] = a;
        }
        floatx4 acc[2][5];
#pragma unroll
        for (int rt = 0; rt < 2; ++rt)
#pragma unroll
            for (int q = 0; q < 5; ++q) acc[rt][q] = floatx4{0.f, 0.f, 0.f, 0.f};
#pragma unroll
        for (int q = 0; q < 5; ++q) {
            acc[0][q] = __builtin_amdgcn_mfma_f32_16x16x32_bf16(aQ[0], bh[q], acc[0][q], 0, 0, 0);
            acc[0][q] = __builtin_amdgcn_mfma_f32_16x16x32_bf16(aQ[0], bl[q], acc[0][q], 0, 0, 0);
            acc[1][q] = __builtin_amdgcn_mfma_f32_16x16x32_bf16(aQ[1], bh[q], acc[1][q], 0, 0, 0);
            acc[1][q] = __builtin_amdgcn_mfma_f32_16x16x32_bf16(aQ[1], bl[q], acc[1][q], 0, 0, 0);
        }
#pragma unroll
        for (int rt = 0; rt < 2; ++rt)
#pragma unroll
            for (int r = 0; r < 4; ++r) {
                const int row = rt * 16 + l4 * 4 + r;
                float s = 0.f;
#pragma unroll
                for (int q = 0; q < 5; ++q)
                    s += acc[rt][q][r] * idla[h * 320 + row * 10 + khalf * 5 + q];
                part[khalf][row][g * 16 + l15] = s;
            }
        __syncthreads();
        {
            const int row = t >> 4, d4 = t & 15;
            float4 p0 = *reinterpret_cast<const float4*>(&part[0][row][d4 * 4]);
            float4 p1 = *reinterpret_cast<const float4*>(&part[1][row][d4 * 4]);
            float4 zv;
            zv.x = 0.1f * (p0.x + p1.x); zv.y = 0.1f * (p0.y + p1.y);
            zv.z = 0.1f * (p0.z + p1.z); zv.w = 0.1f * (p0.w + p1.w);
            reinterpret_cast<float4*>(zl)[row * 65 + h * 16 + d4] = zv;
        }
        __syncthreads();
    }
    {
        const int rt = wave >> 2, ct = wave & 3;
        floatx4 o = floatx4{0.f, 0.f, 0.f, 0.f};
#pragma unroll
        for (int ks = 0; ks < 8; ++ks) {
            const float* zr = &zl[(rt * 16 + l15) * 260 + ks * 32 + l4 * 8];
            float4 x0 = *reinterpret_cast<const float4*>(zr);
            float4 x1 = *reinterpret_cast<const float4*>(zr + 4);
            float xv[8] = {x0.x, x0.y, x0.z, x0.w, x1.x, x1.y, x1.z, x1.w};
            short8 ah, al;
#pragma unroll
            for (int j = 0; j < 8; ++j) {
                unsigned short hi, lo; split2(xv[j], hi, lo);
                ah[j] = (short)hi; al[j] = (short)lo;
            }
            const int slot = ct * 8 + ks;
            short8 wbh = *reinterpret_cast<const short8*>(&Wofh[slot * 512 + lane * 8]);
            short8 wbl = *reinterpret_cast<const short8*>(&Wofl[slot * 512 + lane * 8]);
            o = __builtin_amdgcn_mfma_f32_16x16x32_bf16(ah, wbh, o, 0, 0, 0);
            o = __builtin_amdgcn_mfma_f32_16x16x32_bf16(ah, wbl, o, 0, 0, 0);
            o = __builtin_amdgcn_mfma_f32_16x16x32_bf16(al, wbh, o, 0, 0, 0);
        }
        const int col = ct * 16 + l15;
        const float bb = bo[col];
#pragma unroll
        for (int r = 0; r < 4; ++r) {
            const int n = n0 + rt * 16 + l4 * 4 + r;
            if (n < N) out[(long)n * 64 + col] = o[r] + bb;
        }
    }
}

extern "C" void kernel_launch(void* const* d_in, const int* in_sizes, int n_in,
                              void* d_out, int out_size, void* d_ws, size_t ws_size,
                              hipStream_t stream)
{
    const float* z    = (const float*)d_in[0];
    const float* Wq   = (const float*)d_in[1];
    const float* bq   = (const float*)d_in[2];
    const float* Wk   = (const float*)d_in[3];
    const float* bk   = (const float*)d_in[4];
    const float* Wv   = (const float*)d_in[5];
    const float* bv   = (const float*)d_in[6];
    const float* Wo   = (const float*)d_in[7];
    const float* bo   = (const float*)d_in[8];
    const float* proj = (const float*)d_in[9];
    const float* gum  = (const float*)d_in[10];
    const float* tau  = (const float*)d_in[11];
    float* out = (float*)d_out;

    const int N = in_sizes[0] / 64;          // 50000
    const int ntiles = (N + 15) / 16;        // 3125
    const int nchunk = (N + 127) / 128;      // 391
    const int nblk3  = (N + 31) / 32;        // 1563

    char* wsb = (char*)d_ws;
    size_t off = 0;
    __hip_bfloat16* qp16 = (__hip_bfloat16*)(wsb);
    off += ((size_t)N * 120 * 2 + 255) & ~(size_t)255;
    __hip_bfloat16* v16 = (__hip_bfloat16*)(wsb + off);
    off += ((size_t)N * 256 * 2 + 255) & ~(size_t)255;
    float* argk = (float*)(wsb + off);
    off += ((size_t)N * 120 * 4 + 255) & ~(size_t)255;
    float* kvs      = (float*)(wsb + off);
    float* kssum    = kvs + 76800;
    float* headmax  = kssum + 1200;
    float* blockmax = headmax + 4;
    off += ((size_t)(76800 + 1200 + 4 + (size_t)ntiles * 4) * 4 + 255) & ~(size_t)255;
    unsigned short* Wfh = (unsigned short*)(wsb + off); off += 49152 * 2;
    unsigned short* Wfl = (unsigned short*)(wsb + off); off += 49152 * 2;
    unsigned short* Pfh = (unsigned short*)(wsb + off); off += 2048 * 2;
    unsigned short* Pfl = (unsigned short*)(wsb + off); off += 2048 * 2;
    unsigned short* Wofh = (unsigned short*)(wsb + off); off += 16384 * 2;
    unsigned short* Wofl = (unsigned short*)(wsb + off); off += 16384 * 2;
    unsigned short* Bfh  = (unsigned short*)(wsb + off); off += 81920 * 2;
    unsigned short* Bfl  = (unsigned short*)(wsb + off); off += 81920 * 2;
    off = (off + 255) & ~(size_t)255;
    float* part = (float*)(wsb + off);
    const size_t part_bytes = (size_t)512 * 19520 * 4;
    const int mode = (ws_size >= off + part_bytes) ? 1 : 0;   // two-stage if ws fits

    k_prep<<<dim3(26), dim3(256), 0, stream>>>(Wq, Wk, Wv, proj, Wo,
                                               Wfh, Wfl, Pfh, Pfl, Wofh, Wofl);
    if (!mode)
        k0_zero<<<dim3((78000 + 255) / 256), dim3(256), 0, stream>>>(kvs, 78000);
    k1_feat<<<dim3(ntiles), dim3(256), 0, stream>>>(z, bq, bk, bv, Wfh, Wfl, Pfh, Pfl, tau,
                                                    qp16, v16, argk, blockmax, N);
    k1b_redmax<<<dim3(1), dim3(256), 0, stream>>>(blockmax, headmax, ntiles);
    k2_kvs<<<dim3(512), dim3(256), 0, stream>>>(argk, gum, v16, tau, headmax,
                                                kvs, kssum, part, mode, N, nchunk);
    if (mode)
        k2r_reduce<<<dim3((4 * 19504 + 255) / 256), dim3(256), 0, stream>>>(part, kvs, kssum);
    k2b_frag<<<dim3(40), dim3(256), 0, stream>>>(kvs, Bfh, Bfl);
    k3_out<<<dim3(nblk3), dim3(512), 0, stream>>>(qp16, Bfh, Bfl, kssum,
                                                  Wofh, Wofl, bo, out, N);
}

// Round 12
// 216.259 us; speedup vs baseline: 32.3383x; 1.0814x over previous
//
#include <hip/hip_runtime.h>
#include <hip/hip_bf16.h>

// NodeFormerConv: Performer/Gumbel attention. fp32-equivalent math, fp32 output.
//   k_prep: split Wq|Wk|Wv, proj, Wo into MFMA-fragment-ordered hi/lo bf16
//   (k0   zero kvs/kssum — only in atomic-fallback mode)
//   k1   per 16-row tile, MFMA (hi/lo 3-pass): QKV gemm -> qd/kd LDS + v16;
//        phi gemm -> ddq/ddk; diag+rowmax IN-REGISTER (shfl); exp -> qp16, argk
//        LDS: zh/zl_ unioned with ddq/ddk -> ~52KB -> 3 blocks/CU
//   k1b  blockmax -> headmax[4]
//   k2   MFMA accumulate, batched+prefetched staging; flush -> private slab
//   k2r  reduce 128 chunk-slabs per head -> kvs, kssum
//   k2b  split kvs into fragment-ordered hi/lo bf16 (once, global)
//   k3   per 32-row block: den up front; B-frags from global, NUM MFMA,
//        in-register idl scale, part exchange -> zl; out = zl@Wo + bo (f32)

#define NEPS  1e-6f
#define RATIO 0.18257418583505536f   // 1/sqrt(30)
#define DNORM 0.35355339059327378f   // 64^-0.25

typedef __attribute__((ext_vector_type(8))) short short8;
typedef __attribute__((ext_vector_type(4))) float floatx4;

__device__ inline unsigned short f2bf(float x) {
    __hip_bfloat16 b = __float2bfloat16(x);
    return __builtin_bit_cast(unsigned short, b);
}
__device__ inline float bf2f(unsigned short h) {
    return __builtin_bit_cast(float, (unsigned int)h << 16);
}
__device__ inline void split2(float v, unsigned short& hi, unsigned short& lo) {
    unsigned short h = f2bf(v);
    hi = h; lo = f2bf(v - bf2f(h));
}

__global__ __launch_bounds__(256) void k0_zero(float* __restrict__ p, int count) {
    int id = blockIdx.x * 256 + threadIdx.x;
    if (id < count) p[id] = 0.f;
}

// ---- k_prep: fragment-ordered hi/lo splits (unchanged) ----
__global__ __launch_bounds__(256) void k_prep(
    const float* __restrict__ Wq, const float* __restrict__ Wk, const float* __restrict__ Wv,
    const float* __restrict__ proj, const float* __restrict__ Wo,
    unsigned short* __restrict__ Wfh, unsigned short* __restrict__ Wfl,
    unsigned short* __restrict__ Pfh, unsigned short* __restrict__ Pfl,
    unsigned short* __restrict__ Wofh, unsigned short* __restrict__ Wofl)
{
    const int b = blockIdx.x, t = threadIdx.x;
    if (b < 24) {
        const int slot = b * 256 + t;
        const int lane = slot & 63;
        const int ctks = slot >> 6;
        const int ct = ctks >> 1, ks = ctks & 1;
        const int col = ct * 16 + (lane & 15);
        const int k0 = ks * 32 + (lane >> 4) * 8;
        const float* W = (col < 256) ? Wq : (col < 512) ? Wk : Wv;
        const int cm = col & 255;
#pragma unroll
        for (int j = 0; j < 8; ++j) {
            float w = W[(k0 + j) * 256 + cm];
            unsigned short hi, lo; split2(w, hi, lo);
            Wfh[slot * 8 + j] = hi;
            Wfl[slot * 8 + j] = lo;
        }
    } else if (b == 24) {
        const int lane = t & 63;
        const int ctks = t >> 6;
        const int ct2 = ctks >> 1, ks = ctks & 1;
        const int m = ct2 * 16 + (lane & 15);
        const int k0 = ks * 32 + (lane >> 4) * 8;
#pragma unroll
        for (int j = 0; j < 8; ++j) {
            float p = (m < 30) ? proj[m * 64 + k0 + j] : 0.f;
            unsigned short hi, lo; split2(p, hi, lo);
            Pfh[t * 8 + j] = hi;
            Pfl[t * 8 + j] = lo;
        }
    } else {
        for (int idx = t; idx < 2048; idx += 256) {
            const int slot = idx >> 6, l = idx & 63;
            const int ct = slot >> 3, ks = slot & 7;
            const int col = ct * 16 + (l & 15);
            const int k0 = ks * 32 + (l >> 4) * 8;
#pragma unroll
            for (int j = 0; j < 8; ++j) {
                float w = Wo[(k0 + j) * 64 + col];
                unsigned short hi, lo; split2(w, hi, lo);
                Wofh[slot * 512 + l * 8 + j] = hi;
                Wofl[slot * 512 + l * 8 + j] = lo;
            }
        }
    }
}

// ---- k1: per 16-row tile, MFMA QKV + phi; in-register diag/rowmax; union LDS ----
__global__ __launch_bounds__(256) void k1_feat(
    const float* __restrict__ z,
    const float* __restrict__ bq, const float* __restrict__ bk, const float* __restrict__ bv,
    const unsigned short* __restrict__ Wfh, const unsigned short* __restrict__ Wfl,
    const unsigned short* __restrict__ Pfh, const unsigned short* __restrict__ Pfl,
    const float* __restrict__ tau,
    __hip_bfloat16* __restrict__ qp16, __hip_bfloat16* __restrict__ v16,
    float* __restrict__ argk, float* __restrict__ blockmax, int N)
{
    // union: P0/P1 use zh/zl_ (4608 B); P2/P3 use ddq/ddk (16896 B)
    __shared__ alignas(16) char uni[16896];
    __shared__ alignas(16) float qd[16 * 268];   // stride 268: 2-way banks (free)
    __shared__ alignas(16) float kd[16 * 268];
    __shared__ float dgq[64], dgk[64];           // [h*16+row]
    __shared__ float qmx[64], kmx[64];

    unsigned short* zh  = reinterpret_cast<unsigned short*>(uni);  // [16*72]
    unsigned short* zl_ = zh + 16 * 72;
    float* ddq = reinterpret_cast<float*>(uni);                    // [16*132]
    float* ddk = ddq + 16 * 132;

    const int t = threadIdx.x;
    const int n0 = blockIdx.x * 16;
    const int wave = t >> 6, lane = t & 63;
    const int l15 = lane & 15, l4 = lane >> 4;
    const float dsc = rsqrtf(tau[0]) * DNORM;

    // P0: load z rows, split hi/lo
    for (int i = t; i < 1024; i += 256) {
        int r = i >> 6, c = i & 63;
        float v = (n0 + r < N) ? z[(long)(n0 + r) * 64 + c] : 0.f;
        unsigned short hi, lo; split2(v, hi, lo);
        zh[r * 72 + c] = hi;
        zl_[r * 72 + c] = lo;
    }
    __syncthreads();

    // P1: QKV GEMM. wave w: col-tiles 12w..12w+11
    {
        const int abase = l15 * 72 + l4 * 8;
        short8 ah0 = *reinterpret_cast<const short8*>(&zh[abase]);
        short8 ah1 = *reinterpret_cast<const short8*>(&zh[abase + 32]);
        short8 al0 = *reinterpret_cast<const short8*>(&zl_[abase]);
        short8 al1 = *reinterpret_cast<const short8*>(&zl_[abase + 32]);
        const int row0 = l4 * 4;
#pragma unroll 2
        for (int ci = 0; ci < 12; ++ci) {
            const int ct = wave * 12 + ci;
            short8 bh0 = *reinterpret_cast<const short8*>(&Wfh[(ct * 2 + 0) * 512 + lane * 8]);
            short8 bh1 = *reinterpret_cast<const short8*>(&Wfh[(ct * 2 + 1) * 512 + lane * 8]);
            short8 bl0 = *reinterpret_cast<const short8*>(&Wfl[(ct * 2 + 0) * 512 + lane * 8]);
            short8 bl1 = *reinterpret_cast<const short8*>(&Wfl[(ct * 2 + 1) * 512 + lane * 8]);
            floatx4 acc = floatx4{0.f, 0.f, 0.f, 0.f};
            acc = __builtin_amdgcn_mfma_f32_16x16x32_bf16(ah0, bh0, acc, 0, 0, 0);
            acc = __builtin_amdgcn_mfma_f32_16x16x32_bf16(ah1, bh1, acc, 0, 0, 0);
            acc = __builtin_amdgcn_mfma_f32_16x16x32_bf16(ah0, bl0, acc, 0, 0, 0);
            acc = __builtin_amdgcn_mfma_f32_16x16x32_bf16(ah1, bl1, acc, 0, 0, 0);
            acc = __builtin_amdgcn_mfma_f32_16x16x32_bf16(al0, bh0, acc, 0, 0, 0);
            acc = __builtin_amdgcn_mfma_f32_16x16x32_bf16(al1, bh1, acc, 0, 0, 0);
            const int c = ct * 16 + l15;
            if (c < 256) {
                const float bb = bq[c];
#pragma unroll
                for (int r = 0; r < 4; ++r) qd[(row0 + r) * 268 + c] = (acc[r] + bb) * dsc;
            } else if (c < 512) {
                const float bb = bk[c - 256];
#pragma unroll
                for (int r = 0; r < 4; ++r) kd[(row0 + r) * 268 + (c - 256)] = (acc[r] + bb) * dsc;
            } else {
                const float bb = bv[c - 512];
#pragma unroll
                for (int r = 0; r < 4; ++r)
                    if (n0 + row0 + r < N)
                        v16[(long)(n0 + row0 + r) * 256 + (c - 512)] = __float2bfloat16(acc[r] + bb);
            }
        }
    }
    __syncthreads();

    // P2: phi MFMA (wave w: head w) + diag/rowmax in-register
    {
        short8 pbh[2][2], pbl[2][2];
#pragma unroll
        for (int ct2 = 0; ct2 < 2; ++ct2)
#pragma unroll
            for (int ks = 0; ks < 2; ++ks) {
                pbh[ct2][ks] = *reinterpret_cast<const short8*>(&Pfh[(ct2 * 2 + ks) * 512 + lane * 8]);
                pbl[ct2][ks] = *reinterpret_cast<const short8*>(&Pfl[(ct2 * 2 + ks) * 512 + lane * 8]);
            }
        const int h = wave;
        const int row0 = l4 * 4;
#pragma unroll
        for (int side = 0; side < 2; ++side) {
            const float* dat = side ? kd : qd;
            float* dd = side ? ddk : ddq;
            const int rbase = l15 * 268 + h * 64 + l4 * 8;
            float xv[8], yv[8];
            {
                float4 x0 = *reinterpret_cast<const float4*>(&dat[rbase]);
                float4 x1 = *reinterpret_cast<const float4*>(&dat[rbase + 4]);
                float4 y0 = *reinterpret_cast<const float4*>(&dat[rbase + 32]);
                float4 y1 = *reinterpret_cast<const float4*>(&dat[rbase + 36]);
                xv[0]=x0.x; xv[1]=x0.y; xv[2]=x0.z; xv[3]=x0.w;
                xv[4]=x1.x; xv[5]=x1.y; xv[6]=x1.z; xv[7]=x1.w;
                yv[0]=y0.x; yv[1]=y0.y; yv[2]=y0.z; yv[3]=y0.w;
                yv[4]=y1.x; yv[5]=y1.y; yv[6]=y1.z; yv[7]=y1.w;
            }
            // diag in-register: lanes {l, l^16, l^32, l^48} cover all 64 d's of row l15
            {
                float s = 0.f;
#pragma unroll
                for (int j = 0; j < 8; ++j) s += xv[j] * xv[j] + yv[j] * yv[j];
                s += __shfl_xor(s, 16);
                s += __shfl_xor(s, 32);
                if (l4 == 0) (side ? dgk : dgq)[h * 16 + l15] = 0.5f * s;
            }
            short8 ah0, al0, ah1, al1;
#pragma unroll
            for (int j = 0; j < 8; ++j) {
                unsigned short hi, lo;
                split2(xv[j], hi, lo); ah0[j] = (short)hi; al0[j] = (short)lo;
                split2(yv[j], hi, lo); ah1[j] = (short)hi; al1[j] = (short)lo;
            }
            floatx4 acc2[2];
#pragma unroll
            for (int ct2 = 0; ct2 < 2; ++ct2) {
                floatx4 acc = floatx4{0.f, 0.f, 0.f, 0.f};
                acc = __builtin_amdgcn_mfma_f32_16x16x32_bf16(ah0, pbh[ct2][0], acc, 0, 0, 0);
                acc = __builtin_amdgcn_mfma_f32_16x16x32_bf16(ah1, pbh[ct2][1], acc, 0, 0, 0);
                acc = __builtin_amdgcn_mfma_f32_16x16x32_bf16(ah0, pbl[ct2][0], acc, 0, 0, 0);
                acc = __builtin_amdgcn_mfma_f32_16x16x32_bf16(ah1, pbl[ct2][1], acc, 0, 0, 0);
                acc = __builtin_amdgcn_mfma_f32_16x16x32_bf16(al0, pbh[ct2][0], acc, 0, 0, 0);
                acc = __builtin_amdgcn_mfma_f32_16x16x32_bf16(al1, pbh[ct2][1], acc, 0, 0, 0);
                acc2[ct2] = acc;
#pragma unroll
                for (int r = 0; r < 4; ++r)
                    dd[(row0 + r) * 132 + h * 32 + ct2 * 16 + l15] = acc[r];
            }
            // row-max in-register (pad cols m=30,31 masked to -inf)
#pragma unroll
            for (int r = 0; r < 4; ++r) {
                float a1 = (l15 >= 14) ? -3.4e38f : acc2[1][r];
                float v = fmaxf(acc2[0][r], a1);
                v = fmaxf(v, __shfl_xor(v, 1));
                v = fmaxf(v, __shfl_xor(v, 2));
                v = fmaxf(v, __shfl_xor(v, 4));
                v = fmaxf(v, __shfl_xor(v, 8));
                if (l15 == 0) (side ? kmx : qmx)[h * 16 + row0 + r] = v;
            }
        }
    }
    __syncthreads();

    // P3: blockmax fold + exp/store
    if (t < 4) {
        float mx = -3.4e38f;
        for (int row = 0; row < 16; ++row)
            if (n0 + row < N) mx = fmaxf(mx, kmx[t * 16 + row]);
        blockmax[blockIdx.x * 4 + t] = mx;
    }
    for (int idx = t; idx < 1920; idx += 256) {
        const int row = idx / 120, r = idx % 120, h = r / 30, m = r % 30;
        if (n0 + row < N) {
            float val = RATIO * (__expf(ddq[row * 132 + h * 32 + m] - dgq[h * 16 + row] - qmx[h * 16 + row]) + NEPS);
            qp16[(long)(n0 + row) * 120 + r] = __float2bfloat16(val);
            argk[(long)(n0 + row) * 120 + r] = ddk[row * 132 + h * 32 + m] - dgk[h * 16 + row];
        }
    }
}

__global__ __launch_bounds__(256) void k1b_redmax(
    const float* __restrict__ blockmax, float* __restrict__ headmax, int ntiles)
{
    __shared__ float red[4 * 256];
    const int t = threadIdx.x;
    float lm[4] = {-3.4e38f, -3.4e38f, -3.4e38f, -3.4e38f};
    for (int i = t; i < ntiles; i += 256) {
#pragma unroll
        for (int hh = 0; hh < 4; ++hh) lm[hh] = fmaxf(lm[hh], blockmax[i * 4 + hh]);
    }
#pragma unroll
    for (int hh = 0; hh < 4; ++hh) red[hh * 256 + t] = lm[hh];
    __syncthreads();
    if (t < 4) {
        float mx = red[t * 256];
        for (int i = 1; i < 256; ++i) mx = fmaxf(mx, red[t * 256 + i]);
        headmax[t] = mx;
    }
}

// ---- k2: MFMA accumulate; flush -> private slab (mode 1) or atomics (mode 0) ----
__global__ __launch_bounds__(256) void k2_kvs(
    const float* __restrict__ argk, const float* __restrict__ gum,
    const __hip_bfloat16* __restrict__ v16, const float* __restrict__ tau,
    const float* __restrict__ headmax,
    float* __restrict__ kvs, float* __restrict__ kssum,
    float* __restrict__ part, int mode, int N, int nchunk)
{
    __shared__ alignas(16) unsigned short Vt[80 * 72];
    __shared__ float kpL[64 * 33];
    __shared__ alignas(16) float geT[13 * 72];

    const int t = threadIdx.x;
    const int h = blockIdx.x >> 7;
    const int chunk = blockIdx.x & 127;
    const int n0 = chunk * nchunk;
    const int n1 = (n0 + nchunk < N) ? (n0 + nchunk) : N;
    const float MX = headmax[h];
    const float itau = 1.0f / tau[0];
    const int wave = t >> 6, lane = t & 63;
    const int l15 = lane & 15, l4 = lane >> 4;

    int ar_r[8], ar_m[8];
#pragma unroll
    for (int u = 0; u < 8; ++u) { int i = t + 256 * u; ar_r[u] = i / 30; ar_m[u] = i % 30; }
    int gu_k[3], gu_n[3];
#pragma unroll
    for (int u = 0; u < 3; ++u) { int i = t + 256 * u; gu_k[u] = i >> 6; gu_n[u] = i & 63; }
    int v_n[8], v_dp[8];
#pragma unroll
    for (int u = 0; u < 8; ++u) { int i = t + 256 * u; v_n[u] = i >> 5; v_dp[u] = (i & 31) * 2; }

    float ra[8], rg[3];
    unsigned int rv[8];

    floatx4 acc[5][5];
#pragma unroll
    for (int q = 0; q < 5; ++q)
#pragma unroll
        for (int dt = 0; dt < 5; ++dt) acc[q][dt] = floatx4{0.f, 0.f, 0.f, 0.f};

    int mq[5], kq[5];
#pragma unroll
    for (int q = 0; q < 5; ++q) {
        int row = (wave * 5 + q) * 16 + l15;
        mq[q] = row % 30;
        kq[q] = row / 30;
    }

    if (t < 64) Vt[64 * 72 + t] = f2bf(1.0f);
    for (int i = t; i < 15 * 72; i += 256) Vt[65 * 72 + i] = 0;
    for (int i = t; i < 3 * 72; i += 256) geT[10 * 72 + i] = 0.f;

    const int ntile = (n1 - n0 + 63) >> 6;

#define K2_LOAD(nb_)                                                              \
    do {                                                                          \
        _Pragma("unroll")                                                         \
        for (int u = 0; u < 8; ++u) {                                             \
            int n = (nb_) + ar_r[u]; n = (n < n1) ? n : (n1 - 1);                  \
            ra[u] = argk[(long)n * 120 + h * 30 + ar_m[u]];                       \
        }                                                                         \
        _Pragma("unroll")                                                         \
        for (int u = 0; u < 3; ++u) {                                             \
            int n = (nb_) + gu_n[u]; n = (n < n1) ? n : (n1 - 1);                  \
            rg[u] = gum[(long)n * 40 + h * 10 + gu_k[u]];                         \
        }                                                                         \
        _Pragma("unroll")                                                         \
        for (int u = 0; u < 8; ++u) {                                             \
            int n = (nb_) + v_n[u]; n = (n < n1) ? n : (n1 - 1);                   \
            rv[u] = *reinterpret_cast<const unsigned int*>(                       \
                v16 + (long)n * 256 + h * 64 + v_dp[u]);                          \
        }                                                                         \
    } while (0)

    K2_LOAD(n0);

    for (int tt = 0; tt < ntile; ++tt) {
        const int nb = n0 + tt * 64;
        __syncthreads();
#pragma unroll
        for (int u = 0; u < 8; ++u) {
            if (u < 7 || t < 128) {
                bool ok = (nb + ar_r[u] < n1);
                kpL[ar_r[u] * 33 + ar_m[u]] =
                    ok ? RATIO * (__expf(ra[u] - MX) + NEPS) : 0.f;
            }
        }
#pragma unroll
        for (int u = 0; u < 3; ++u) {
            if (u < 2 || t < 128) {
                bool ok = (nb + gu_n[u] < n1);
                geT[gu_k[u] * 72 + gu_n[u]] = ok ? __expf(rg[u] * itau) : 0.f;
            }
        }
#pragma unroll
        for (int u = 0; u < 8; ++u) {
            bool ok = (nb + v_n[u] < n1);
            unsigned int uu = ok ? rv[u] : 0u;
            Vt[v_dp[u] * 72 + v_n[u]] = (unsigned short)(uu & 0xffffu);
            Vt[(v_dp[u] + 1) * 72 + v_n[u]] = (unsigned short)(uu >> 16);
        }
        __syncthreads();
        if (tt + 1 < ntile) K2_LOAD(nb + 64);

#pragma unroll
        for (int nh = 0; nh < 2; ++nh) {
            const int nbase = nh * 32 + l4 * 8;
            short8 b[5];
#pragma unroll
            for (int dt = 0; dt < 5; ++dt)
                b[dt] = *reinterpret_cast<const short8*>(&Vt[(dt * 16 + l15) * 72 + nbase]);
#pragma unroll
            for (int q = 0; q < 5; ++q) {
                float4 g0 = *reinterpret_cast<const float4*>(&geT[kq[q] * 72 + nbase]);
                float4 g1 = *reinterpret_cast<const float4*>(&geT[kq[q] * 72 + nbase + 4]);
                const float gg[8] = {g0.x, g0.y, g0.z, g0.w, g1.x, g1.y, g1.z, g1.w};
                short8 a;
#pragma unroll
                for (int j = 0; j < 8; ++j) {
                    float kp = kpL[(nbase + j) * 33 + mq[q]];
                    a[j] = (short)f2bf(kp * gg[j]);
                }
#pragma unroll
                for (int dt = 0; dt < 5; ++dt)
                    acc[q][dt] = __builtin_amdgcn_mfma_f32_16x16x32_bf16(a, b[dt], acc[q][dt], 0, 0, 0);
            }
        }
    }
#undef K2_LOAD

    if (mode) {
        float* slab = part + (long)blockIdx.x * 19520;
#pragma unroll
        for (int q = 0; q < 5; ++q) {
            const int kmb = (wave * 5 + q) * 16 + l4 * 4;
#pragma unroll
            for (int r = 0; r < 4; ++r) {
                const int km = kmb + r;
                if (km < 300) {
#pragma unroll
                    for (int dt = 0; dt < 4; ++dt)
                        slab[km * 64 + dt * 16 + l15] = acc[q][dt][r];
                    if (l15 == 0) slab[19200 + km] = acc[q][4][r];
                }
            }
        }
    } else {
        float* kvh = kvs + h * 19200;
#pragma unroll
        for (int q = 0; q < 5; ++q) {
            const int kmb = (wave * 5 + q) * 16 + l4 * 4;
#pragma unroll
            for (int r = 0; r < 4; ++r) {
                const int km = kmb + r;
                if (km < 300) {
#pragma unroll
                    for (int dt = 0; dt < 4; ++dt)
                        atomicAdd(&kvh[km * 64 + dt * 16 + l15], acc[q][dt][r]);
                    if (l15 == 0)
                        atomicAdd(&kssum[h * 300 + km], acc[q][4][r]);
                }
            }
        }
    }
}

// ---- k2r: reduce 128 chunk-slabs per head -> kvs, kssum ----
__global__ __launch_bounds__(256) void k2r_reduce(
    const float* __restrict__ part, float* __restrict__ kvs, float* __restrict__ kssum)
{
    const int o = blockIdx.x * 256 + threadIdx.x;
    if (o >= 4 * 19504) return;
    const int h = o / 19504, e = o % 19504;
    const float* p = part + (long)h * 128 * 19520 + e;
    float s = 0.f;
#pragma unroll 8
    for (int c = 0; c < 128; ++c) s += p[(long)c * 19520];
    if (e < 19200) kvs[h * 19200 + e] = s;
    else if (e - 19200 < 300) kssum[h * 300 + (e - 19200)] = s;
}

// ---- k2b: split kvs into fragment-ordered hi/lo bf16 (unchanged) ----
__global__ __launch_bounds__(256) void k2b_frag(
    const float* __restrict__ kvs,
    unsigned short* __restrict__ Bfh, unsigned short* __restrict__ Bfl)
{
    const int slot = blockIdx.x * 256 + threadIdx.x;
    if (slot >= 10240) return;
    const int h = slot / 2560;
    const int rem = slot % 2560;
    const int ct = rem >> 6, lane = rem & 63;
    const int col = ct * 16 + (lane & 15);
    const int k = col >> 6, d = col & 63;
    const int mb = (lane >> 4) * 8;
    const float* src = kvs + h * 19200 + (k * 30 + mb) * 64 + d;
    short8 hi8, lo8;
#pragma unroll
    for (int j = 0; j < 8; ++j) {
        float v = (mb + j < 30) ? src[j * 64] : 0.f;
        unsigned short hh, ll; split2(v, hh, ll);
        hi8[j] = (short)hh; lo8[j] = (short)ll;
    }
    *reinterpret_cast<short8*>(&Bfh[(long)slot * 8]) = hi8;
    *reinterpret_cast<short8*>(&Bfl[(long)slot * 8]) = lo8;
}

// ---- k3: unchanged from round 11 ----
__global__ __launch_bounds__(512) void k3_out(
    const __hip_bfloat16* __restrict__ qp16,
    const unsigned short* __restrict__ Bfh, const unsigned short* __restrict__ Bfl,
    const float* __restrict__ kssum,
    const unsigned short* __restrict__ Wofh, const unsigned short* __restrict__ Wofl,
    const float* __restrict__ bo, float* __restrict__ out, int N)
{
    __shared__ alignas(16) unsigned short qpall[32 * 136];
    __shared__ float ksall[1200];
    __shared__ float idla[4 * 320];
    __shared__ alignas(16) float part[2][32][68];
    __shared__ alignas(16) float zl[32 * 260];

    const int t = threadIdx.x;
    const int n0 = blockIdx.x * 32;
    const int wave = t >> 6, lane = t & 63;
    const int g = wave & 3, khalf = wave >> 2;
    const int l15 = lane & 15, l4 = lane >> 4;

    for (int i = t; i < 1200; i += 512) ksall[i] = kssum[i];
    for (int i = t; i < 32 * 60; i += 512) {
        int rr = i / 60, dw = i % 60;
        int n = n0 + rr; if (n >= N) n = N - 1;
        unsigned int u = *reinterpret_cast<const unsigned int*>(
            (const unsigned short*)qp16 + (long)n * 120 + dw * 2);
        int h = dw / 15, md = (dw % 15) * 2;
        qpall[rr * 136 + h * 32 + md] = (unsigned short)(u & 0xffffu);
        qpall[rr * 136 + h * 32 + md + 1] = (unsigned short)(u >> 16);
    }
    __syncthreads();

    for (int i = t; i < 1280; i += 512) {
        int h = i / 320, rem = i % 320;
        int rr = rem / 10, kk = rem % 10;
        const unsigned short* qr = &qpall[rr * 136 + h * 32];
        const float* kr = &ksall[h * 300 + kk * 30];
        float s = 0.f;
#pragma unroll
        for (int m = 0; m < 30; ++m) s += bf2f(qr[m]) * kr[m];
        idla[i] = 1.0f / s;
    }
    __syncthreads();

    for (int h = 0; h < 4; ++h) {
        short8 bh[5], bl[5];
#pragma unroll
        for (int q = 0; q < 5; ++q) {
            const int ct = (khalf * 5 + q) * 4 + g;
            const long off = ((long)(h * 40 + ct) * 64 + lane) * 8;
            bh[q] = *reinterpret_cast<const short8*>(Bfh + off);
            bl[q] = *reinterpret_cast<const short8*>(Bfl + off);
        }
        short8 aQ[2];
#pragma unroll
        for (int rt = 0; rt < 2; ++rt) {
            const unsigned int* qrow = reinterpret_cast<const unsigned int*>(
                &qpall[(rt * 16 + l15) * 136 + h * 32 + l4 * 8]);
            short8 a;
#pragma unroll
            for (int jj = 0; jj < 4; ++jj) {
                unsigned int u = qrow[jj];
                a[jj * 2] = (short)(u & 0xffffu);
                a[jj * 2 + 1] = (short)(u >> 16);
            }
            if (l4 == 3) { a[6] = 0; a[7] = 0; }
            aQ[rt] = a;
        }
        floatx4 acc[2][5];
#pragma unroll
        for (int rt = 0; rt < 2; ++rt)
#pragma unroll
            for (int q = 0; q < 5; ++q) acc[rt][q] = floatx4{0.f, 0.f, 0.f, 0.f};
#pragma unroll
        for (int q = 0; q < 5; ++q) {
            acc[0][q] = __builtin_amdgcn_mfma_f32_16x16x32_bf16(aQ[0], bh[q], acc[0][q], 0, 0, 0);
            acc[0][q] = __builtin_amdgcn_mfma_f32_16x16x32_bf16(aQ[0], bl[q], acc[0][q], 0, 0, 0);
            acc[1][q] = __builtin_amdgcn_mfma_f32_16x16x32_bf16(aQ[1], bh[q], acc[1][q], 0, 0, 0);
            acc[1][q] = __builtin_amdgcn_mfma_f32_16x16x32_bf16(aQ[1], bl[q], acc[1][q], 0, 0, 0);
        }
#pragma unroll
        for (int rt = 0; rt < 2; ++rt)
#pragma unroll
            for (int r = 0; r < 4; ++r) {
                const int row = rt * 16 + l4 * 4 + r;
                float s = 0.f;
#pragma unroll
                for (int q = 0; q < 5; ++q)
                    s += acc[rt][q][r] * idla[h * 320 + row * 10 + khalf * 5 + q];
                part[khalf][row][g * 16 + l15] = s;
            }
        __syncthreads();
        {
            const int row = t >> 4, d4 = t & 15;
            float4 p0 = *reinterpret_cast<const float4*>(&part[0][row][d4 * 4]);
            float4 p1 = *reinterpret_cast<const float4*>(&part[1][row][d4 * 4]);
            float4 zv;
            zv.x = 0.1f * (p0.x + p1.x); zv.y = 0.1f * (p0.y + p1.y);
            zv.z = 0.1f * (p0.z + p1.z); zv.w = 0.1f * (p0.w + p1.w);
            reinterpret_cast<float4*>(zl)[row * 65 + h * 16 + d4] = zv;
        }
        __syncthreads();
    }
    {
        const int rt = wave >> 2, ct = wave & 3;
        floatx4 o = floatx4{0.f, 0.f, 0.f, 0.f};
#pragma unroll
        for (int ks = 0; ks < 8; ++ks) {
            const float* zr = &zl[(rt * 16 + l15) * 260 + ks * 32 + l4 * 8];
            float4 x0 = *reinterpret_cast<const float4*>(zr);
            float4 x1 = *reinterpret_cast<const float4*>(zr + 4);
            float xv[8] = {x0.x, x0.y, x0.z, x0.w, x1.x, x1.y, x1.z, x1.w};
            short8 ah, al;
#pragma unroll
            for (int j = 0; j < 8; ++j) {
                unsigned short hi, lo; split2(xv[j], hi, lo);
                ah[j] = (short)hi; al[j] = (short)lo;
            }
            const int slot = ct * 8 + ks;
            short8 wbh = *reinterpret_cast<const short8*>(&Wofh[slot * 512 + lane * 8]);
            short8 wbl = *reinterpret_cast<const short8*>(&Wofl[slot * 512 + lane * 8]);
            o = __builtin_amdgcn_mfma_f32_16x16x32_bf16(ah, wbh, o, 0, 0, 0);
            o = __builtin_amdgcn_mfma_f32_16x16x32_bf16(ah, wbl, o, 0, 0, 0);
            o = __builtin_amdgcn_mfma_f32_16x16x32_bf16(al, wbh, o, 0, 0, 0);
        }
        const int col = ct * 16 + l15;
        const float bb = bo[col];
#pragma unroll
        for (int r = 0; r < 4; ++r) {
            const int n = n0 + rt * 16 + l4 * 4 + r;
            if (n < N) out[(long)n * 64 + col] = o[r] + bb;
        }
    }
}

extern "C" void kernel_launch(void* const* d_in, const int* in_sizes, int n_in,
                              void* d_out, int out_size, void* d_ws, size_t ws_size,
                              hipStream_t stream)
{
    const float* z    = (const float*)d_in[0];
    const float* Wq   = (const float*)d_in[1];
    const float* bq   = (const float*)d_in[2];
    const float* Wk   = (const float*)d_in[3];
    const float* bk   = (const float*)d_in[4];
    const float* Wv   = (const float*)d_in[5];
    const float* bv   = (const float*)d_in[6];
    const float* Wo   = (const float*)d_in[7];
    const float* bo   = (const float*)d_in[8];
    const float* proj = (const float*)d_in[9];
    const float* gum  = (const float*)d_in[10];
    const float* tau  = (const float*)d_in[11];
    float* out = (float*)d_out;

    const int N = in_sizes[0] / 64;          // 50000
    const int ntiles = (N + 15) / 16;        // 3125
    const int nchunk = (N + 127) / 128;      // 391
    const int nblk3  = (N + 31) / 32;        // 1563

    char* wsb = (char*)d_ws;
    size_t off = 0;
    __hip_bfloat16* qp16 = (__hip_bfloat16*)(wsb);
    off += ((size_t)N * 120 * 2 + 255) & ~(size_t)255;
    __hip_bfloat16* v16 = (__hip_bfloat16*)(wsb + off);
    off += ((size_t)N * 256 * 2 + 255) & ~(size_t)255;
    float* argk = (float*)(wsb + off);
    off += ((size_t)N * 120 * 4 + 255) & ~(size_t)255;
    float* kvs      = (float*)(wsb + off);
    float* kssum    = kvs + 76800;
    float* headmax  = kssum + 1200;
    float* blockmax = headmax + 4;
    off += ((size_t)(76800 + 1200 + 4 + (size_t)ntiles * 4) * 4 + 255) & ~(size_t)255;
    unsigned short* Wfh = (unsigned short*)(wsb + off); off += 49152 * 2;
    unsigned short* Wfl = (unsigned short*)(wsb + off); off += 49152 * 2;
    unsigned short* Pfh = (unsigned short*)(wsb + off); off += 2048 * 2;
    unsigned short* Pfl = (unsigned short*)(wsb + off); off += 2048 * 2;
    unsigned short* Wofh = (unsigned short*)(wsb + off); off += 16384 * 2;
    unsigned short* Wofl = (unsigned short*)(wsb + off); off += 16384 * 2;
    unsigned short* Bfh  = (unsigned short*)(wsb + off); off += 81920 * 2;
    unsigned short* Bfl  = (unsigned short*)(wsb + off); off += 81920 * 2;
    off = (off + 255) & ~(size_t)255;
    float* part = (float*)(wsb + off);
    const size_t part_bytes = (size_t)512 * 19520 * 4;
    const int mode = (ws_size >= off + part_bytes) ? 1 : 0;   // two-stage if ws fits

    k_prep<<<dim3(26), dim3(256), 0, stream>>>(Wq, Wk, Wv, proj, Wo,
                                               Wfh, Wfl, Pfh, Pfl, Wofh, Wofl);
    if (!mode)
        k0_zero<<<dim3((78000 + 255) / 256), dim3(256), 0, stream>>>(kvs, 78000);
    k1_feat<<<dim3(ntiles), dim3(256), 0, stream>>>(z, bq, bk, bv, Wfh, Wfl, Pfh, Pfl, tau,
                                                    qp16, v16, argk, blockmax, N);
    k1b_redmax<<<dim3(1), dim3(256), 0, stream>>>(blockmax, headmax, ntiles);
    k2_kvs<<<dim3(512), dim3(256), 0, stream>>>(argk, gum, v16, tau, headmax,
                                                kvs, kssum, part, mode, N, nchunk);
    if (mode)
        k2r_reduce<<<dim3((4 * 19504 + 255) / 256), dim3(256), 0, stream>>>(part, kvs, kssum);
    k2b_frag<<<dim3(40), dim3(256), 0, stream>>>(kvs, Bfh, Bfl);
    k3_out<<<dim3(nblk3), dim3(512), 0, stream>>>(qp16, Bfh, Bfl, kssum,
                                                  Wofh, Wofl, bo, out, N);
}

// Round 13
// 197.568 us; speedup vs baseline: 35.3977x; 1.0946x over previous
//
#include <hip/hip_runtime.h>
#include <hip/hip_bf16.h>

// NodeFormerConv: Performer/Gumbel attention. fp32-equivalent math, fp32 output.
//   k_prep: split Wq|Wk|Wv, proj, Wo into MFMA-fragment-ordered hi/lo bf16
//   (k0   zero kvs/kssum — only in atomic-fallback mode)
//   k1   per 16-row tile, MFMA: QKV gemm -> qd/kd LDS + v16; phi gemm; diag,
//        rowmax, exp, qp16/argk stores ALL IN-REGISTER (no dd LDS, 2 barriers)
//   k1b  blockmax -> headmax[4]
//   k2   MFMA accumulate, batched+prefetched staging; flush -> private slab
//   k2r  reduce 128 chunk-slabs per head -> kvs, kssum
//   k2b  split kvs into fragment-ordered hi/lo bf16 (once, global)
//   k3   per 32-row block: den up front; B-frags from global, NUM MFMA,
//        in-register idl scale, part exchange -> zl; out = zl@Wo + bo (f32)

#define NEPS  1e-6f
#define RATIO 0.18257418583505536f   // 1/sqrt(30)
#define DNORM 0.35355339059327378f   // 64^-0.25

typedef __attribute__((ext_vector_type(8))) short short8;
typedef __attribute__((ext_vector_type(4))) float floatx4;

__device__ inline unsigned short f2bf(float x) {
    __hip_bfloat16 b = __float2bfloat16(x);
    return __builtin_bit_cast(unsigned short, b);
}
__device__ inline float bf2f(unsigned short h) {
    return __builtin_bit_cast(float, (unsigned int)h << 16);
}
__device__ inline void split2(float v, unsigned short& hi, unsigned short& lo) {
    unsigned short h = f2bf(v);
    hi = h; lo = f2bf(v - bf2f(h));
}

__global__ __launch_bounds__(256) void k0_zero(float* __restrict__ p, int count) {
    int id = blockIdx.x * 256 + threadIdx.x;
    if (id < count) p[id] = 0.f;
}

// ---- k_prep: fragment-ordered hi/lo splits (unchanged) ----
__global__ __launch_bounds__(256) void k_prep(
    const float* __restrict__ Wq, const float* __restrict__ Wk, const float* __restrict__ Wv,
    const float* __restrict__ proj, const float* __restrict__ Wo,
    unsigned short* __restrict__ Wfh, unsigned short* __restrict__ Wfl,
    unsigned short* __restrict__ Pfh, unsigned short* __restrict__ Pfl,
    unsigned short* __restrict__ Wofh, unsigned short* __restrict__ Wofl)
{
    const int b = blockIdx.x, t = threadIdx.x;
    if (b < 24) {
        const int slot = b * 256 + t;
        const int lane = slot & 63;
        const int ctks = slot >> 6;
        const int ct = ctks >> 1, ks = ctks & 1;
        const int col = ct * 16 + (lane & 15);
        const int k0 = ks * 32 + (lane >> 4) * 8;
        const float* W = (col < 256) ? Wq : (col < 512) ? Wk : Wv;
        const int cm = col & 255;
#pragma unroll
        for (int j = 0; j < 8; ++j) {
            float w = W[(k0 + j) * 256 + cm];
            unsigned short hi, lo; split2(w, hi, lo);
            Wfh[slot * 8 + j] = hi;
            Wfl[slot * 8 + j] = lo;
        }
    } else if (b == 24) {
        const int lane = t & 63;
        const int ctks = t >> 6;
        const int ct2 = ctks >> 1, ks = ctks & 1;
        const int m = ct2 * 16 + (lane & 15);
        const int k0 = ks * 32 + (lane >> 4) * 8;
#pragma unroll
        for (int j = 0; j < 8; ++j) {
            float p = (m < 30) ? proj[m * 64 + k0 + j] : 0.f;
            unsigned short hi, lo; split2(p, hi, lo);
            Pfh[t * 8 + j] = hi;
            Pfl[t * 8 + j] = lo;
        }
    } else {
        for (int idx = t; idx < 2048; idx += 256) {
            const int slot = idx >> 6, l = idx & 63;
            const int ct = slot >> 3, ks = slot & 7;
            const int col = ct * 16 + (l & 15);
            const int k0 = ks * 32 + (l >> 4) * 8;
#pragma unroll
            for (int j = 0; j < 8; ++j) {
                float w = Wo[(k0 + j) * 64 + col];
                unsigned short hi, lo; split2(w, hi, lo);
                Wofh[slot * 512 + l * 8 + j] = hi;
                Wofl[slot * 512 + l * 8 + j] = lo;
            }
        }
    }
}

// ---- k1: per 16-row tile, MFMA QKV + phi; fully in-register epilogue ----
__global__ __launch_bounds__(256) void k1_feat(
    const float* __restrict__ z,
    const float* __restrict__ bq, const float* __restrict__ bk, const float* __restrict__ bv,
    const unsigned short* __restrict__ Wfh, const unsigned short* __restrict__ Wfl,
    const unsigned short* __restrict__ Pfh, const unsigned short* __restrict__ Pfl,
    const float* __restrict__ tau,
    __hip_bfloat16* __restrict__ qp16, __hip_bfloat16* __restrict__ v16,
    float* __restrict__ argk, float* __restrict__ blockmax, int N)
{
    __shared__ alignas(16) unsigned short zh[16 * 72];
    __shared__ alignas(16) unsigned short zl_[16 * 72];
    __shared__ alignas(16) float qd[16 * 268];   // stride 268: benign banks
    __shared__ alignas(16) float kd[16 * 268];

    const int t = threadIdx.x;
    const int n0 = blockIdx.x * 16;
    const int wave = t >> 6, lane = t & 63;
    const int l15 = lane & 15, l4 = lane >> 4;
    const float dsc = rsqrtf(tau[0]) * DNORM;

    // P0: load z rows, split hi/lo
    for (int i = t; i < 1024; i += 256) {
        int r = i >> 6, c = i & 63;
        float v = (n0 + r < N) ? z[(long)(n0 + r) * 64 + c] : 0.f;
        unsigned short hi, lo; split2(v, hi, lo);
        zh[r * 72 + c] = hi;
        zl_[r * 72 + c] = lo;
    }
    __syncthreads();

    // P1: QKV GEMM. wave w: col-tiles 12w..12w+11
    {
        const int abase = l15 * 72 + l4 * 8;
        short8 ah0 = *reinterpret_cast<const short8*>(&zh[abase]);
        short8 ah1 = *reinterpret_cast<const short8*>(&zh[abase + 32]);
        short8 al0 = *reinterpret_cast<const short8*>(&zl_[abase]);
        short8 al1 = *reinterpret_cast<const short8*>(&zl_[abase + 32]);
        const int row0 = l4 * 4;
#pragma unroll 2
        for (int ci = 0; ci < 12; ++ci) {
            const int ct = wave * 12 + ci;
            short8 bh0 = *reinterpret_cast<const short8*>(&Wfh[(ct * 2 + 0) * 512 + lane * 8]);
            short8 bh1 = *reinterpret_cast<const short8*>(&Wfh[(ct * 2 + 1) * 512 + lane * 8]);
            short8 bl0 = *reinterpret_cast<const short8*>(&Wfl[(ct * 2 + 0) * 512 + lane * 8]);
            short8 bl1 = *reinterpret_cast<const short8*>(&Wfl[(ct * 2 + 1) * 512 + lane * 8]);
            floatx4 acc = floatx4{0.f, 0.f, 0.f, 0.f};
            acc = __builtin_amdgcn_mfma_f32_16x16x32_bf16(ah0, bh0, acc, 0, 0, 0);
            acc = __builtin_amdgcn_mfma_f32_16x16x32_bf16(ah1, bh1, acc, 0, 0, 0);
            acc = __builtin_amdgcn_mfma_f32_16x16x32_bf16(ah0, bl0, acc, 0, 0, 0);
            acc = __builtin_amdgcn_mfma_f32_16x16x32_bf16(ah1, bl1, acc, 0, 0, 0);
            acc = __builtin_amdgcn_mfma_f32_16x16x32_bf16(al0, bh0, acc, 0, 0, 0);
            acc = __builtin_amdgcn_mfma_f32_16x16x32_bf16(al1, bh1, acc, 0, 0, 0);
            const int c = ct * 16 + l15;
            if (c < 256) {
                const float bb = bq[c];
#pragma unroll
                for (int r = 0; r < 4; ++r) qd[(row0 + r) * 268 + c] = (acc[r] + bb) * dsc;
            } else if (c < 512) {
                const float bb = bk[c - 256];
#pragma unroll
                for (int r = 0; r < 4; ++r) kd[(row0 + r) * 268 + (c - 256)] = (acc[r] + bb) * dsc;
            } else {
                const float bb = bv[c - 512];
#pragma unroll
                for (int r = 0; r < 4; ++r)
                    if (n0 + row0 + r < N)
                        v16[(long)(n0 + row0 + r) * 256 + (c - 512)] = __float2bfloat16(acc[r] + bb);
            }
        }
    }
    __syncthreads();

    // P2: phi MFMA (wave w: head w) + diag/rowmax/exp/store fully in-register
    {
        short8 pbh[2][2], pbl[2][2];
#pragma unroll
        for (int ct2 = 0; ct2 < 2; ++ct2)
#pragma unroll
            for (int ks = 0; ks < 2; ++ks) {
                pbh[ct2][ks] = *reinterpret_cast<const short8*>(&Pfh[(ct2 * 2 + ks) * 512 + lane * 8]);
                pbl[ct2][ks] = *reinterpret_cast<const short8*>(&Pfl[(ct2 * 2 + ks) * 512 + lane * 8]);
            }
        const int h = wave;
        const int row0 = l4 * 4;
#pragma unroll
        for (int side = 0; side < 2; ++side) {
            const float* dat = side ? kd : qd;
            const int rbase = l15 * 268 + h * 64 + l4 * 8;
            float xv[8], yv[8];
            {
                float4 x0 = *reinterpret_cast<const float4*>(&dat[rbase]);
                float4 x1 = *reinterpret_cast<const float4*>(&dat[rbase + 4]);
                float4 y0 = *reinterpret_cast<const float4*>(&dat[rbase + 32]);
                float4 y1 = *reinterpret_cast<const float4*>(&dat[rbase + 36]);
                xv[0]=x0.x; xv[1]=x0.y; xv[2]=x0.z; xv[3]=x0.w;
                xv[4]=x1.x; xv[5]=x1.y; xv[6]=x1.z; xv[7]=x1.w;
                yv[0]=y0.x; yv[1]=y0.y; yv[2]=y0.z; yv[3]=y0.w;
                yv[4]=y1.x; yv[5]=y1.y; yv[6]=y1.z; yv[7]=y1.w;
            }
            // diag: lanes {l, l^16, l^32, l^48} cover all 64 d's; butterfly -> all lanes
            float diag;
            {
                float s = 0.f;
#pragma unroll
                for (int j = 0; j < 8; ++j) s += xv[j] * xv[j] + yv[j] * yv[j];
                s += __shfl_xor(s, 16);
                s += __shfl_xor(s, 32);
                diag = 0.5f * s;
            }
            short8 ah0, al0, ah1, al1;
#pragma unroll
            for (int j = 0; j < 8; ++j) {
                unsigned short hi, lo;
                split2(xv[j], hi, lo); ah0[j] = (short)hi; al0[j] = (short)lo;
                split2(yv[j], hi, lo); ah1[j] = (short)hi; al1[j] = (short)lo;
            }
            floatx4 acc2[2];
#pragma unroll
            for (int ct2 = 0; ct2 < 2; ++ct2) {
                floatx4 acc = floatx4{0.f, 0.f, 0.f, 0.f};
                acc = __builtin_amdgcn_mfma_f32_16x16x32_bf16(ah0, pbh[ct2][0], acc, 0, 0, 0);
                acc = __builtin_amdgcn_mfma_f32_16x16x32_bf16(ah1, pbh[ct2][1], acc, 0, 0, 0);
                acc = __builtin_amdgcn_mfma_f32_16x16x32_bf16(ah0, pbl[ct2][0], acc, 0, 0, 0);
                acc = __builtin_amdgcn_mfma_f32_16x16x32_bf16(ah1, pbl[ct2][1], acc, 0, 0, 0);
                acc = __builtin_amdgcn_mfma_f32_16x16x32_bf16(al0, pbh[ct2][0], acc, 0, 0, 0);
                acc = __builtin_amdgcn_mfma_f32_16x16x32_bf16(al1, pbh[ct2][1], acc, 0, 0, 0);
                acc2[ct2] = acc;
            }
            // row-max (pad m=30,31 -> -inf); butterfly over l15 bits -> all lanes
            float vmax[4];
#pragma unroll
            for (int r = 0; r < 4; ++r) {
                float a1 = (l15 >= 14) ? -3.4e38f : acc2[1][r];
                float v = fmaxf(acc2[0][r], a1);
                v = fmaxf(v, __shfl_xor(v, 1));
                v = fmaxf(v, __shfl_xor(v, 2));
                v = fmaxf(v, __shfl_xor(v, 4));
                v = fmaxf(v, __shfl_xor(v, 8));
                vmax[r] = v;
            }
            if (side == 0) {
#pragma unroll
                for (int ct2 = 0; ct2 < 2; ++ct2) {
                    const int m = ct2 * 16 + l15;
                    if (m < 30) {
#pragma unroll
                        for (int r = 0; r < 4; ++r) {
                            const int n = n0 + row0 + r;
                            if (n < N) {
                                float val = RATIO * (__expf(acc2[ct2][r] - diag - vmax[r]) + NEPS);
                                ((unsigned short*)qp16)[(long)n * 120 + h * 30 + m] = f2bf(val);
                            }
                        }
                    }
                }
            } else {
#pragma unroll
                for (int ct2 = 0; ct2 < 2; ++ct2) {
                    const int m = ct2 * 16 + l15;
                    if (m < 30) {
#pragma unroll
                        for (int r = 0; r < 4; ++r) {
                            const int n = n0 + row0 + r;
                            if (n < N)
                                argk[(long)n * 120 + h * 30 + m] = acc2[ct2][r] - diag;
                        }
                    }
                }
                // per-wave blockmax for head h (valid rows only)
                float mv = -3.4e38f;
#pragma unroll
                for (int r = 0; r < 4; ++r)
                    if (n0 + row0 + r < N) mv = fmaxf(mv, vmax[r]);
                mv = fmaxf(mv, __shfl_xor(mv, 16));
                mv = fmaxf(mv, __shfl_xor(mv, 32));
                if (lane == 0) blockmax[blockIdx.x * 4 + h] = mv;
            }
        }
    }
}

__global__ __launch_bounds__(256) void k1b_redmax(
    const float* __restrict__ blockmax, float* __restrict__ headmax, int ntiles)
{
    __shared__ float red[4 * 256];
    const int t = threadIdx.x;
    float lm[4] = {-3.4e38f, -3.4e38f, -3.4e38f, -3.4e38f};
    for (int i = t; i < ntiles; i += 256) {
#pragma unroll
        for (int hh = 0; hh < 4; ++hh) lm[hh] = fmaxf(lm[hh], blockmax[i * 4 + hh]);
    }
#pragma unroll
    for (int hh = 0; hh < 4; ++hh) red[hh * 256 + t] = lm[hh];
    __syncthreads();
    if (t < 4) {
        float mx = red[t * 256];
        for (int i = 1; i < 256; ++i) mx = fmaxf(mx, red[t * 256 + i]);
        headmax[t] = mx;
    }
}

// ---- k2: MFMA accumulate; flush -> private slab (mode 1) or atomics (mode 0) ----
__global__ __launch_bounds__(256) void k2_kvs(
    const float* __restrict__ argk, const float* __restrict__ gum,
    const __hip_bfloat16* __restrict__ v16, const float* __restrict__ tau,
    const float* __restrict__ headmax,
    float* __restrict__ kvs, float* __restrict__ kssum,
    float* __restrict__ part, int mode, int N, int nchunk)
{
    __shared__ alignas(16) unsigned short Vt[80 * 72];
    __shared__ float kpL[64 * 33];
    __shared__ alignas(16) float geT[13 * 72];

    const int t = threadIdx.x;
    const int h = blockIdx.x >> 7;
    const int chunk = blockIdx.x & 127;
    const int n0 = chunk * nchunk;
    const int n1 = (n0 + nchunk < N) ? (n0 + nchunk) : N;
    const float MX = headmax[h];
    const float itau = 1.0f / tau[0];
    const int wave = t >> 6, lane = t & 63;
    const int l15 = lane & 15, l4 = lane >> 4;

    int ar_r[8], ar_m[8];
#pragma unroll
    for (int u = 0; u < 8; ++u) { int i = t + 256 * u; ar_r[u] = i / 30; ar_m[u] = i % 30; }
    int gu_k[3], gu_n[3];
#pragma unroll
    for (int u = 0; u < 3; ++u) { int i = t + 256 * u; gu_k[u] = i >> 6; gu_n[u] = i & 63; }
    int v_n[8], v_dp[8];
#pragma unroll
    for (int u = 0; u < 8; ++u) { int i = t + 256 * u; v_n[u] = i >> 5; v_dp[u] = (i & 31) * 2; }

    float ra[8], rg[3];
    unsigned int rv[8];

    floatx4 acc[5][5];
#pragma unroll
    for (int q = 0; q < 5; ++q)
#pragma unroll
        for (int dt = 0; dt < 5; ++dt) acc[q][dt] = floatx4{0.f, 0.f, 0.f, 0.f};

    int mq[5], kq[5];
#pragma unroll
    for (int q = 0; q < 5; ++q) {
        int row = (wave * 5 + q) * 16 + l15;
        mq[q] = row % 30;
        kq[q] = row / 30;
    }

    if (t < 64) Vt[64 * 72 + t] = f2bf(1.0f);
    for (int i = t; i < 15 * 72; i += 256) Vt[65 * 72 + i] = 0;
    for (int i = t; i < 3 * 72; i += 256) geT[10 * 72 + i] = 0.f;

    const int ntile = (n1 - n0 + 63) >> 6;

#define K2_LOAD(nb_)                                                              \
    do {                                                                          \
        _Pragma("unroll")                                                         \
        for (int u = 0; u < 8; ++u) {                                             \
            int n = (nb_) + ar_r[u]; n = (n < n1) ? n : (n1 - 1);                  \
            ra[u] = argk[(long)n * 120 + h * 30 + ar_m[u]];                       \
        }                                                                         \
        _Pragma("unroll")                                                         \
        for (int u = 0; u < 3; ++u) {                                             \
            int n = (nb_) + gu_n[u]; n = (n < n1) ? n : (n1 - 1);                  \
            rg[u] = gum[(long)n * 40 + h * 10 + gu_k[u]];                         \
        }                                                                         \
        _Pragma("unroll")                                                         \
        for (int u = 0; u < 8; ++u) {                                             \
            int n = (nb_) + v_n[u]; n = (n < n1) ? n : (n1 - 1);                   \
            rv[u] = *reinterpret_cast<const unsigned int*>(                       \
                v16 + (long)n * 256 + h * 64 + v_dp[u]);                          \
        }                                                                         \
    } while (0)

    K2_LOAD(n0);

    for (int tt = 0; tt < ntile; ++tt) {
        const int nb = n0 + tt * 64;
        __syncthreads();
#pragma unroll
        for (int u = 0; u < 8; ++u) {
            if (u < 7 || t < 128) {
                bool ok = (nb + ar_r[u] < n1);
                kpL[ar_r[u] * 33 + ar_m[u]] =
                    ok ? RATIO * (__expf(ra[u] - MX) + NEPS) : 0.f;
            }
        }
#pragma unroll
        for (int u = 0; u < 3; ++u) {
            if (u < 2 || t < 128) {
                bool ok = (nb + gu_n[u] < n1);
                geT[gu_k[u] * 72 + gu_n[u]] = ok ? __expf(rg[u] * itau) : 0.f;
            }
        }
#pragma unroll
        for (int u = 0; u < 8; ++u) {
            bool ok = (nb + v_n[u] < n1);
            unsigned int uu = ok ? rv[u] : 0u;
            Vt[v_dp[u] * 72 + v_n[u]] = (unsigned short)(uu & 0xffffu);
            Vt[(v_dp[u] + 1) * 72 + v_n[u]] = (unsigned short)(uu >> 16);
        }
        __syncthreads();
        if (tt + 1 < ntile) K2_LOAD(nb + 64);

#pragma unroll
        for (int nh = 0; nh < 2; ++nh) {
            const int nbase = nh * 32 + l4 * 8;
            short8 b[5];
#pragma unroll
            for (int dt = 0; dt < 5; ++dt)
                b[dt] = *reinterpret_cast<const short8*>(&Vt[(dt * 16 + l15) * 72 + nbase]);
#pragma unroll
            for (int q = 0; q < 5; ++q) {
                float4 g0 = *reinterpret_cast<const float4*>(&geT[kq[q] * 72 + nbase]);
                float4 g1 = *reinterpret_cast<const float4*>(&geT[kq[q] * 72 + nbase + 4]);
                const float gg[8] = {g0.x, g0.y, g0.z, g0.w, g1.x, g1.y, g1.z, g1.w};
                short8 a;
#pragma unroll
                for (int j = 0; j < 8; ++j) {
                    float kp = kpL[(nbase + j) * 33 + mq[q]];
                    a[j] = (short)f2bf(kp * gg[j]);
                }
#pragma unroll
                for (int dt = 0; dt < 5; ++dt)
                    acc[q][dt] = __builtin_amdgcn_mfma_f32_16x16x32_bf16(a, b[dt], acc[q][dt], 0, 0, 0);
            }
        }
    }
#undef K2_LOAD

    if (mode) {
        float* slab = part + (long)blockIdx.x * 19520;
#pragma unroll
        for (int q = 0; q < 5; ++q) {
            const int kmb = (wave * 5 + q) * 16 + l4 * 4;
#pragma unroll
            for (int r = 0; r < 4; ++r) {
                const int km = kmb + r;
                if (km < 300) {
#pragma unroll
                    for (int dt = 0; dt < 4; ++dt)
                        slab[km * 64 + dt * 16 + l15] = acc[q][dt][r];
                    if (l15 == 0) slab[19200 + km] = acc[q][4][r];
                }
            }
        }
    } else {
        float* kvh = kvs + h * 19200;
#pragma unroll
        for (int q = 0; q < 5; ++q) {
            const int kmb = (wave * 5 + q) * 16 + l4 * 4;
#pragma unroll
            for (int r = 0; r < 4; ++r) {
                const int km = kmb + r;
                if (km < 300) {
#pragma unroll
                    for (int dt = 0; dt < 4; ++dt)
                        atomicAdd(&kvh[km * 64 + dt * 16 + l15], acc[q][dt][r]);
                    if (l15 == 0)
                        atomicAdd(&kssum[h * 300 + km], acc[q][4][r]);
                }
            }
        }
    }
}

// ---- k2r: reduce 128 chunk-slabs per head -> kvs, kssum ----
__global__ __launch_bounds__(256) void k2r_reduce(
    const float* __restrict__ part, float* __restrict__ kvs, float* __restrict__ kssum)
{
    const int o = blockIdx.x * 256 + threadIdx.x;
    if (o >= 4 * 19504) return;
    const int h = o / 19504, e = o % 19504;
    const float* p = part + (long)h * 128 * 19520 + e;
    float s = 0.f;
#pragma unroll 8
    for (int c = 0; c < 128; ++c) s += p[(long)c * 19520];
    if (e < 19200) kvs[h * 19200 + e] = s;
    else if (e - 19200 < 300) kssum[h * 300 + (e - 19200)] = s;
}

// ---- k2b: split kvs into fragment-ordered hi/lo bf16 (unchanged) ----
__global__ __launch_bounds__(256) void k2b_frag(
    const float* __restrict__ kvs,
    unsigned short* __restrict__ Bfh, unsigned short* __restrict__ Bfl)
{
    const int slot = blockIdx.x * 256 + threadIdx.x;
    if (slot >= 10240) return;
    const int h = slot / 2560;
    const int rem = slot % 2560;
    const int ct = rem >> 6, lane = rem & 63;
    const int col = ct * 16 + (lane & 15);
    const int k = col >> 6, d = col & 63;
    const int mb = (lane >> 4) * 8;
    const float* src = kvs + h * 19200 + (k * 30 + mb) * 64 + d;
    short8 hi8, lo8;
#pragma unroll
    for (int j = 0; j < 8; ++j) {
        float v = (mb + j < 30) ? src[j * 64] : 0.f;
        unsigned short hh, ll; split2(v, hh, ll);
        hi8[j] = (short)hh; lo8[j] = (short)ll;
    }
    *reinterpret_cast<short8*>(&Bfh[(long)slot * 8]) = hi8;
    *reinterpret_cast<short8*>(&Bfl[(long)slot * 8]) = lo8;
}

// ---- k3: unchanged from round 12 ----
__global__ __launch_bounds__(512) void k3_out(
    const __hip_bfloat16* __restrict__ qp16,
    const unsigned short* __restrict__ Bfh, const unsigned short* __restrict__ Bfl,
    const float* __restrict__ kssum,
    const unsigned short* __restrict__ Wofh, const unsigned short* __restrict__ Wofl,
    const float* __restrict__ bo, float* __restrict__ out, int N)
{
    __shared__ alignas(16) unsigned short qpall[32 * 136];
    __shared__ float ksall[1200];
    __shared__ float idla[4 * 320];
    __shared__ alignas(16) float part[2][32][68];
    __shared__ alignas(16) float zl[32 * 260];

    const int t = threadIdx.x;
    const int n0 = blockIdx.x * 32;
    const int wave = t >> 6, lane = t & 63;
    const int g = wave & 3, khalf = wave >> 2;
    const int l15 = lane & 15, l4 = lane >> 4;

    for (int i = t; i < 1200; i += 512) ksall[i] = kssum[i];
    for (int i = t; i < 32 * 60; i += 512) {
        int rr = i / 60, dw = i % 60;
        int n = n0 + rr; if (n >= N) n = N - 1;
        unsigned int u = *reinterpret_cast<const unsigned int*>(
            (const unsigned short*)qp16 + (long)n * 120 + dw * 2);
        int h = dw / 15, md = (dw % 15) * 2;
        qpall[rr * 136 + h * 32 + md] = (unsigned short)(u & 0xffffu);
        qpall[rr * 136 + h * 32 + md + 1] = (unsigned short)(u >> 16);
    }
    __syncthreads();

    for (int i = t; i < 1280; i += 512) {
        int h = i / 320, rem = i % 320;
        int rr = rem / 10, kk = rem % 10;
        const unsigned short* qr = &qpall[rr * 136 + h * 32];
        const float* kr = &ksall[h * 300 + kk * 30];
        float s = 0.f;
#pragma unroll
        for (int m = 0; m < 30; ++m) s += bf2f(qr[m]) * kr[m];
        idla[i] = 1.0f / s;
    }
    __syncthreads();

    for (int h = 0; h < 4; ++h) {
        short8 bh[5], bl[5];
#pragma unroll
        for (int q = 0; q < 5; ++q) {
            const int ct = (khalf * 5 + q) * 4 + g;
            const long off = ((long)(h * 40 + ct) * 64 + lane) * 8;
            bh[q] = *reinterpret_cast<const short8*>(Bfh + off);
            bl[q] = *reinterpret_cast<const short8*>(Bfl + off);
        }
        short8 aQ[2];
#pragma unroll
        for (int rt = 0; rt < 2; ++rt) {
            const unsigned int* qrow = reinterpret_cast<const unsigned int*>(
                &qpall[(rt * 16 + l15) * 136 + h * 32 + l4 * 8]);
            short8 a;
#pragma unroll
            for (int jj = 0; jj < 4; ++jj) {
                unsigned int u = qrow[jj];
                a[jj * 2] = (short)(u & 0xffffu);
                a[jj * 2 + 1] = (short)(u >> 16);
            }
            if (l4 == 3) { a[6] = 0; a[7] = 0; }
            aQ[rt] = a;
        }
        floatx4 acc[2][5];
#pragma unroll
        for (int rt = 0; rt < 2; ++rt)
#pragma unroll
            for (int q = 0; q < 5; ++q) acc[rt][q] = floatx4{0.f, 0.f, 0.f, 0.f};
#pragma unroll
        for (int q = 0; q < 5; ++q) {
            acc[0][q] = __builtin_amdgcn_mfma_f32_16x16x32_bf16(aQ[0], bh[q], acc[0][q], 0, 0, 0);
            acc[0][q] = __builtin_amdgcn_mfma_f32_16x16x32_bf16(aQ[0], bl[q], acc[0][q], 0, 0, 0);
            acc[1][q] = __builtin_amdgcn_mfma_f32_16x16x32_bf16(aQ[1], bh[q], acc[1][q], 0, 0, 0);
            acc[1][q] = __builtin_amdgcn_mfma_f32_16x16x32_bf16(aQ[1], bl[q], acc[1][q], 0, 0, 0);
        }
#pragma unroll
        for (int rt = 0; rt < 2; ++rt)
#pragma unroll
            for (int r = 0; r < 4; ++r) {
                const int row = rt * 16 + l4 * 4 + r;
                float s = 0.f;
#pragma unroll
                for (int q = 0; q < 5; ++q)
                    s += acc[rt][q][r] * idla[h * 320 + row * 10 + khalf * 5 + q];
                part[khalf][row][g * 16 + l15] = s;
            }
        __syncthreads();
        {
            const int row = t >> 4, d4 = t & 15;
            float4 p0 = *reinterpret_cast<const float4*>(&part[0][row][d4 * 4]);
            float4 p1 = *reinterpret_cast<const float4*>(&part[1][row][d4 * 4]);
            float4 zv;
            zv.x = 0.1f * (p0.x + p1.x); zv.y = 0.1f * (p0.y + p1.y);
            zv.z = 0.1f * (p0.z + p1.z); zv.w = 0.1f * (p0.w + p1.w);
            reinterpret_cast<float4*>(zl)[row * 65 + h * 16 + d4] = zv;
        }
        __syncthreads();
    }
    {
        const int rt = wave >> 2, ct = wave & 3;
        floatx4 o = floatx4{0.f, 0.f, 0.f, 0.f};
#pragma unroll
        for (int ks = 0; ks < 8; ++ks) {
            const float* zr = &zl[(rt * 16 + l15) * 260 + ks * 32 + l4 * 8];
            float4 x0 = *reinterpret_cast<const float4*>(zr);
            float4 x1 = *reinterpret_cast<const float4*>(zr + 4);
            float xv[8] = {x0.x, x0.y, x0.z, x0.w, x1.x, x1.y, x1.z, x1.w};
            short8 ah, al;
#pragma unroll
            for (int j = 0; j < 8; ++j) {
                unsigned short hi, lo; split2(xv[j], hi, lo);
                ah[j] = (short)hi; al[j] = (short)lo;
            }
            const int slot = ct * 8 + ks;
            short8 wbh = *reinterpret_cast<const short8*>(&Wofh[slot * 512 + lane * 8]);
            short8 wbl = *reinterpret_cast<const short8*>(&Wofl[slot * 512 + lane * 8]);
            o = __builtin_amdgcn_mfma_f32_16x16x32_bf16(ah, wbh, o, 0, 0, 0);
            o = __builtin_amdgcn_mfma_f32_16x16x32_bf16(ah, wbl, o, 0, 0, 0);
            o = __builtin_amdgcn_mfma_f32_16x16x32_bf16(al, wbh, o, 0, 0, 0);
        }
        const int col = ct * 16 + l15;
        const float bb = bo[col];
#pragma unroll
        for (int r = 0; r < 4; ++r) {
            const int n = n0 + rt * 16 + l4 * 4 + r;
            if (n < N) out[(long)n * 64 + col] = o[r] + bb;
        }
    }
}

extern "C" void kernel_launch(void* const* d_in, const int* in_sizes, int n_in,
                              void* d_out, int out_size, void* d_ws, size_t ws_size,
                              hipStream_t stream)
{
    const float* z    = (const float*)d_in[0];
    const float* Wq   = (const float*)d_in[1];
    const float* bq   = (const float*)d_in[2];
    const float* Wk   = (const float*)d_in[3];
    const float* bk   = (const float*)d_in[4];
    const float* Wv   = (const float*)d_in[5];
    const float* bv   = (const float*)d_in[6];
    const float* Wo   = (const float*)d_in[7];
    const float* bo   = (const float*)d_in[8];
    const float* proj = (const float*)d_in[9];
    const float* gum  = (const float*)d_in[10];
    const float* tau  = (const float*)d_in[11];
    float* out = (float*)d_out;

    const int N = in_sizes[0] / 64;          // 50000
    const int ntiles = (N + 15) / 16;        // 3125
    const int nchunk = (N + 127) / 128;      // 391
    const int nblk3  = (N + 31) / 32;        // 1563

    char* wsb = (char*)d_ws;
    size_t off = 0;
    __hip_bfloat16* qp16 = (__hip_bfloat16*)(wsb);
    off += ((size_t)N * 120 * 2 + 255) & ~(size_t)255;
    __hip_bfloat16* v16 = (__hip_bfloat16*)(wsb + off);
    off += ((size_t)N * 256 * 2 + 255) & ~(size_t)255;
    float* argk = (float*)(wsb + off);
    off += ((size_t)N * 120 * 4 + 255) & ~(size_t)255;
    float* kvs      = (float*)(wsb + off);
    float* kssum    = kvs + 76800;
    float* headmax  = kssum + 1200;
    float* blockmax = headmax + 4;
    off += ((size_t)(76800 + 1200 + 4 + (size_t)ntiles * 4) * 4 + 255) & ~(size_t)255;
    unsigned short* Wfh = (unsigned short*)(wsb + off); off += 49152 * 2;
    unsigned short* Wfl = (unsigned short*)(wsb + off); off += 49152 * 2;
    unsigned short* Pfh = (unsigned short*)(wsb + off); off += 2048 * 2;
    unsigned short* Pfl = (unsigned short*)(wsb + off); off += 2048 * 2;
    unsigned short* Wofh = (unsigned short*)(wsb + off); off += 16384 * 2;
    unsigned short* Wofl = (unsigned short*)(wsb + off); off += 16384 * 2;
    unsigned short* Bfh  = (unsigned short*)(wsb + off); off += 81920 * 2;
    unsigned short* Bfl  = (unsigned short*)(wsb + off); off += 81920 * 2;
    off = (off + 255) & ~(size_t)255;
    float* part = (float*)(wsb + off);
    const size_t part_bytes = (size_t)512 * 19520 * 4;
    const int mode = (ws_size >= off + part_bytes) ? 1 : 0;   // two-stage if ws fits

    k_prep<<<dim3(26), dim3(256), 0, stream>>>(Wq, Wk, Wv, proj, Wo,
                                               Wfh, Wfl, Pfh, Pfl, Wofh, Wofl);
    if (!mode)
        k0_zero<<<dim3((78000 + 255) / 256), dim3(256), 0, stream>>>(kvs, 78000);
    k1_feat<<<dim3(ntiles), dim3(256), 0, stream>>>(z, bq, bk, bv, Wfh, Wfl, Pfh, Pfl, tau,
                                                    qp16, v16, argk, blockmax, N);
    k1b_redmax<<<dim3(1), dim3(256), 0, stream>>>(blockmax, headmax, ntiles);
    k2_kvs<<<dim3(512), dim3(256), 0, stream>>>(argk, gum, v16, tau, headmax,
                                                kvs, kssum, part, mode, N, nchunk);
    if (mode)
        k2r_reduce<<<dim3((4 * 19504 + 255) / 256), dim3(256), 0, stream>>>(part, kvs, kssum);
    k2b_frag<<<dim3(40), dim3(256), 0, stream>>>(kvs, Bfh, Bfl);
    k3_out<<<dim3(nblk3), dim3(512), 0, stream>>>(qp16, Bfh, Bfl, kssum,
                                                  Wofh, Wofl, bo, out, N);
}

// Round 14
// 188.222 us; speedup vs baseline: 37.1552x; 1.0497x over previous
//
#include <hip/hip_runtime.h>
#include <hip/hip_bf16.h>

// NodeFormerConv: Performer/Gumbel attention. fp32-equivalent math, fp32 output.
//   k_prep: split Wq|Wk|Wv, proj, Wo into MFMA-fragment-ordered hi/lo bf16
//   (k0   zero kvs/kssum — only in atomic-fallback mode)
//   k1   per 16-row tile, MFMA: QKV gemm -> qd/kd LDS + v16; phi gemm; diag,
//        rowmax, exp in-register; stores qp16 (bf16) and p16 = bf16(exp(dd-diag-bmx))
//   k1b  blockmax -> headmax[4]
//   k2   MFMA accumulate; kp = RATIO*(p16*scaleAll[tile] + NEPS) (no per-elem exp);
//        batched+prefetched staging; flush -> private slab (or atomics fallback)
//   k2r  (mode 1) reduce 128 chunk-slabs -> kssum + fragment-ordered Bfh/Bfl direct
//   k2b  (mode 0 only) split kvs into fragments
//   k3   per 32-row block: den up front; B-frags from global, NUM MFMA,
//        in-register idl scale, part exchange -> zl; out = zl@Wo + bo (f32)

#define NEPS  1e-6f
#define RATIO 0.18257418583505536f   // 1/sqrt(30)
#define DNORM 0.35355339059327378f   // 64^-0.25

typedef __attribute__((ext_vector_type(8))) short short8;
typedef __attribute__((ext_vector_type(4))) float floatx4;

__device__ inline unsigned short f2bf(float x) {
    __hip_bfloat16 b = __float2bfloat16(x);
    return __builtin_bit_cast(unsigned short, b);
}
__device__ inline float bf2f(unsigned short h) {
    return __builtin_bit_cast(float, (unsigned int)h << 16);
}
__device__ inline void split2(float v, unsigned short& hi, unsigned short& lo) {
    unsigned short h = f2bf(v);
    hi = h; lo = f2bf(v - bf2f(h));
}

__global__ __launch_bounds__(256) void k0_zero(float* __restrict__ p, int count) {
    int id = blockIdx.x * 256 + threadIdx.x;
    if (id < count) p[id] = 0.f;
}

// ---- k_prep: fragment-ordered hi/lo splits (unchanged) ----
__global__ __launch_bounds__(256) void k_prep(
    const float* __restrict__ Wq, const float* __restrict__ Wk, const float* __restrict__ Wv,
    const float* __restrict__ proj, const float* __restrict__ Wo,
    unsigned short* __restrict__ Wfh, unsigned short* __restrict__ Wfl,
    unsigned short* __restrict__ Pfh, unsigned short* __restrict__ Pfl,
    unsigned short* __restrict__ Wofh, unsigned short* __restrict__ Wofl)
{
    const int b = blockIdx.x, t = threadIdx.x;
    if (b < 24) {
        const int slot = b * 256 + t;
        const int lane = slot & 63;
        const int ctks = slot >> 6;
        const int ct = ctks >> 1, ks = ctks & 1;
        const int col = ct * 16 + (lane & 15);
        const int k0 = ks * 32 + (lane >> 4) * 8;
        const float* W = (col < 256) ? Wq : (col < 512) ? Wk : Wv;
        const int cm = col & 255;
#pragma unroll
        for (int j = 0; j < 8; ++j) {
            float w = W[(k0 + j) * 256 + cm];
            unsigned short hi, lo; split2(w, hi, lo);
            Wfh[slot * 8 + j] = hi;
            Wfl[slot * 8 + j] = lo;
        }
    } else if (b == 24) {
        const int lane = t & 63;
        const int ctks = t >> 6;
        const int ct2 = ctks >> 1, ks = ctks & 1;
        const int m = ct2 * 16 + (lane & 15);
        const int k0 = ks * 32 + (lane >> 4) * 8;
#pragma unroll
        for (int j = 0; j < 8; ++j) {
            float p = (m < 30) ? proj[m * 64 + k0 + j] : 0.f;
            unsigned short hi, lo; split2(p, hi, lo);
            Pfh[t * 8 + j] = hi;
            Pfl[t * 8 + j] = lo;
        }
    } else {
        for (int idx = t; idx < 2048; idx += 256) {
            const int slot = idx >> 6, l = idx & 63;
            const int ct = slot >> 3, ks = slot & 7;
            const int col = ct * 16 + (l & 15);
            const int k0 = ks * 32 + (l >> 4) * 8;
#pragma unroll
            for (int j = 0; j < 8; ++j) {
                float w = Wo[(k0 + j) * 64 + col];
                unsigned short hi, lo; split2(w, hi, lo);
                Wofh[slot * 512 + l * 8 + j] = hi;
                Wofl[slot * 512 + l * 8 + j] = lo;
            }
        }
    }
}

// ---- k1: per 16-row tile, MFMA QKV + phi; fully in-register epilogue ----
__global__ __launch_bounds__(256) void k1_feat(
    const float* __restrict__ z,
    const float* __restrict__ bq, const float* __restrict__ bk, const float* __restrict__ bv,
    const unsigned short* __restrict__ Wfh, const unsigned short* __restrict__ Wfl,
    const unsigned short* __restrict__ Pfh, const unsigned short* __restrict__ Pfl,
    const float* __restrict__ tau,
    __hip_bfloat16* __restrict__ qp16, __hip_bfloat16* __restrict__ v16,
    __hip_bfloat16* __restrict__ p16, float* __restrict__ blockmax, int N)
{
    __shared__ alignas(16) unsigned short zh[16 * 72];
    __shared__ alignas(16) unsigned short zl_[16 * 72];
    __shared__ alignas(16) float qd[16 * 268];
    __shared__ alignas(16) float kd[16 * 268];

    const int t = threadIdx.x;
    const int n0 = blockIdx.x * 16;
    const int wave = t >> 6, lane = t & 63;
    const int l15 = lane & 15, l4 = lane >> 4;
    const float dsc = rsqrtf(tau[0]) * DNORM;

    for (int i = t; i < 1024; i += 256) {
        int r = i >> 6, c = i & 63;
        float v = (n0 + r < N) ? z[(long)(n0 + r) * 64 + c] : 0.f;
        unsigned short hi, lo; split2(v, hi, lo);
        zh[r * 72 + c] = hi;
        zl_[r * 72 + c] = lo;
    }
    __syncthreads();

    {
        const int abase = l15 * 72 + l4 * 8;
        short8 ah0 = *reinterpret_cast<const short8*>(&zh[abase]);
        short8 ah1 = *reinterpret_cast<const short8*>(&zh[abase + 32]);
        short8 al0 = *reinterpret_cast<const short8*>(&zl_[abase]);
        short8 al1 = *reinterpret_cast<const short8*>(&zl_[abase + 32]);
        const int row0 = l4 * 4;
#pragma unroll 2
        for (int ci = 0; ci < 12; ++ci) {
            const int ct = wave * 12 + ci;
            short8 bh0 = *reinterpret_cast<const short8*>(&Wfh[(ct * 2 + 0) * 512 + lane * 8]);
            short8 bh1 = *reinterpret_cast<const short8*>(&Wfh[(ct * 2 + 1) * 512 + lane * 8]);
            short8 bl0 = *reinterpret_cast<const short8*>(&Wfl[(ct * 2 + 0) * 512 + lane * 8]);
            short8 bl1 = *reinterpret_cast<const short8*>(&Wfl[(ct * 2 + 1) * 512 + lane * 8]);
            floatx4 acc = floatx4{0.f, 0.f, 0.f, 0.f};
            acc = __builtin_amdgcn_mfma_f32_16x16x32_bf16(ah0, bh0, acc, 0, 0, 0);
            acc = __builtin_amdgcn_mfma_f32_16x16x32_bf16(ah1, bh1, acc, 0, 0, 0);
            acc = __builtin_amdgcn_mfma_f32_16x16x32_bf16(ah0, bl0, acc, 0, 0, 0);
            acc = __builtin_amdgcn_mfma_f32_16x16x32_bf16(ah1, bl1, acc, 0, 0, 0);
            acc = __builtin_amdgcn_mfma_f32_16x16x32_bf16(al0, bh0, acc, 0, 0, 0);
            acc = __builtin_amdgcn_mfma_f32_16x16x32_bf16(al1, bh1, acc, 0, 0, 0);
            const int c = ct * 16 + l15;
            if (c < 256) {
                const float bb = bq[c];
#pragma unroll
                for (int r = 0; r < 4; ++r) qd[(row0 + r) * 268 + c] = (acc[r] + bb) * dsc;
            } else if (c < 512) {
                const float bb = bk[c - 256];
#pragma unroll
                for (int r = 0; r < 4; ++r) kd[(row0 + r) * 268 + (c - 256)] = (acc[r] + bb) * dsc;
            } else {
                const float bb = bv[c - 512];
#pragma unroll
                for (int r = 0; r < 4; ++r)
                    if (n0 + row0 + r < N)
                        v16[(long)(n0 + row0 + r) * 256 + (c - 512)] = __float2bfloat16(acc[r] + bb);
            }
        }
    }
    __syncthreads();

    // P2: phi MFMA (wave w: head w) + diag/rowmax/exp/store fully in-register
    {
        short8 pbh[2][2], pbl[2][2];
#pragma unroll
        for (int ct2 = 0; ct2 < 2; ++ct2)
#pragma unroll
            for (int ks = 0; ks < 2; ++ks) {
                pbh[ct2][ks] = *reinterpret_cast<const short8*>(&Pfh[(ct2 * 2 + ks) * 512 + lane * 8]);
                pbl[ct2][ks] = *reinterpret_cast<const short8*>(&Pfl[(ct2 * 2 + ks) * 512 + lane * 8]);
            }
        const int h = wave;
        const int row0 = l4 * 4;
#pragma unroll
        for (int side = 0; side < 2; ++side) {
            const float* dat = side ? kd : qd;
            const int rbase = l15 * 268 + h * 64 + l4 * 8;
            float xv[8], yv[8];
            {
                float4 x0 = *reinterpret_cast<const float4*>(&dat[rbase]);
                float4 x1 = *reinterpret_cast<const float4*>(&dat[rbase + 4]);
                float4 y0 = *reinterpret_cast<const float4*>(&dat[rbase + 32]);
                float4 y1 = *reinterpret_cast<const float4*>(&dat[rbase + 36]);
                xv[0]=x0.x; xv[1]=x0.y; xv[2]=x0.z; xv[3]=x0.w;
                xv[4]=x1.x; xv[5]=x1.y; xv[6]=x1.z; xv[7]=x1.w;
                yv[0]=y0.x; yv[1]=y0.y; yv[2]=y0.z; yv[3]=y0.w;
                yv[4]=y1.x; yv[5]=y1.y; yv[6]=y1.z; yv[7]=y1.w;
            }
            float diag;
            {
                float s = 0.f;
#pragma unroll
                for (int j = 0; j < 8; ++j) s += xv[j] * xv[j] + yv[j] * yv[j];
                s += __shfl_xor(s, 16);
                s += __shfl_xor(s, 32);
                diag = 0.5f * s;
            }
            short8 ah0, al0, ah1, al1;
#pragma unroll
            for (int j = 0; j < 8; ++j) {
                unsigned short hi, lo;
                split2(xv[j], hi, lo); ah0[j] = (short)hi; al0[j] = (short)lo;
                split2(yv[j], hi, lo); ah1[j] = (short)hi; al1[j] = (short)lo;
            }
            floatx4 acc2[2];
#pragma unroll
            for (int ct2 = 0; ct2 < 2; ++ct2) {
                floatx4 acc = floatx4{0.f, 0.f, 0.f, 0.f};
                acc = __builtin_amdgcn_mfma_f32_16x16x32_bf16(ah0, pbh[ct2][0], acc, 0, 0, 0);
                acc = __builtin_amdgcn_mfma_f32_16x16x32_bf16(ah1, pbh[ct2][1], acc, 0, 0, 0);
                acc = __builtin_amdgcn_mfma_f32_16x16x32_bf16(ah0, pbl[ct2][0], acc, 0, 0, 0);
                acc = __builtin_amdgcn_mfma_f32_16x16x32_bf16(ah1, pbl[ct2][1], acc, 0, 0, 0);
                acc = __builtin_amdgcn_mfma_f32_16x16x32_bf16(al0, pbh[ct2][0], acc, 0, 0, 0);
                acc = __builtin_amdgcn_mfma_f32_16x16x32_bf16(al1, pbh[ct2][1], acc, 0, 0, 0);
                acc2[ct2] = acc;
            }
            float vmax[4];
#pragma unroll
            for (int r = 0; r < 4; ++r) {
                float a1 = (l15 >= 14) ? -3.4e38f : acc2[1][r];
                float v = fmaxf(acc2[0][r], a1);
                v = fmaxf(v, __shfl_xor(v, 1));
                v = fmaxf(v, __shfl_xor(v, 2));
                v = fmaxf(v, __shfl_xor(v, 4));
                v = fmaxf(v, __shfl_xor(v, 8));
                vmax[r] = v;
            }
            if (side == 0) {
#pragma unroll
                for (int ct2 = 0; ct2 < 2; ++ct2) {
                    const int m = ct2 * 16 + l15;
                    if (m < 30) {
#pragma unroll
                        for (int r = 0; r < 4; ++r) {
                            const int n = n0 + row0 + r;
                            if (n < N) {
                                float val = RATIO * (__expf(acc2[ct2][r] - diag - vmax[r]) + NEPS);
                                ((unsigned short*)qp16)[(long)n * 120 + h * 30 + m] = f2bf(val);
                            }
                        }
                    }
                }
            } else {
                // tile-max over valid rows -> all lanes
                float mv = -3.4e38f;
#pragma unroll
                for (int r = 0; r < 4; ++r)
                    if (n0 + row0 + r < N) mv = fmaxf(mv, vmax[r]);
                mv = fmaxf(mv, __shfl_xor(mv, 16));
                mv = fmaxf(mv, __shfl_xor(mv, 32));
                if (lane == 0) blockmax[blockIdx.x * 4 + h] = mv;
#pragma unroll
                for (int ct2 = 0; ct2 < 2; ++ct2) {
                    const int m = ct2 * 16 + l15;
                    if (m < 30) {
#pragma unroll
                        for (int r = 0; r < 4; ++r) {
                            const int n = n0 + row0 + r;
                            if (n < N)
                                ((unsigned short*)p16)[(long)n * 120 + h * 30 + m] =
                                    f2bf(__expf(acc2[ct2][r] - diag - mv));
                        }
                    }
                }
            }
        }
    }
}

__global__ __launch_bounds__(256) void k1b_redmax(
    const float* __restrict__ blockmax, float* __restrict__ headmax, int ntiles)
{
    __shared__ float red[4 * 256];
    const int t = threadIdx.x;
    float lm[4] = {-3.4e38f, -3.4e38f, -3.4e38f, -3.4e38f};
    for (int i = t; i < ntiles; i += 256) {
#pragma unroll
        for (int hh = 0; hh < 4; ++hh) lm[hh] = fmaxf(lm[hh], blockmax[i * 4 + hh]);
    }
#pragma unroll
    for (int hh = 0; hh < 4; ++hh) red[hh * 256 + t] = lm[hh];
    __syncthreads();
    if (t < 4) {
        float mx = red[t * 256];
        for (int i = 1; i < 256; ++i) mx = fmaxf(mx, red[t * 256 + i]);
        headmax[t] = mx;
    }
}

// ---- k2: MFMA accumulate; kp from p16*scale; flush slab (mode 1) or atomics ----
__global__ __launch_bounds__(256) void k2_kvs(
    const __hip_bfloat16* __restrict__ p16, const float* __restrict__ gum,
    const __hip_bfloat16* __restrict__ v16, const float* __restrict__ tau,
    const float* __restrict__ headmax, const float* __restrict__ blockmax,
    float* __restrict__ kvs, float* __restrict__ kssum,
    float* __restrict__ part, int mode, int N, int nchunk)
{
    __shared__ alignas(16) unsigned short Vt[80 * 72];
    __shared__ float kpL[64 * 33];
    __shared__ alignas(16) float geT[13 * 72];
    __shared__ float scaleAll[32];

    const int t = threadIdx.x;
    const int h = blockIdx.x >> 7;
    const int chunk = blockIdx.x & 127;
    const int n0 = chunk * nchunk;
    const int n1 = (n0 + nchunk < N) ? (n0 + nchunk) : N;
    const float MX = headmax[h];
    const float itau = 1.0f / tau[0];
    const int wave = t >> 6, lane = t & 63;
    const int l15 = lane & 15, l4 = lane >> 4;
    const int tb0 = n0 >> 4;

    // per-thread staging coords: p16 pairs (960 uints), gum, v16
    int pr_r[4], pr_m[4]; bool pvld[4];
#pragma unroll
    for (int u = 0; u < 4; ++u) {
        int i = t + 256 * u;
        pvld[u] = (i < 960);
        int ii = pvld[u] ? i : 959;
        pr_r[u] = (2 * ii) / 30;
        pr_m[u] = (2 * ii) % 30;
    }
    int gu_k[3], gu_n[3];
#pragma unroll
    for (int u = 0; u < 3; ++u) { int i = t + 256 * u; gu_k[u] = i >> 6; gu_n[u] = i & 63; }
    int v_n[8], v_dp[8];
#pragma unroll
    for (int u = 0; u < 8; ++u) { int i = t + 256 * u; v_n[u] = i >> 5; v_dp[u] = (i & 31) * 2; }

    unsigned int rp[4], rv[8];
    float rg[3];

    floatx4 acc[5][5];
#pragma unroll
    for (int q = 0; q < 5; ++q)
#pragma unroll
        for (int dt = 0; dt < 5; ++dt) acc[q][dt] = floatx4{0.f, 0.f, 0.f, 0.f};

    int mq[5], kq[5];
#pragma unroll
    for (int q = 0; q < 5; ++q) {
        int row = (wave * 5 + q) * 16 + l15;
        mq[q] = row % 30;
        kq[q] = row / 30;
    }

    if (t < 64) Vt[64 * 72 + t] = f2bf(1.0f);
    for (int i = t; i < 15 * 72; i += 256) Vt[65 * 72 + i] = 0;
    for (int i = t; i < 3 * 72; i += 256) geT[10 * 72 + i] = 0.f;
    if (t < 32) {                       // tile scales for this chunk (<=27 used)
        int tid = tb0 + t;
        int maxtid = (N - 1) >> 4;
        if (tid > maxtid) tid = maxtid;
        scaleAll[t] = __expf(blockmax[tid * 4 + h] - MX);
    }

    const int ntile = (n1 - n0 + 63) >> 6;

#define K2_LOAD(nb_)                                                              \
    do {                                                                          \
        _Pragma("unroll")                                                         \
        for (int u = 0; u < 4; ++u) {                                             \
            int n = (nb_) + pr_r[u]; n = (n < n1) ? n : (n1 - 1);                  \
            rp[u] = *reinterpret_cast<const unsigned int*>(                       \
                (const unsigned short*)p16 + (long)n * 120 + h * 30 + pr_m[u]);   \
        }                                                                         \
        _Pragma("unroll")                                                         \
        for (int u = 0; u < 3; ++u) {                                             \
            int n = (nb_) + gu_n[u]; n = (n < n1) ? n : (n1 - 1);                  \
            rg[u] = gum[(long)n * 40 + h * 10 + gu_k[u]];                         \
        }                                                                         \
        _Pragma("unroll")                                                         \
        for (int u = 0; u < 8; ++u) {                                             \
            int n = (nb_) + v_n[u]; n = (n < n1) ? n : (n1 - 1);                   \
            rv[u] = *reinterpret_cast<const unsigned int*>(                       \
                v16 + (long)n * 256 + h * 64 + v_dp[u]);                          \
        }                                                                         \
    } while (0)

    K2_LOAD(n0);

    for (int tt = 0; tt < ntile; ++tt) {
        const int nb = n0 + tt * 64;
        __syncthreads();                               // B0: prev reads + scaleAll ready
#pragma unroll
        for (int u = 0; u < 4; ++u) {
            if (pvld[u]) {
                bool ok = (nb + pr_r[u] < n1);
                float sc = scaleAll[((nb + pr_r[u]) >> 4) - tb0];
                float plo = bf2f((unsigned short)(rp[u] & 0xffffu));
                float phi = bf2f((unsigned short)(rp[u] >> 16));
                kpL[pr_r[u] * 33 + pr_m[u]]     = ok ? RATIO * (plo * sc + NEPS) : 0.f;
                kpL[pr_r[u] * 33 + pr_m[u] + 1] = ok ? RATIO * (phi * sc + NEPS) : 0.f;
            }
        }
#pragma unroll
        for (int u = 0; u < 3; ++u) {
            if (u < 2 || t < 128) {
                bool ok = (nb + gu_n[u] < n1);
                geT[gu_k[u] * 72 + gu_n[u]] = ok ? __expf(rg[u] * itau) : 0.f;
            }
        }
#pragma unroll
        for (int u = 0; u < 8; ++u) {
            bool ok = (nb + v_n[u] < n1);
            unsigned int uu = ok ? rv[u] : 0u;
            Vt[v_dp[u] * 72 + v_n[u]] = (unsigned short)(uu & 0xffffu);
            Vt[(v_dp[u] + 1) * 72 + v_n[u]] = (unsigned short)(uu >> 16);
        }
        __syncthreads();                               // B1: staging visible
        if (tt + 1 < ntile) K2_LOAD(nb + 64);

#pragma unroll
        for (int nh = 0; nh < 2; ++nh) {
            const int nbase = nh * 32 + l4 * 8;
            short8 b[5];
#pragma unroll
            for (int dt = 0; dt < 5; ++dt)
                b[dt] = *reinterpret_cast<const short8*>(&Vt[(dt * 16 + l15) * 72 + nbase]);
#pragma unroll
            for (int q = 0; q < 5; ++q) {
                float4 g0 = *reinterpret_cast<const float4*>(&geT[kq[q] * 72 + nbase]);
                float4 g1 = *reinterpret_cast<const float4*>(&geT[kq[q] * 72 + nbase + 4]);
                const float gg[8] = {g0.x, g0.y, g0.z, g0.w, g1.x, g1.y, g1.z, g1.w};
                short8 a;
#pragma unroll
                for (int j = 0; j < 8; ++j) {
                    float kp = kpL[(nbase + j) * 33 + mq[q]];
                    a[j] = (short)f2bf(kp * gg[j]);
                }
#pragma unroll
                for (int dt = 0; dt < 5; ++dt)
                    acc[q][dt] = __builtin_amdgcn_mfma_f32_16x16x32_bf16(a, b[dt], acc[q][dt], 0, 0, 0);
            }
        }
    }
#undef K2_LOAD

    if (mode) {
        float* slab = part + (long)blockIdx.x * 19520;
#pragma unroll
        for (int q = 0; q < 5; ++q) {
            const int kmb = (wave * 5 + q) * 16 + l4 * 4;
#pragma unroll
            for (int r = 0; r < 4; ++r) {
                const int km = kmb + r;
                if (km < 300) {
#pragma unroll
                    for (int dt = 0; dt < 4; ++dt)
                        slab[km * 64 + dt * 16 + l15] = acc[q][dt][r];
                    if (l15 == 0) slab[19200 + km] = acc[q][4][r];
                }
            }
        }
    } else {
        float* kvh = kvs + h * 19200;
#pragma unroll
        for (int q = 0; q < 5; ++q) {
            const int kmb = (wave * 5 + q) * 16 + l4 * 4;
#pragma unroll
            for (int r = 0; r < 4; ++r) {
                const int km = kmb + r;
                if (km < 300) {
#pragma unroll
                    for (int dt = 0; dt < 4; ++dt)
                        atomicAdd(&kvh[km * 64 + dt * 16 + l15], acc[q][dt][r]);
                    if (l15 == 0)
                        atomicAdd(&kssum[h * 300 + km], acc[q][4][r]);
                }
            }
        }
    }
}

// ---- k2r (mode 1): reduce 128 slabs/head -> kssum + Bfh/Bfl direct ----
// blocks 0..304: main; blocks 305..324: zero pad slots (m=30,31)
__global__ __launch_bounds__(256) void k2r_reduce(
    const float* __restrict__ part, float* __restrict__ kssum,
    unsigned short* __restrict__ Bfh, unsigned short* __restrict__ Bfl)
{
    const int b = blockIdx.x, t = threadIdx.x;
    if (b >= 305) {                                    // pad zeroing
        const int p = (b - 305) * 256 + t;             // < 5120
        const int j = 6 + (p & 1);
        const int q2 = p >> 1;
        const int l15 = q2 & 15;
        const int ct = (q2 >> 4) % 40;
        const int h = q2 / 640;
        const long idx = ((long)(h * 40 + ct) * 64 + 48 + l15) * 8 + j;
        Bfh[idx] = 0; Bfl[idx] = 0;
        return;
    }
    const int o = b * 256 + t;
    if (o >= 4 * 19504) return;
    const int h = o / 19504, e = o % 19504;
    const float* p = part + (long)h * 128 * 19520 + e;
    float s = 0.f;
#pragma unroll 8
    for (int c = 0; c < 128; ++c) s += p[(long)c * 19520];
    if (e < 19200) {
        const int km = e >> 6, d = e & 63;
        const int k = km / 30, m = km % 30;
        const int col = k * 64 + d;
        const int ct = col >> 4;
        const int lane = ((m >> 3) << 4) | (d & 15);
        const int j = m & 7;
        const long idx = ((long)(h * 40 + ct) * 64 + lane) * 8 + j;
        unsigned short hi, lo; split2(s, hi, lo);
        Bfh[idx] = hi; Bfl[idx] = lo;
    } else if (e - 19200 < 300) {
        kssum[h * 300 + (e - 19200)] = s;
    }
}

// ---- k2b (mode 0 only): split kvs into fragment-ordered hi/lo bf16 ----
__global__ __launch_bounds__(256) void k2b_frag(
    const float* __restrict__ kvs,
    unsigned short* __restrict__ Bfh, unsigned short* __restrict__ Bfl)
{
    const int slot = blockIdx.x * 256 + threadIdx.x;
    if (slot >= 10240) return;
    const int h = slot / 2560;
    const int rem = slot % 2560;
    const int ct = rem >> 6, lane = rem & 63;
    const int col = ct * 16 + (lane & 15);
    const int k = col >> 6, d = col & 63;
    const int mb = (lane >> 4) * 8;
    const float* src = kvs + h * 19200 + (k * 30 + mb) * 64 + d;
    short8 hi8, lo8;
#pragma unroll
    for (int j = 0; j < 8; ++j) {
        float v = (mb + j < 30) ? src[j * 64] : 0.f;
        unsigned short hh, ll; split2(v, hh, ll);
        hi8[j] = (short)hh; lo8[j] = (short)ll;
    }
    *reinterpret_cast<short8*>(&Bfh[(long)slot * 8]) = hi8;
    *reinterpret_cast<short8*>(&Bfl[(long)slot * 8]) = lo8;
}

// ---- k3: unchanged ----
__global__ __launch_bounds__(512) void k3_out(
    const __hip_bfloat16* __restrict__ qp16,
    const unsigned short* __restrict__ Bfh, const unsigned short* __restrict__ Bfl,
    const float* __restrict__ kssum,
    const unsigned short* __restrict__ Wofh, const unsigned short* __restrict__ Wofl,
    const float* __restrict__ bo, float* __restrict__ out, int N)
{
    __shared__ alignas(16) unsigned short qpall[32 * 136];
    __shared__ float ksall[1200];
    __shared__ float idla[4 * 320];
    __shared__ alignas(16) float part[2][32][68];
    __shared__ alignas(16) float zl[32 * 260];

    const int t = threadIdx.x;
    const int n0 = blockIdx.x * 32;
    const int wave = t >> 6, lane = t & 63;
    const int g = wave & 3, khalf = wave >> 2;
    const int l15 = lane & 15, l4 = lane >> 4;

    for (int i = t; i < 1200; i += 512) ksall[i] = kssum[i];
    for (int i = t; i < 32 * 60; i += 512) {
        int rr = i / 60, dw = i % 60;
        int n = n0 + rr; if (n >= N) n = N - 1;
        unsigned int u = *reinterpret_cast<const unsigned int*>(
            (const unsigned short*)qp16 + (long)n * 120 + dw * 2);
        int h = dw / 15, md = (dw % 15) * 2;
        qpall[rr * 136 + h * 32 + md] = (unsigned short)(u & 0xffffu);
        qpall[rr * 136 + h * 32 + md + 1] = (unsigned short)(u >> 16);
    }
    __syncthreads();

    for (int i = t; i < 1280; i += 512) {
        int h = i / 320, rem = i % 320;
        int rr = rem / 10, kk = rem % 10;
        const unsigned short* qr = &qpall[rr * 136 + h * 32];
        const float* kr = &ksall[h * 300 + kk * 30];
        float s = 0.f;
#pragma unroll
        for (int m = 0; m < 30; ++m) s += bf2f(qr[m]) * kr[m];
        idla[i] = 1.0f / s;
    }
    __syncthreads();

    for (int h = 0; h < 4; ++h) {
        short8 bh[5], bl[5];
#pragma unroll
        for (int q = 0; q < 5; ++q) {
            const int ct = (khalf * 5 + q) * 4 + g;
            const long off = ((long)(h * 40 + ct) * 64 + lane) * 8;
            bh[q] = *reinterpret_cast<const short8*>(Bfh + off);
            bl[q] = *reinterpret_cast<const short8*>(Bfl + off);
        }
        short8 aQ[2];
#pragma unroll
        for (int rt = 0; rt < 2; ++rt) {
            const unsigned int* qrow = reinterpret_cast<const unsigned int*>(
                &qpall[(rt * 16 + l15) * 136 + h * 32 + l4 * 8]);
            short8 a;
#pragma unroll
            for (int jj = 0; jj < 4; ++jj) {
                unsigned int u = qrow[jj];
                a[jj * 2] = (short)(u & 0xffffu);
                a[jj * 2 + 1] = (short)(u >> 16);
            }
            if (l4 == 3) { a[6] = 0; a[7] = 0; }
            aQ[rt] = a;
        }
        floatx4 acc[2][5];
#pragma unroll
        for (int rt = 0; rt < 2; ++rt)
#pragma unroll
            for (int q = 0; q < 5; ++q) acc[rt][q] = floatx4{0.f, 0.f, 0.f, 0.f};
#pragma unroll
        for (int q = 0; q < 5; ++q) {
            acc[0][q] = __builtin_amdgcn_mfma_f32_16x16x32_bf16(aQ[0], bh[q], acc[0][q], 0, 0, 0);
            acc[0][q] = __builtin_amdgcn_mfma_f32_16x16x32_bf16(aQ[0], bl[q], acc[0][q], 0, 0, 0);
            acc[1][q] = __builtin_amdgcn_mfma_f32_16x16x32_bf16(aQ[1], bh[q], acc[1][q], 0, 0, 0);
            acc[1][q] = __builtin_amdgcn_mfma_f32_16x16x32_bf16(aQ[1], bl[q], acc[1][q], 0, 0, 0);
        }
#pragma unroll
        for (int rt = 0; rt < 2; ++rt)
#pragma unroll
            for (int r = 0; r < 4; ++r) {
                const int row = rt * 16 + l4 * 4 + r;
                float s = 0.f;
#pragma unroll
                for (int q = 0; q < 5; ++q)
                    s += acc[rt][q][r] * idla[h * 320 + row * 10 + khalf * 5 + q];
                part[khalf][row][g * 16 + l15] = s;
            }
        __syncthreads();
        {
            const int row = t >> 4, d4 = t & 15;
            float4 p0 = *reinterpret_cast<const float4*>(&part[0][row][d4 * 4]);
            float4 p1 = *reinterpret_cast<const float4*>(&part[1][row][d4 * 4]);
            float4 zv;
            zv.x = 0.1f * (p0.x + p1.x); zv.y = 0.1f * (p0.y + p1.y);
            zv.z = 0.1f * (p0.z + p1.z); zv.w = 0.1f * (p0.w + p1.w);
            reinterpret_cast<float4*>(zl)[row * 65 + h * 16 + d4] = zv;
        }
        __syncthreads();
    }
    {
        const int rt = wave >> 2, ct = wave & 3;
        floatx4 o = floatx4{0.f, 0.f, 0.f, 0.f};
#pragma unroll
        for (int ks = 0; ks < 8; ++ks) {
            const float* zr = &zl[(rt * 16 + l15) * 260 + ks * 32 + l4 * 8];
            float4 x0 = *reinterpret_cast<const float4*>(zr);
            float4 x1 = *reinterpret_cast<const float4*>(zr + 4);
            float xv[8] = {x0.x, x0.y, x0.z, x0.w, x1.x, x1.y, x1.z, x1.w};
            short8 ah, al;
#pragma unroll
            for (int j = 0; j < 8; ++j) {
                unsigned short hi, lo; split2(xv[j], hi, lo);
                ah[j] = (short)hi; al[j] = (short)lo;
            }
            const int slot = ct * 8 + ks;
            short8 wbh = *reinterpret_cast<const short8*>(&Wofh[slot * 512 + lane * 8]);
            short8 wbl = *reinterpret_cast<const short8*>(&Wofl[slot * 512 + lane * 8]);
            o = __builtin_amdgcn_mfma_f32_16x16x32_bf16(ah, wbh, o, 0, 0, 0);
            o = __builtin_amdgcn_mfma_f32_16x16x32_bf16(ah, wbl, o, 0, 0, 0);
            o = __builtin_amdgcn_mfma_f32_16x16x32_bf16(al, wbh, o, 0, 0, 0);
        }
        const int col = ct * 16 + l15;
        const float bb = bo[col];
#pragma unroll
        for (int r = 0; r < 4; ++r) {
            const int n = n0 + rt * 16 + l4 * 4 + r;
            if (n < N) out[(long)n * 64 + col] = o[r] + bb;
        }
    }
}

extern "C" void kernel_launch(void* const* d_in, const int* in_sizes, int n_in,
                              void* d_out, int out_size, void* d_ws, size_t ws_size,
                              hipStream_t stream)
{
    const float* z    = (const float*)d_in[0];
    const float* Wq   = (const float*)d_in[1];
    const float* bq   = (const float*)d_in[2];
    const float* Wk   = (const float*)d_in[3];
    const float* bk   = (const float*)d_in[4];
    const float* Wv   = (const float*)d_in[5];
    const float* bv   = (const float*)d_in[6];
    const float* Wo   = (const float*)d_in[7];
    const float* bo   = (const float*)d_in[8];
    const float* proj = (const float*)d_in[9];
    const float* gum  = (const float*)d_in[10];
    const float* tau  = (const float*)d_in[11];
    float* out = (float*)d_out;

    const int N = in_sizes[0] / 64;          // 50000
    const int ntiles = (N + 15) / 16;        // 3125
    const int nchunk = (N + 127) / 128;      // 391
    const int nblk3  = (N + 31) / 32;        // 1563

    char* wsb = (char*)d_ws;
    size_t off = 0;
    __hip_bfloat16* qp16 = (__hip_bfloat16*)(wsb);
    off += ((size_t)N * 120 * 2 + 255) & ~(size_t)255;
    __hip_bfloat16* v16 = (__hip_bfloat16*)(wsb + off);
    off += ((size_t)N * 256 * 2 + 255) & ~(size_t)255;
    __hip_bfloat16* p16 = (__hip_bfloat16*)(wsb + off);
    off += ((size_t)N * 120 * 2 + 255) & ~(size_t)255;
    float* kvs      = (float*)(wsb + off);
    float* kssum    = kvs + 76800;
    float* headmax  = kssum + 1200;
    float* blockmax = headmax + 4;
    off += ((size_t)(76800 + 1200 + 4 + (size_t)ntiles * 4) * 4 + 255) & ~(size_t)255;
    unsigned short* Wfh = (unsigned short*)(wsb + off); off += 49152 * 2;
    unsigned short* Wfl = (unsigned short*)(wsb + off); off += 49152 * 2;
    unsigned short* Pfh = (unsigned short*)(wsb + off); off += 2048 * 2;
    unsigned short* Pfl = (unsigned short*)(wsb + off); off += 2048 * 2;
    unsigned short* Wofh = (unsigned short*)(wsb + off); off += 16384 * 2;
    unsigned short* Wofl = (unsigned short*)(wsb + off); off += 16384 * 2;
    unsigned short* Bfh  = (unsigned short*)(wsb + off); off += 81920 * 2;
    unsigned short* Bfl  = (unsigned short*)(wsb + off); off += 81920 * 2;
    off = (off + 255) & ~(size_t)255;
    float* part = (float*)(wsb + off);
    const size_t part_bytes = (size_t)512 * 19520 * 4;
    const int mode = (ws_size >= off + part_bytes) ? 1 : 0;   // two-stage if ws fits

    k_prep<<<dim3(26), dim3(256), 0, stream>>>(Wq, Wk, Wv, proj, Wo,
                                               Wfh, Wfl, Pfh, Pfl, Wofh, Wofl);
    if (!mode)
        k0_zero<<<dim3((78000 + 255) / 256), dim3(256), 0, stream>>>(kvs, 78000);
    k1_feat<<<dim3(ntiles), dim3(256), 0, stream>>>(z, bq, bk, bv, Wfh, Wfl, Pfh, Pfl, tau,
                                                    qp16, v16, p16, blockmax, N);
    k1b_redmax<<<dim3(1), dim3(256), 0, stream>>>(blockmax, headmax, ntiles);
    k2_kvs<<<dim3(512), dim3(256), 0, stream>>>(p16, gum, v16, tau, headmax, blockmax,
                                                kvs, kssum, part, mode, N, nchunk);
    if (mode)
        k2r_reduce<<<dim3(325), dim3(256), 0, stream>>>(part, kssum, Bfh, Bfl);
    else
        k2b_frag<<<dim3(40), dim3(256), 0, stream>>>(kvs, Bfh, Bfl);
    k3_out<<<dim3(nblk3), dim3(512), 0, stream>>>(qp16, Bfh, Bfl, kssum,
                                                  Wofh, Wofl, bo, out, N);
}

// Round 16
// 157.764 us; speedup vs baseline: 44.3285x; 1.1931x over previous
//
#include <hip/hip_runtime.h>
#include <hip/hip_bf16.h>

// NodeFormerConv: Performer/Gumbel attention. fp32-equivalent math, fp32 output.
//   k_prep: split Wq|Wk|Wv, proj, Wo into MFMA-fragment-ordered hi/lo bf16
//   (k0   zero kvs/kssum — only in atomic-fallback mode)
//   k1   per 16-row tile, MFMA: QKV gemm (ct = wave+4*ci: Q=ci0-3,K=4-7,V=8-11 held
//        in regs); phi gemm; diag/rowmax/exp in-register; v16/qp16/p16 staged in
//        LDS (union over qd) and flushed as contiguous uint4 spans
//   k2   MFMA accumulate; headmax reduced in-kernel from blockmax (k1b folded);
//        kp = RATIO*(p16*scaleAll[tile] + NEPS); batched+prefetched staging;
//        flush -> private slab (or atomics fallback)
//   k2r  (mode 1) reduce 128 chunk-slabs -> kssum + fragment-ordered Bfh/Bfl direct
//   k2b  (mode 0 only) split kvs into fragments
//   k3   per 32-row block: den up front; B-frags from global, NUM MFMA,
//        in-register idl scale, part exchange -> zl; out = zl@Wo + bo (f32)

#define NEPS  1e-6f
#define RATIO 0.18257418583505536f   // 1/sqrt(30)
#define DNORM 0.35355339059327378f   // 64^-0.25

typedef __attribute__((ext_vector_type(8))) short short8;
typedef __attribute__((ext_vector_type(4))) float floatx4;

__device__ inline unsigned short f2bf(float x) {
    __hip_bfloat16 b = __float2bfloat16(x);
    return __builtin_bit_cast(unsigned short, b);
}
__device__ inline float bf2f(unsigned short h) {
    return __builtin_bit_cast(float, (unsigned int)h << 16);
}
__device__ inline void split2(float v, unsigned short& hi, unsigned short& lo) {
    unsigned short h = f2bf(v);
    hi = h; lo = f2bf(v - bf2f(h));
}

__global__ __launch_bounds__(256) void k0_zero(float* __restrict__ p, int count) {
    int id = blockIdx.x * 256 + threadIdx.x;
    if (id < count) p[id] = 0.f;
}

// ---- k_prep: fragment-ordered hi/lo splits (unchanged) ----
__global__ __launch_bounds__(256) void k_prep(
    const float* __restrict__ Wq, const float* __restrict__ Wk, const float* __restrict__ Wv,
    const float* __restrict__ proj, const float* __restrict__ Wo,
    unsigned short* __restrict__ Wfh, unsigned short* __restrict__ Wfl,
    unsigned short* __restrict__ Pfh, unsigned short* __restrict__ Pfl,
    unsigned short* __restrict__ Wofh, unsigned short* __restrict__ Wofl)
{
    const int b = blockIdx.x, t = threadIdx.x;
    if (b < 24) {
        const int slot = b * 256 + t;
        const int lane = slot & 63;
        const int ctks = slot >> 6;
        const int ct = ctks >> 1, ks = ctks & 1;
        const int col = ct * 16 + (lane & 15);
        const int k0 = ks * 32 + (lane >> 4) * 8;
        const float* W = (col < 256) ? Wq : (col < 512) ? Wk : Wv;
        const int cm = col & 255;
#pragma unroll
        for (int j = 0; j < 8; ++j) {
            float w = W[(k0 + j) * 256 + cm];
            unsigned short hi, lo; split2(w, hi, lo);
            Wfh[slot * 8 + j] = hi;
            Wfl[slot * 8 + j] = lo;
        }
    } else if (b == 24) {
        const int lane = t & 63;
        const int ctks = t >> 6;
        const int ct2 = ctks >> 1, ks = ctks & 1;
        const int m = ct2 * 16 + (lane & 15);
        const int k0 = ks * 32 + (lane >> 4) * 8;
#pragma unroll
        for (int j = 0; j < 8; ++j) {
            float p = (m < 30) ? proj[m * 64 + k0 + j] : 0.f;
            unsigned short hi, lo; split2(p, hi, lo);
            Pfh[t * 8 + j] = hi;
            Pfl[t * 8 + j] = lo;
        }
    } else {
        for (int idx = t; idx < 2048; idx += 256) {
            const int slot = idx >> 6, l = idx & 63;
            const int ct = slot >> 3, ks = slot & 7;
            const int col = ct * 16 + (l & 15);
            const int k0 = ks * 32 + (l >> 4) * 8;
#pragma unroll
            for (int j = 0; j < 8; ++j) {
                float w = Wo[(k0 + j) * 64 + col];
                unsigned short hi, lo; split2(w, hi, lo);
                Wofh[slot * 512 + l * 8 + j] = hi;
                Wofl[slot * 512 + l * 8 + j] = lo;
            }
        }
    }
}

// ---- k1: per 16-row tile; coalesced staged stores ----
__global__ __launch_bounds__(256) void k1_feat(
    const float* __restrict__ z,
    const float* __restrict__ bq, const float* __restrict__ bk, const float* __restrict__ bv,
    const unsigned short* __restrict__ Wfh, const unsigned short* __restrict__ Wfl,
    const unsigned short* __restrict__ Pfh, const unsigned short* __restrict__ Pfl,
    const float* __restrict__ tau,
    __hip_bfloat16* __restrict__ qp16, __hip_bfloat16* __restrict__ v16,
    __hip_bfloat16* __restrict__ p16, float* __restrict__ blockmax, int N)
{
    __shared__ alignas(16) unsigned short zh[16 * 72];
    __shared__ alignas(16) unsigned short zl_[16 * 72];
    __shared__ alignas(16) float qd[16 * 268];   // unioned w/ staging after P2 loads
    __shared__ alignas(16) float kd[16 * 268];

    unsigned short* vsS = reinterpret_cast<unsigned short*>(qd);   // [16*256] 8192B
    unsigned short* qpS = vsS + 4096;                              // [16*120] 3840B
    unsigned short* ppS = qpS + 1920;                              // [16*120] 3840B

    const int t = threadIdx.x;
    const int n0 = blockIdx.x * 16;
    const int wave = t >> 6, lane = t & 63;
    const int l15 = lane & 15, l4 = lane >> 4;
    const float dsc = rsqrtf(tau[0]) * DNORM;

    // P0: load z rows, split hi/lo
    for (int i = t; i < 1024; i += 256) {
        int r = i >> 6, c = i & 63;
        float v = (n0 + r < N) ? z[(long)(n0 + r) * 64 + c] : 0.f;
        unsigned short hi, lo; split2(v, hi, lo);
        zh[r * 72 + c] = hi;
        zl_[r * 72 + c] = lo;
    }
    __syncthreads();

    // P1: QKV GEMM. ct = wave + 4*ci: ci 0-3 -> Q, 4-7 -> K, 8-11 -> V (regs)
    float accv[4][4];
    {
        const int abase = l15 * 72 + l4 * 8;
        short8 ah0 = *reinterpret_cast<const short8*>(&zh[abase]);
        short8 ah1 = *reinterpret_cast<const short8*>(&zh[abase + 32]);
        short8 al0 = *reinterpret_cast<const short8*>(&zl_[abase]);
        short8 al1 = *reinterpret_cast<const short8*>(&zl_[abase + 32]);
        const int row0 = l4 * 4;
#define QKV_MFMA(ci_)                                                                   \
        floatx4 acc = floatx4{0.f, 0.f, 0.f, 0.f};                                      \
        {                                                                               \
            const int ct = wave + 4 * (ci_);                                            \
            short8 bh0 = *reinterpret_cast<const short8*>(&Wfh[(ct * 2 + 0) * 512 + lane * 8]); \
            short8 bh1 = *reinterpret_cast<const short8*>(&Wfh[(ct * 2 + 1) * 512 + lane * 8]); \
            short8 bl0 = *reinterpret_cast<const short8*>(&Wfl[(ct * 2 + 0) * 512 + lane * 8]); \
            short8 bl1 = *reinterpret_cast<const short8*>(&Wfl[(ct * 2 + 1) * 512 + lane * 8]); \
            acc = __builtin_amdgcn_mfma_f32_16x16x32_bf16(ah0, bh0, acc, 0, 0, 0);      \
            acc = __builtin_amdgcn_mfma_f32_16x16x32_bf16(ah1, bh1, acc, 0, 0, 0);      \
            acc = __builtin_amdgcn_mfma_f32_16x16x32_bf16(ah0, bl0, acc, 0, 0, 0);      \
            acc = __builtin_amdgcn_mfma_f32_16x16x32_bf16(ah1, bl1, acc, 0, 0, 0);      \
            acc = __builtin_amdgcn_mfma_f32_16x16x32_bf16(al0, bh0, acc, 0, 0, 0);      \
            acc = __builtin_amdgcn_mfma_f32_16x16x32_bf16(al1, bh1, acc, 0, 0, 0);      \
        }
#pragma unroll 2
        for (int ci = 0; ci < 4; ++ci) {           // Q
            QKV_MFMA(ci)
            const int c = (wave + 4 * ci) * 16 + l15;
            const float bb = bq[c];
#pragma unroll
            for (int r = 0; r < 4; ++r) qd[(row0 + r) * 268 + c] = (acc[r] + bb) * dsc;
        }
#pragma unroll 2
        for (int ci = 4; ci < 8; ++ci) {           // K
            QKV_MFMA(ci)
            const int c = (wave + 4 * ci) * 16 + l15 - 256;
            const float bb = bk[c];
#pragma unroll
            for (int r = 0; r < 4; ++r) kd[(row0 + r) * 268 + c] = (acc[r] + bb) * dsc;
        }
#pragma unroll
        for (int ci = 8; ci < 12; ++ci) {          // V: hold in regs (+bias)
            QKV_MFMA(ci)
            const int c = (wave + 4 * ci) * 16 + l15 - 512;
            const float bb = bv[c];
#pragma unroll
            for (int r = 0; r < 4; ++r) accv[ci - 8][r] = acc[r] + bb;
        }
#undef QKV_MFMA
    }
    __syncthreads();

    // P2: phi MFMA (wave w: head w); all epilogue in-register; staged stores
    {
        short8 pbh[2][2], pbl[2][2];
#pragma unroll
        for (int ct2 = 0; ct2 < 2; ++ct2)
#pragma unroll
            for (int ks = 0; ks < 2; ++ks) {
                pbh[ct2][ks] = *reinterpret_cast<const short8*>(&Pfh[(ct2 * 2 + ks) * 512 + lane * 8]);
                pbl[ct2][ks] = *reinterpret_cast<const short8*>(&Pfl[(ct2 * 2 + ks) * 512 + lane * 8]);
            }
        const int h = wave;
        const int row0 = l4 * 4;
        const int rbase = l15 * 268 + h * 64 + l4 * 8;
        float xq[8], yq[8], xk[8], yk[8];
        {
            float4 a0 = *reinterpret_cast<const float4*>(&qd[rbase]);
            float4 a1 = *reinterpret_cast<const float4*>(&qd[rbase + 4]);
            float4 a2 = *reinterpret_cast<const float4*>(&qd[rbase + 32]);
            float4 a3 = *reinterpret_cast<const float4*>(&qd[rbase + 36]);
            xq[0]=a0.x; xq[1]=a0.y; xq[2]=a0.z; xq[3]=a0.w;
            xq[4]=a1.x; xq[5]=a1.y; xq[6]=a1.z; xq[7]=a1.w;
            yq[0]=a2.x; yq[1]=a2.y; yq[2]=a2.z; yq[3]=a2.w;
            yq[4]=a3.x; yq[5]=a3.y; yq[6]=a3.z; yq[7]=a3.w;
            float4 b0 = *reinterpret_cast<const float4*>(&kd[rbase]);
            float4 b1 = *reinterpret_cast<const float4*>(&kd[rbase + 4]);
            float4 b2 = *reinterpret_cast<const float4*>(&kd[rbase + 32]);
            float4 b3 = *reinterpret_cast<const float4*>(&kd[rbase + 36]);
            xk[0]=b0.x; xk[1]=b0.y; xk[2]=b0.z; xk[3]=b0.w;
            xk[4]=b1.x; xk[5]=b1.y; xk[6]=b1.z; xk[7]=b1.w;
            yk[0]=b2.x; yk[1]=b2.y; yk[2]=b2.z; yk[3]=b2.w;
            yk[4]=b3.x; yk[5]=b3.y; yk[6]=b3.z; yk[7]=b3.w;
        }
        __syncthreads();               // qd/kd dead -> union staging writable

        // ---- q side ----
        {
            float diag;
            {
                float s = 0.f;
#pragma unroll
                for (int j = 0; j < 8; ++j) s += xq[j] * xq[j] + yq[j] * yq[j];
                s += __shfl_xor(s, 16);
                s += __shfl_xor(s, 32);
                diag = 0.5f * s;
            }
            short8 ah0, al0, ah1, al1;
#pragma unroll
            for (int j = 0; j < 8; ++j) {
                unsigned short hi, lo;
                split2(xq[j], hi, lo); ah0[j] = (short)hi; al0[j] = (short)lo;
                split2(yq[j], hi, lo); ah1[j] = (short)hi; al1[j] = (short)lo;
            }
            floatx4 acc2[2];
#pragma unroll
            for (int ct2 = 0; ct2 < 2; ++ct2) {
                floatx4 acc = floatx4{0.f, 0.f, 0.f, 0.f};
                acc = __builtin_amdgcn_mfma_f32_16x16x32_bf16(ah0, pbh[ct2][0], acc, 0, 0, 0);
                acc = __builtin_amdgcn_mfma_f32_16x16x32_bf16(ah1, pbh[ct2][1], acc, 0, 0, 0);
                acc = __builtin_amdgcn_mfma_f32_16x16x32_bf16(ah0, pbl[ct2][0], acc, 0, 0, 0);
                acc = __builtin_amdgcn_mfma_f32_16x16x32_bf16(ah1, pbl[ct2][1], acc, 0, 0, 0);
                acc = __builtin_amdgcn_mfma_f32_16x16x32_bf16(al0, pbh[ct2][0], acc, 0, 0, 0);
                acc = __builtin_amdgcn_mfma_f32_16x16x32_bf16(al1, pbh[ct2][1], acc, 0, 0, 0);
                acc2[ct2] = acc;
            }
#pragma unroll
            for (int r = 0; r < 4; ++r) {
                float a1 = (l15 >= 14) ? -3.4e38f : acc2[1][r];
                float v = fmaxf(acc2[0][r], a1);
                v = fmaxf(v, __shfl_xor(v, 1));
                v = fmaxf(v, __shfl_xor(v, 2));
                v = fmaxf(v, __shfl_xor(v, 4));
                v = fmaxf(v, __shfl_xor(v, 8));
#pragma unroll
                for (int ct2 = 0; ct2 < 2; ++ct2) {
                    const int m = ct2 * 16 + l15;
                    if (m < 30)
                        qpS[(row0 + r) * 120 + h * 30 + m] =
                            f2bf(RATIO * (__expf(acc2[ct2][r] - diag - v) + NEPS));
                }
            }
        }
        // ---- k side ----
        {
            float diag;
            {
                float s = 0.f;
#pragma unroll
                for (int j = 0; j < 8; ++j) s += xk[j] * xk[j] + yk[j] * yk[j];
                s += __shfl_xor(s, 16);
                s += __shfl_xor(s, 32);
                diag = 0.5f * s;
            }
            short8 ah0, al0, ah1, al1;
#pragma unroll
            for (int j = 0; j < 8; ++j) {
                unsigned short hi, lo;
                split2(xk[j], hi, lo); ah0[j] = (short)hi; al0[j] = (short)lo;
                split2(yk[j], hi, lo); ah1[j] = (short)hi; al1[j] = (short)lo;
            }
            floatx4 acc2[2];
#pragma unroll
            for (int ct2 = 0; ct2 < 2; ++ct2) {
                floatx4 acc = floatx4{0.f, 0.f, 0.f, 0.f};
                acc = __builtin_amdgcn_mfma_f32_16x16x32_bf16(ah0, pbh[ct2][0], acc, 0, 0, 0);
                acc = __builtin_amdgcn_mfma_f32_16x16x32_bf16(ah1, pbh[ct2][1], acc, 0, 0, 0);
                acc = __builtin_amdgcn_mfma_f32_16x16x32_bf16(ah0, pbl[ct2][0], acc, 0, 0, 0);
                acc = __builtin_amdgcn_mfma_f32_16x16x32_bf16(ah1, pbl[ct2][1], acc, 0, 0, 0);
                acc = __builtin_amdgcn_mfma_f32_16x16x32_bf16(al0, pbh[ct2][0], acc, 0, 0, 0);
                acc = __builtin_amdgcn_mfma_f32_16x16x32_bf16(al1, pbh[ct2][1], acc, 0, 0, 0);
                acc2[ct2] = acc;
            }
            float vmax[4];
#pragma unroll
            for (int r = 0; r < 4; ++r) {
                float a1 = (l15 >= 14) ? -3.4e38f : acc2[1][r];
                float v = fmaxf(acc2[0][r], a1);
                v = fmaxf(v, __shfl_xor(v, 1));
                v = fmaxf(v, __shfl_xor(v, 2));
                v = fmaxf(v, __shfl_xor(v, 4));
                v = fmaxf(v, __shfl_xor(v, 8));
                vmax[r] = v;
            }
            float mv = -3.4e38f;
#pragma unroll
            for (int r = 0; r < 4; ++r)
                if (n0 + row0 + r < N) mv = fmaxf(mv, vmax[r]);
            mv = fmaxf(mv, __shfl_xor(mv, 16));
            mv = fmaxf(mv, __shfl_xor(mv, 32));
            if (lane == 0) blockmax[blockIdx.x * 4 + h] = mv;
#pragma unroll
            for (int ct2 = 0; ct2 < 2; ++ct2) {
                const int m = ct2 * 16 + l15;
                if (m < 30)
#pragma unroll
                    for (int r = 0; r < 4; ++r)
                        ppS[(row0 + r) * 120 + h * 30 + m] =
                            f2bf(__expf(acc2[ct2][r] - diag - mv));
            }
        }
        // ---- V stage (compile-time ci) ----
#pragma unroll
        for (int ci = 8; ci < 12; ++ci) {
            const int cc = (wave + 4 * ci - 32) * 16 + l15;
#pragma unroll
            for (int r = 0; r < 4; ++r)
                vsS[(row0 + r) * 256 + cc] = f2bf(accv[ci - 8][r]);
        }
    }
    __syncthreads();

    // P3: coalesced uint4 flush (16 rows: v16 = 32 uint4/row, qp/p = 15 uint4/row)
    {
        const uint4* vs4 = reinterpret_cast<const uint4*>(vsS);
        uint4* vg = reinterpret_cast<uint4*>(v16) + (long)n0 * 32;
        for (int i = t; i < 512; i += 256) {
            if (n0 + (i >> 5) < N) vg[i] = vs4[i];
        }
        const uint4* qs4 = reinterpret_cast<const uint4*>(qpS);
        uint4* qg = reinterpret_cast<uint4*>(qp16) + (long)n0 * 15;
        const uint4* ps4 = reinterpret_cast<const uint4*>(ppS);
        uint4* pg = reinterpret_cast<uint4*>(p16) + (long)n0 * 15;
        for (int i = t; i < 240; i += 256) {        // FIX: 16 rows x 15 uint4 = 240
            if (n0 + i / 15 < N) { qg[i] = qs4[i]; pg[i] = ps4[i]; }
        }
    }
}

// ---- k2: MFMA accumulate; in-kernel headmax reduce; kp from p16*scale ----
__global__ __launch_bounds__(256) void k2_kvs(
    const __hip_bfloat16* __restrict__ p16, const float* __restrict__ gum,
    const __hip_bfloat16* __restrict__ v16, const float* __restrict__ tau,
    const float* __restrict__ blockmax,
    float* __restrict__ kvs, float* __restrict__ kssum,
    float* __restrict__ part, int mode, int N, int nchunk, int ntiles)
{
    __shared__ alignas(16) unsigned short Vt[80 * 72];
    __shared__ float kpL[64 * 33];
    __shared__ alignas(16) float geT[13 * 72];
    __shared__ float scaleAll[32];
    __shared__ float redmx[256];

    const int t = threadIdx.x;
    const int h = blockIdx.x >> 7;
    const int chunk = blockIdx.x & 127;
    const int n0 = chunk * nchunk;
    const int n1 = (n0 + nchunk < N) ? (n0 + nchunk) : N;
    const float itau = 1.0f / tau[0];
    const int wave = t >> 6, lane = t & 63;
    const int l15 = lane & 15, l4 = lane >> 4;
    const int tb0 = n0 >> 4;

    int pr_r[4], pr_m[4]; bool pvld[4];
#pragma unroll
    for (int u = 0; u < 4; ++u) {
        int i = t + 256 * u;
        pvld[u] = (i < 960);
        int ii = pvld[u] ? i : 959;
        pr_r[u] = (2 * ii) / 30;
        pr_m[u] = (2 * ii) % 30;
    }
    int gu_k[3], gu_n[3];
#pragma unroll
    for (int u = 0; u < 3; ++u) { int i = t + 256 * u; gu_k[u] = i >> 6; gu_n[u] = i & 63; }
    int v_n[8], v_dp[8];
#pragma unroll
    for (int u = 0; u < 8; ++u) { int i = t + 256 * u; v_n[u] = i >> 5; v_dp[u] = (i & 31) * 2; }

    unsigned int rp[4], rv[8];
    float rg[3];

    floatx4 acc[5][5];
#pragma unroll
    for (int q = 0; q < 5; ++q)
#pragma unroll
        for (int dt = 0; dt < 5; ++dt) acc[q][dt] = floatx4{0.f, 0.f, 0.f, 0.f};

    int mq[5], kq[5];
#pragma unroll
    for (int q = 0; q < 5; ++q) {
        int row = (wave * 5 + q) * 16 + l15;
        mq[q] = row % 30;
        kq[q] = row / 30;
    }

    if (t < 64) Vt[64 * 72 + t] = f2bf(1.0f);
    for (int i = t; i < 15 * 72; i += 256) Vt[65 * 72 + i] = 0;
    for (int i = t; i < 3 * 72; i += 256) geT[10 * 72 + i] = 0.f;

    const int ntile = (n1 - n0 + 63) >> 6;

#define K2_LOAD(nb_)                                                              \
    do {                                                                          \
        _Pragma("unroll")                                                         \
        for (int u = 0; u < 4; ++u) {                                             \
            int n = (nb_) + pr_r[u]; n = (n < n1) ? n : (n1 - 1);                  \
            rp[u] = *reinterpret_cast<const unsigned int*>(                       \
                (const unsigned short*)p16 + (long)n * 120 + h * 30 + pr_m[u]);   \
        }                                                                         \
        _Pragma("unroll")                                                         \
        for (int u = 0; u < 3; ++u) {                                             \
            int n = (nb_) + gu_n[u]; n = (n < n1) ? n : (n1 - 1);                  \
            rg[u] = gum[(long)n * 40 + h * 10 + gu_k[u]];                         \
        }                                                                         \
        _Pragma("unroll")                                                         \
        for (int u = 0; u < 8; ++u) {                                             \
            int n = (nb_) + v_n[u]; n = (n < n1) ? n : (n1 - 1);                   \
            rv[u] = *reinterpret_cast<const unsigned int*>(                       \
                v16 + (long)n * 256 + h * 64 + v_dp[u]);                          \
        }                                                                         \
    } while (0)

    K2_LOAD(n0);

    // in-kernel headmax reduce (folded k1b)
    {
        float lm = -3.4e38f;
        for (int i = t; i < ntiles; i += 256) lm = fmaxf(lm, blockmax[i * 4 + h]);
        redmx[t] = lm;
        __syncthreads();
#pragma unroll
        for (int s = 128; s > 0; s >>= 1) {
            if (t < s) redmx[t] = fmaxf(redmx[t], redmx[t + s]);
            __syncthreads();
        }
    }
    const float MX = redmx[0];
    if (t < 32) {
        int tid = tb0 + t;
        int maxtid = (N - 1) >> 4;
        if (tid > maxtid) tid = maxtid;
        scaleAll[t] = __expf(blockmax[tid * 4 + h] - MX);
    }

    for (int tt = 0; tt < ntile; ++tt) {
        const int nb = n0 + tt * 64;
        __syncthreads();
#pragma unroll
        for (int u = 0; u < 4; ++u) {
            if (pvld[u]) {
                bool ok = (nb + pr_r[u] < n1);
                float sc = scaleAll[((nb + pr_r[u]) >> 4) - tb0];
                float plo = bf2f((unsigned short)(rp[u] & 0xffffu));
                float phi = bf2f((unsigned short)(rp[u] >> 16));
                kpL[pr_r[u] * 33 + pr_m[u]]     = ok ? RATIO * (plo * sc + NEPS) : 0.f;
                kpL[pr_r[u] * 33 + pr_m[u] + 1] = ok ? RATIO * (phi * sc + NEPS) : 0.f;
            }
        }
#pragma unroll
        for (int u = 0; u < 3; ++u) {
            if (u < 2 || t < 128) {
                bool ok = (nb + gu_n[u] < n1);
                geT[gu_k[u] * 72 + gu_n[u]] = ok ? __expf(rg[u] * itau) : 0.f;
            }
        }
#pragma unroll
        for (int u = 0; u < 8; ++u) {
            bool ok = (nb + v_n[u] < n1);
            unsigned int uu = ok ? rv[u] : 0u;
            Vt[v_dp[u] * 72 + v_n[u]] = (unsigned short)(uu & 0xffffu);
            Vt[(v_dp[u] + 1) * 72 + v_n[u]] = (unsigned short)(uu >> 16);
        }
        __syncthreads();
        if (tt + 1 < ntile) K2_LOAD(nb + 64);

#pragma unroll
        for (int nh = 0; nh < 2; ++nh) {
            const int nbase = nh * 32 + l4 * 8;
            short8 b[5];
#pragma unroll
            for (int dt = 0; dt < 5; ++dt)
                b[dt] = *reinterpret_cast<const short8*>(&Vt[(dt * 16 + l15) * 72 + nbase]);
#pragma unroll
            for (int q = 0; q < 5; ++q) {
                float4 g0 = *reinterpret_cast<const float4*>(&geT[kq[q] * 72 + nbase]);
                float4 g1 = *reinterpret_cast<const float4*>(&geT[kq[q] * 72 + nbase + 4]);
                const float gg[8] = {g0.x, g0.y, g0.z, g0.w, g1.x, g1.y, g1.z, g1.w};
                short8 a;
#pragma unroll
                for (int j = 0; j < 8; ++j) {
                    float kp = kpL[(nbase + j) * 33 + mq[q]];
                    a[j] = (short)f2bf(kp * gg[j]);
                }
#pragma unroll
                for (int dt = 0; dt < 5; ++dt)
                    acc[q][dt] = __builtin_amdgcn_mfma_f32_16x16x32_bf16(a, b[dt], acc[q][dt], 0, 0, 0);
            }
        }
    }
#undef K2_LOAD

    if (mode) {
        float* slab = part + (long)blockIdx.x * 19520;
#pragma unroll
        for (int q = 0; q < 5; ++q) {
            const int kmb = (wave * 5 + q) * 16 + l4 * 4;
#pragma unroll
            for (int r = 0; r < 4; ++r) {
                const int km = kmb + r;
                if (km < 300) {
#pragma unroll
                    for (int dt = 0; dt < 4; ++dt)
                        slab[km * 64 + dt * 16 + l15] = acc[q][dt][r];
                    if (l15 == 0) slab[19200 + km] = acc[q][4][r];
                }
            }
        }
    } else {
        float* kvh = kvs + h * 19200;
#pragma unroll
        for (int q = 0; q < 5; ++q) {
            const int kmb = (wave * 5 + q) * 16 + l4 * 4;
#pragma unroll
            for (int r = 0; r < 4; ++r) {
                const int km = kmb + r;
                if (km < 300) {
#pragma unroll
                    for (int dt = 0; dt < 4; ++dt)
                        atomicAdd(&kvh[km * 64 + dt * 16 + l15], acc[q][dt][r]);
                    if (l15 == 0)
                        atomicAdd(&kssum[h * 300 + km], acc[q][4][r]);
                }
            }
        }
    }
}

// ---- k2r (mode 1): reduce 128 slabs/head -> kssum + Bfh/Bfl direct ----
__global__ __launch_bounds__(256) void k2r_reduce(
    const float* __restrict__ part, float* __restrict__ kssum,
    unsigned short* __restrict__ Bfh, unsigned short* __restrict__ Bfl)
{
    const int b = blockIdx.x, t = threadIdx.x;
    if (b >= 305) {                                    // pad zeroing
        const int p = (b - 305) * 256 + t;             // < 5120
        const int j = 6 + (p & 1);
        const int q2 = p >> 1;
        const int l15 = q2 & 15;
        const int ct = (q2 >> 4) % 40;
        const int h = q2 / 640;
        const long idx = ((long)(h * 40 + ct) * 64 + 48 + l15) * 8 + j;
        Bfh[idx] = 0; Bfl[idx] = 0;
        return;
    }
    const int o = b * 256 + t;
    if (o >= 4 * 19504) return;
    const int h = o / 19504, e = o % 19504;
    const float* p = part + (long)h * 128 * 19520 + e;
    float s = 0.f;
#pragma unroll 8
    for (int c = 0; c < 128; ++c) s += p[(long)c * 19520];
    if (e < 19200) {
        const int km = e >> 6, d = e & 63;
        const int k = km / 30, m = km % 30;
        const int col = k * 64 + d;
        const int ct = col >> 4;
        const int lane = ((m >> 3) << 4) | (d & 15);
        const int j = m & 7;
        const long idx = ((long)(h * 40 + ct) * 64 + lane) * 8 + j;
        unsigned short hi, lo; split2(s, hi, lo);
        Bfh[idx] = hi; Bfl[idx] = lo;
    } else if (e - 19200 < 300) {
        kssum[h * 300 + (e - 19200)] = s;
    }
}

// ---- k2b (mode 0 only) ----
__global__ __launch_bounds__(256) void k2b_frag(
    const float* __restrict__ kvs,
    unsigned short* __restrict__ Bfh, unsigned short* __restrict__ Bfl)
{
    const int slot = blockIdx.x * 256 + threadIdx.x;
    if (slot >= 10240) return;
    const int h = slot / 2560;
    const int rem = slot % 2560;
    const int ct = rem >> 6, lane = rem & 63;
    const int col = ct * 16 + (lane & 15);
    const int k = col >> 6, d = col & 63;
    const int mb = (lane >> 4) * 8;
    const float* src = kvs + h * 19200 + (k * 30 + mb) * 64 + d;
    short8 hi8, lo8;
#pragma unroll
    for (int j = 0; j < 8; ++j) {
        float v = (mb + j < 30) ? src[j * 64] : 0.f;
        unsigned short hh, ll; split2(v, hh, ll);
        hi8[j] = (short)hh; lo8[j] = (short)ll;
    }
    *reinterpret_cast<short8*>(&Bfh[(long)slot * 8]) = hi8;
    *reinterpret_cast<short8*>(&Bfl[(long)slot * 8]) = lo8;
}

// ---- k3: unchanged ----
__global__ __launch_bounds__(512) void k3_out(
    const __hip_bfloat16* __restrict__ qp16,
    const unsigned short* __restrict__ Bfh, const unsigned short* __restrict__ Bfl,
    const float* __restrict__ kssum,
    const unsigned short* __restrict__ Wofh, const unsigned short* __restrict__ Wofl,
    const float* __restrict__ bo, float* __restrict__ out, int N)
{
    __shared__ alignas(16) unsigned short qpall[32 * 136];
    __shared__ float ksall[1200];
    __shared__ float idla[4 * 320];
    __shared__ alignas(16) float part[2][32][68];
    __shared__ alignas(16) float zl[32 * 260];

    const int t = threadIdx.x;
    const int n0 = blockIdx.x * 32;
    const int wave = t >> 6, lane = t & 63;
    const int g = wave & 3, khalf = wave >> 2;
    const int l15 = lane & 15, l4 = lane >> 4;

    for (int i = t; i < 1200; i += 512) ksall[i] = kssum[i];
    for (int i = t; i < 32 * 60; i += 512) {
        int rr = i / 60, dw = i % 60;
        int n = n0 + rr; if (n >= N) n = N - 1;
        unsigned int u = *reinterpret_cast<const unsigned int*>(
            (const unsigned short*)qp16 + (long)n * 120 + dw * 2);
        int h = dw / 15, md = (dw % 15) * 2;
        qpall[rr * 136 + h * 32 + md] = (unsigned short)(u & 0xffffu);
        qpall[rr * 136 + h * 32 + md + 1] = (unsigned short)(u >> 16);
    }
    __syncthreads();

    for (int i = t; i < 1280; i += 512) {
        int h = i / 320, rem = i % 320;
        int rr = rem / 10, kk = rem % 10;
        const unsigned short* qr = &qpall[rr * 136 + h * 32];
        const float* kr = &ksall[h * 300 + kk * 30];
        float s = 0.f;
#pragma unroll
        for (int m = 0; m < 30; ++m) s += bf2f(qr[m]) * kr[m];
        idla[i] = 1.0f / s;
    }
    __syncthreads();

    for (int h = 0; h < 4; ++h) {
        short8 bh[5], bl[5];
#pragma unroll
        for (int q = 0; q < 5; ++q) {
            const int ct = (khalf * 5 + q) * 4 + g;
            const long off = ((long)(h * 40 + ct) * 64 + lane) * 8;
            bh[q] = *reinterpret_cast<const short8*>(Bfh + off);
            bl[q] = *reinterpret_cast<const short8*>(Bfl + off);
        }
        short8 aQ[2];
#pragma unroll
        for (int rt = 0; rt < 2; ++rt) {
            const unsigned int* qrow = reinterpret_cast<const unsigned int*>(
                &qpall[(rt * 16 + l15) * 136 + h * 32 + l4 * 8]);
            short8 a;
#pragma unroll
            for (int jj = 0; jj < 4; ++jj) {
                unsigned int u = qrow[jj];
                a[jj * 2] = (short)(u & 0xffffu);
                a[jj * 2 + 1] = (short)(u >> 16);
            }
            if (l4 == 3) { a[6] = 0; a[7] = 0; }
            aQ[rt] = a;
        }
        floatx4 acc[2][5];
#pragma unroll
        for (int rt = 0; rt < 2; ++rt)
#pragma unroll
            for (int q = 0; q < 5; ++q) acc[rt][q] = floatx4{0.f, 0.f, 0.f, 0.f};
#pragma unroll
        for (int q = 0; q < 5; ++q) {
            acc[0][q] = __builtin_amdgcn_mfma_f32_16x16x32_bf16(aQ[0], bh[q], acc[0][q], 0, 0, 0);
            acc[0][q] = __builtin_amdgcn_mfma_f32_16x16x32_bf16(aQ[0], bl[q], acc[0][q], 0, 0, 0);
            acc[1][q] = __builtin_amdgcn_mfma_f32_16x16x32_bf16(aQ[1], bh[q], acc[1][q], 0, 0, 0);
            acc[1][q] = __builtin_amdgcn_mfma_f32_16x16x32_bf16(aQ[1], bl[q], acc[1][q], 0, 0, 0);
        }
#pragma unroll
        for (int rt = 0; rt < 2; ++rt)
#pragma unroll
            for (int r = 0; r < 4; ++r) {
                const int row = rt * 16 + l4 * 4 + r;
                float s = 0.f;
#pragma unroll
                for (int q = 0; q < 5; ++q)
                    s += acc[rt][q][r] * idla[h * 320 + row * 10 + khalf * 5 + q];
                part[khalf][row][g * 16 + l15] = s;
            }
        __syncthreads();
        {
            const int row = t >> 4, d4 = t & 15;
            float4 p0 = *reinterpret_cast<const float4*>(&part[0][row][d4 * 4]);
            float4 p1 = *reinterpret_cast<const float4*>(&part[1][row][d4 * 4]);
            float4 zv;
            zv.x = 0.1f * (p0.x + p1.x); zv.y = 0.1f * (p0.y + p1.y);
            zv.z = 0.1f * (p0.z + p1.z); zv.w = 0.1f * (p0.w + p1.w);
            reinterpret_cast<float4*>(zl)[row * 65 + h * 16 + d4] = zv;
        }
        __syncthreads();
    }
    {
        const int rt = wave >> 2, ct = wave & 3;
        floatx4 o = floatx4{0.f, 0.f, 0.f, 0.f};
#pragma unroll
        for (int ks = 0; ks < 8; ++ks) {
            const float* zr = &zl[(rt * 16 + l15) * 260 + ks * 32 + l4 * 8];
            float4 x0 = *reinterpret_cast<const float4*>(zr);
            float4 x1 = *reinterpret_cast<const float4*>(zr + 4);
            float xv[8] = {x0.x, x0.y, x0.z, x0.w, x1.x, x1.y, x1.z, x1.w};
            short8 ah, al;
#pragma unroll
            for (int j = 0; j < 8; ++j) {
                unsigned short hi, lo; split2(xv[j], hi, lo);
                ah[j] = (short)hi; al[j] = (short)lo;
            }
            const int slot = ct * 8 + ks;
            short8 wbh = *reinterpret_cast<const short8*>(&Wofh[slot * 512 + lane * 8]);
            short8 wbl = *reinterpret_cast<const short8*>(&Wofl[slot * 512 + lane * 8]);
            o = __builtin_amdgcn_mfma_f32_16x16x32_bf16(ah, wbh, o, 0, 0, 0);
            o = __builtin_amdgcn_mfma_f32_16x16x32_bf16(ah, wbl, o, 0, 0, 0);
            o = __builtin_amdgcn_mfma_f32_16x16x32_bf16(al, wbh, o, 0, 0, 0);
        }
        const int col = ct * 16 + l15;
        const float bb = bo[col];
#pragma unroll
        for (int r = 0; r < 4; ++r) {
            const int n = n0 + rt * 16 + l4 * 4 + r;
            if (n < N) out[(long)n * 64 + col] = o[r] + bb;
        }
    }
}

extern "C" void kernel_launch(void* const* d_in, const int* in_sizes, int n_in,
                              void* d_out, int out_size, void* d_ws, size_t ws_size,
                              hipStream_t stream)
{
    const float* z    = (const float*)d_in[0];
    const float* Wq   = (const float*)d_in[1];
    const float* bq   = (const float*)d_in[2];
    const float* Wk   = (const float*)d_in[3];
    const float* bk   = (const float*)d_in[4];
    const float* Wv   = (const float*)d_in[5];
    const float* bv   = (const float*)d_in[6];
    const float* Wo   = (const float*)d_in[7];
    const float* bo   = (const float*)d_in[8];
    const float* proj = (const float*)d_in[9];
    const float* gum  = (const float*)d_in[10];
    const float* tau  = (const float*)d_in[11];
    float* out = (float*)d_out;

    const int N = in_sizes[0] / 64;          // 50000
    const int ntiles = (N + 15) / 16;        // 3125
    const int nchunk = (N + 127) / 128;      // 391
    const int nblk3  = (N + 31) / 32;        // 1563

    char* wsb = (char*)d_ws;
    size_t off = 0;
    __hip_bfloat16* qp16 = (__hip_bfloat16*)(wsb);
    off += ((size_t)N * 120 * 2 + 255) & ~(size_t)255;
    __hip_bfloat16* v16 = (__hip_bfloat16*)(wsb + off);
    off += ((size_t)N * 256 * 2 + 255) & ~(size_t)255;
    __hip_bfloat16* p16 = (__hip_bfloat16*)(wsb + off);
    off += ((size_t)N * 120 * 2 + 255) & ~(size_t)255;
    float* kvs      = (float*)(wsb + off);
    float* kssum    = kvs + 76800;
    float* headmax  = kssum + 1200;
    float* blockmax = headmax + 4;
    off += ((size_t)(76800 + 1200 + 4 + (size_t)ntiles * 4) * 4 + 255) & ~(size_t)255;
    unsigned short* Wfh = (unsigned short*)(wsb + off); off += 49152 * 2;
    unsigned short* Wfl = (unsigned short*)(wsb + off); off += 49152 * 2;
    unsigned short* Pfh = (unsigned short*)(wsb + off); off += 2048 * 2;
    unsigned short* Pfl = (unsigned short*)(wsb + off); off += 2048 * 2;
    unsigned short* Wofh = (unsigned short*)(wsb + off); off += 16384 * 2;
    unsigned short* Wofl = (unsigned short*)(wsb + off); off += 16384 * 2;
    unsigned short* Bfh  = (unsigned short*)(wsb + off); off += 81920 * 2;
    unsigned short* Bfl  = (unsigned short*)(wsb + off); off += 81920 * 2;
    off = (off + 255) & ~(size_t)255;
    float* part = (float*)(wsb + off);
    const size_t part_bytes = (size_t)512 * 19520 * 4;
    const int mode = (ws_size >= off + part_bytes) ? 1 : 0;   // two-stage if ws fits

    k_prep<<<dim3(26), dim3(256), 0, stream>>>(Wq, Wk, Wv, proj, Wo,
                                               Wfh, Wfl, Pfh, Pfl, Wofh, Wofl);
    if (!mode)
        k0_zero<<<dim3((78000 + 255) / 256), dim3(256), 0, stream>>>(kvs, 78000);
    k1_feat<<<dim3(ntiles), dim3(256), 0, stream>>>(z, bq, bk, bv, Wfh, Wfl, Pfh, Pfl, tau,
                                                    qp16, v16, p16, blockmax, N);
    k2_kvs<<<dim3(512), dim3(256), 0, stream>>>(p16, gum, v16, tau, blockmax,
                                                kvs, kssum, part, mode, N, nchunk, ntiles);
    if (mode)
        k2r_reduce<<<dim3(325), dim3(256), 0, stream>>>(part, kssum, Bfh, Bfl);
    else
        k2b_frag<<<dim3(40), dim3(256), 0, stream>>>(kvs, Bfh, Bfl);
    k3_out<<<dim3(nblk3), dim3(512), 0, stream>>>(qp16, Bfh, Bfl, kssum,
                                                  Wofh, Wofl, bo, out, N);
}